// Round 7
// baseline (971.247 us; speedup 1.0000x reference)
//
#include <hip/hip_runtime.h>
#include <hip/hip_bf16.h>
#include <math.h>

#define NN 20000
#define EE 320000
#define PQ_COLS  384    // q
#define PQP_COLS 288    // qp (global after transform)
#define VE_COLS  672    // [v 384 | vp 288] bf16
#define KE_COLS  768    // 12 heads x 64: [k 32 | kp 24 | 0 | 1(57) | skkp_hi(58) | skkp_res(59) | 0...]
#define FCOLS 1440      // [p2n 384 | node 384 | loc 288 | nrm 96 | dirn 288]

__device__ __forceinline__ float b2f(unsigned short u) {
  return __uint_as_float(((unsigned)u) << 16);
}

template<typename PT> __device__ __forceinline__ float ldp(const PT* p);
template<> __device__ __forceinline__ float ldp<float>(const float* p) { return *p; }
template<> __device__ __forceinline__ float ldp<__hip_bfloat16>(const __hip_bfloat16* p) { return __bfloat162float(*p); }
template<typename PT> __device__ __forceinline__ void stp(PT* p, float v);
template<> __device__ __forceinline__ void stp<float>(float* p, float v) { *p = v; }
template<> __device__ __forceinline__ void stp<__hip_bfloat16>(__hip_bfloat16* p, float v) { *p = __float2bfloat16(v); }

// ---------------- projections: x @ [Wq|Wk|Wv|Wqp|Wkp|Wvp] -> Pq | KE.k | VE.v | Pqp | KE.kp | VE.vp
template<typename TA, typename TP>
__global__ __launch_bounds__(256) void proj_gemm(
    const float* __restrict__ x,
    const float* __restrict__ Wq, const float* __restrict__ Wk, const float* __restrict__ Wv,
    const float* __restrict__ Wqp, const float* __restrict__ Wkp, const float* __restrict__ Wvp,
    TA* __restrict__ Pq, TP* __restrict__ Pqp,
    __hip_bfloat16* __restrict__ KE, __hip_bfloat16* __restrict__ VE)
{
  __shared__ float Ast[32][36];
  __shared__ float Bs[32][132];
  const int t = threadIdx.x;
  const int n0 = blockIdx.x * 32;
  const int c0 = blockIdx.y * 128;
  const int tx = t & 31, ty = t >> 5;
  const int cl = t & 127, kset = t >> 7;
  const int c = c0 + cl;
  const float* wcol = nullptr; int wstr = 0;
  if      (c < 384)  { wcol = Wq  + c;        wstr = 384; }
  else if (c < 768)  { wcol = Wk  + (c-384);  wstr = 384; }
  else if (c < 1152) { wcol = Wv  + (c-768);  wstr = 384; }
  else if (c < 1440) { wcol = Wqp + (c-1152); wstr = 288; }
  else if (c < 1728) { wcol = Wkp + (c-1440); wstr = 288; }
  else if (c < 2016) { wcol = Wvp + (c-1728); wstr = 288; }
  float acc[4][4] = {};
  const int ar = t >> 3, akc = (t & 7) * 4;
  for (int k0 = 0; k0 < 128; k0 += 32) {
    float4 av4 = *(const float4*)&x[(size_t)(n0 + ar)*128 + k0 + akc];
    Ast[akc+0][ar] = av4.x; Ast[akc+1][ar] = av4.y;
    Ast[akc+2][ar] = av4.z; Ast[akc+3][ar] = av4.w;
    #pragma unroll
    for (int u = 0; u < 16; u++) {
      int kk = kset + 2*u;
      Bs[kk][cl] = wcol ? wcol[(size_t)(k0 + kk)*wstr] : 0.f;
    }
    __syncthreads();
    #pragma unroll
    for (int kk = 0; kk < 32; kk++) {
      float4 a4 = *(const float4*)&Ast[kk][ty*4];
      float4 b4 = *(const float4*)&Bs[kk][tx*4];
      float av[4] = {a4.x, a4.y, a4.z, a4.w};
      float bv[4] = {b4.x, b4.y, b4.z, b4.w};
      #pragma unroll
      for (int i2 = 0; i2 < 4; i2++)
        #pragma unroll
        for (int j2 = 0; j2 < 4; j2++)
          acc[i2][j2] += av[i2] * bv[j2];
    }
    __syncthreads();
  }
  const int gc = c0 + tx*4;
  #pragma unroll
  for (int i2 = 0; i2 < 4; i2++) {
    int r = n0 + ty*4 + i2;
    if (gc < 384) {
      TA* dp = Pq + (size_t)r*PQ_COLS + gc;
      #pragma unroll
      for (int j2 = 0; j2 < 4; j2++) stp(&dp[j2], acc[i2][j2]);
    } else if (gc < 768) {                 // k -> KE slots
      int d = gc - 384, h = d >> 5, i = d & 31;
      __hip_bfloat16* dp = KE + (size_t)r*KE_COLS + h*64 + i;
      #pragma unroll
      for (int j2 = 0; j2 < 4; j2++) dp[j2] = __float2bfloat16(acc[i2][j2]);
    } else if (gc < 1152) {                // v -> VE[0..383]
      __hip_bfloat16* dp = VE + (size_t)r*VE_COLS + (gc - 768);
      #pragma unroll
      for (int j2 = 0; j2 < 4; j2++) dp[j2] = __float2bfloat16(acc[i2][j2]);
    } else if (gc < 1440) {                // qp (local)
      TP* dp = Pqp + (size_t)r*PQP_COLS + (gc - 1152);
      #pragma unroll
      for (int j2 = 0; j2 < 4; j2++) stp(&dp[j2], acc[i2][j2]);
    } else if (gc < 1728) {                // kp (local) -> KE slots
      int d = gc - 1440, h = d / 24, i = d - 24*h;
      __hip_bfloat16* dp = KE + (size_t)r*KE_COLS + h*64 + 32 + i;
      #pragma unroll
      for (int j2 = 0; j2 < 4; j2++) dp[j2] = __float2bfloat16(acc[i2][j2]);
    } else {                               // vp (local) -> VE[384..671]
      __hip_bfloat16* dp = VE + (size_t)r*VE_COLS + 384 + (gc - 1728);
      #pragma unroll
      for (int j2 = 0; j2 < 4; j2++) if (gc + j2 < 2016) dp[j2] = __float2bfloat16(acc[i2][j2]);
    }
  }
}

// ---------------- point transform in place: qp (Pqp), kp (KE bf16), vp (VE bf16)
template<typename TP>
__global__ void transform_pts(const float* __restrict__ R, const float* __restrict__ tr,
                              TP* __restrict__ Pqp, __hip_bfloat16* __restrict__ KE,
                              __hip_bfloat16* __restrict__ VE)
{
  int idx = blockIdx.x*256 + threadIdx.x;   // N * 288 point-triples
  if (idx >= NN*288) return;
  int n = idx / 288, rem = idx - n*288;
  const float* Rn = R + (size_t)n*9;
  float t0 = tr[n*3], t1 = tr[n*3+1], t2 = tr[n*3+2];
  if (rem < 96) {
    TP* p = Pqp + (size_t)n*PQP_COLS + rem*3;
    float l0 = ldp(p), l1 = ldp(p+1), l2 = ldp(p+2);
    stp(p,   Rn[0]*l0 + Rn[1]*l1 + Rn[2]*l2 + t0);
    stp(p+1, Rn[3]*l0 + Rn[4]*l1 + Rn[5]*l2 + t1);
    stp(p+2, Rn[6]*l0 + Rn[7]*l1 + Rn[8]*l2 + t2);
  } else if (rem < 192) {
    int j = rem - 96, h = j >> 3, jj = j & 7;
    __hip_bfloat16* p = KE + (size_t)n*KE_COLS + h*64 + 32 + jj*3;
    float l0 = __bfloat162float(p[0]), l1 = __bfloat162float(p[1]), l2 = __bfloat162float(p[2]);
    p[0] = __float2bfloat16(Rn[0]*l0 + Rn[1]*l1 + Rn[2]*l2 + t0);
    p[1] = __float2bfloat16(Rn[3]*l0 + Rn[4]*l1 + Rn[5]*l2 + t1);
    p[2] = __float2bfloat16(Rn[6]*l0 + Rn[7]*l1 + Rn[8]*l2 + t2);
  } else {
    __hip_bfloat16* p = VE + (size_t)n*VE_COLS + 384 + (rem-192)*3;
    float l0 = __bfloat162float(p[0]), l1 = __bfloat162float(p[1]), l2 = __bfloat162float(p[2]);
    p[0] = __float2bfloat16(Rn[0]*l0 + Rn[1]*l1 + Rn[2]*l2 + t0);
    p[1] = __float2bfloat16(Rn[3]*l0 + Rn[4]*l1 + Rn[5]*l2 + t1);
    p[2] = __float2bfloat16(Rn[6]*l0 + Rn[7]*l1 + Rn[8]*l2 + t2);
  }
}

// ---------------- CSR build
__global__ void count_edges(const int* __restrict__ ei, int* __restrict__ cnt)
{
  int e = blockIdx.x*256 + threadIdx.x;
  if (e < EE) atomicAdd(&cnt[ei[e]], 1);
}

__global__ __launch_bounds__(1024) void scan_csr(const int* __restrict__ cnt,
                                                 int* __restrict__ rowptr,
                                                 int* __restrict__ cursor)
{
  __shared__ int part[1024];
  int t = threadIdx.x;
  int base = t*20;
  int loc[20];
  int s = 0;
  #pragma unroll
  for (int i = 0; i < 20; i++) {
    int idx = base + i;
    int cc = (idx < NN) ? cnt[idx] : 0;
    loc[i] = s; s += cc;
  }
  part[t] = s;
  __syncthreads();
  for (int off = 1; off < 1024; off <<= 1) {
    int v = (t >= off) ? part[t-off] : 0;
    __syncthreads();
    part[t] += v;
    __syncthreads();
  }
  int pre = (t == 0) ? 0 : part[t-1];
  #pragma unroll
  for (int i = 0; i < 20; i++) {
    int idx = base + i;
    if (idx < NN) { rowptr[idx] = pre + loc[i]; cursor[idx] = pre + loc[i]; }
  }
  if (t == 1023) rowptr[NN] = part[1023];
}

__global__ void fill_csr(const int* __restrict__ ei, int* __restrict__ cursor,
                         int* __restrict__ eidx)
{
  int e = blockIdx.x*256 + threadIdx.x;
  if (e >= EE) return;
  int pos = atomicAdd(&cursor[ei[e]], 1);
  eidx[pos] = e;
}

// ---------------- fill KE pad slots: 56->0, 57->1, 58->skkp_hi, 59->skkp_res, 60..63->0
__global__ __launch_bounds__(256) void build_skkp(
    __hip_bfloat16* __restrict__ KE, const float* __restrict__ spc)
{
  __shared__ float skk[12], cfb[12];
  const int n = blockIdx.x, t = threadIdx.x;
  if (t < 12) { cfb[t] = log1pf(expf(spc[t])) * (1.f/12.f); skk[t] = 0.f; }
  __syncthreads();
  for (int s = t; s < 288; s += 256) {
    int h = s / 24, j = s - 24*h;
    float v = __bfloat162float(KE[(size_t)n*KE_COLS + h*64 + 32 + j]);
    atomicAdd(&skk[h], v*v);
  }
  __syncthreads();
  if (t < 96) {
    int h = t >> 3, i = t & 7;    // pad slot 56+i of head h
    float skkp = -0.57735026919f * cfb[h] * skk[h];
    __hip_bfloat16 hi = __float2bfloat16(skkp);
    float res = skkp - __bfloat162float(hi);
    __hip_bfloat16 outv;
    if (i == 1)      outv = __float2bfloat16(1.0f);
    else if (i == 2) outv = hi;
    else if (i == 3) outv = __float2bfloat16(res);
    else             outv = __float2bfloat16(0.0f);
    KE[(size_t)n*KE_COLS + h*64 + 56 + i] = outv;
  }
}

__device__ __forceinline__ float dot8(const float* qr, uint4 v) {
  float s;
  s  = qr[0]*b2f((unsigned short)(v.x & 0xffffu));
  s += qr[1]*b2f((unsigned short)(v.x >> 16));
  s += qr[2]*b2f((unsigned short)(v.y & 0xffffu));
  s += qr[3]*b2f((unsigned short)(v.y >> 16));
  s += qr[4]*b2f((unsigned short)(v.z & 0xffffu));
  s += qr[5]*b2f((unsigned short)(v.z >> 16));
  s += qr[6]*b2f((unsigned short)(v.w & 0xffffu));
  s += qr[7]*b2f((unsigned short)(v.w >> 16));
  return s;
}

// ---------------- fused attention: logits + online softmax + vectorized aggregation
template<typename TA, typename TP>
__global__ __launch_bounds__(256) void attn_fused(
    const TA* __restrict__ Pq, const TP* __restrict__ Pqp,
    const __hip_bfloat16* __restrict__ KE, const __hip_bfloat16* __restrict__ VE,
    const float* __restrict__ z, const int* __restrict__ ei,
    const float* __restrict__ Wpair, const float* __restrict__ spc,
    const int* __restrict__ rowptr, const int* __restrict__ eidx,
    const float* __restrict__ R, const float* __restrict__ tr,
    __hip_bfloat16* __restrict__ featB)
{
  __shared__ float wpT[12*33];
  __shared__ __hip_bfloat16 sZ[64][34];
  __shared__ float sLA[64][13];   // pair logits, later overwritten with weights
  __shared__ float sLB[64][13];   // KE-dot logits (incl. skkp + Aconst)
  __shared__ int   sD[64];
  __shared__ float cfs[12], mh[12], sh[12], rh[12], mch[12], sqq[12];
  __shared__ float sVE[3][672];
  __shared__ float sAgg[288];

  const int n = blockIdx.x, t = threadIdx.x;
  const int beg = rowptr[n], end = rowptr[n+1];
  const int lane = t & 63, wid = t >> 6;
  const float inv_sqrt3 = 0.57735026919f;

  if (t < 12) { cfs[t] = log1pf(expf(spc[t])) * (1.f/12.f); mh[t] = -1e30f; sh[t] = 0.f; sqq[t] = 0.f; }
  for (int i = t; i < 384; i += 256) {
    int c = i / 12, h = i - 12*c;
    wpT[h*33 + c] = Wpair[i] * inv_sqrt3;
  }
  __syncthreads();
  for (int s = t; s < 288; s += 256) {
    float v = ldp(&Pqp[(size_t)n*PQP_COLS + s]);   // qp global
    atomicAdd(&sqq[s/24], v*v);
  }
  __syncthreads();
  // per-lane Qe registers (no LDS):
  // slot i semantics: [ c1*q(32) | c2*cf*qp(24) | 0 | Aconst(57) | 1(58) | 1(59) | 0... ]
  float q0[8], q1[8];
  {
    const int i0 = (lane & 7) * 8;
    const int ha = lane >> 3;             // heads 0..7
    #pragma unroll
    for (int j = 0; j < 8; j++) {
      int i = i0 + j;
      float val = 0.f;
      if (i < 32)       val = 0.1020620726f * ldp(&Pq[(size_t)n*PQ_COLS + ha*32 + i]);
      else if (i < 56)  val = 1.15470053838f * cfs[ha] * ldp(&Pqp[(size_t)n*PQP_COLS + ha*24 + (i-32)]);
      else if (i == 57) val = -inv_sqrt3 * cfs[ha] * sqq[ha];
      else if (i == 58 || i == 59) val = 1.0f;
      q0[j] = val;
    }
    if (lane < 32) {
      const int hb = 8 + (lane >> 3);     // heads 8..11
      #pragma unroll
      for (int j = 0; j < 8; j++) {
        int i = i0 + j;
        float val = 0.f;
        if (i < 32)       val = 0.1020620726f * ldp(&Pq[(size_t)n*PQ_COLS + hb*32 + i]);
        else if (i < 56)  val = 1.15470053838f * cfs[hb] * ldp(&Pqp[(size_t)n*PQP_COLS + hb*24 + (i-32)]);
        else if (i == 57) val = -inv_sqrt3 * cfs[hb] * sqq[hb];
        else if (i == 58 || i == 59) val = 1.0f;
        q1[j] = val;
      }
    } else {
      #pragma unroll
      for (int j = 0; j < 8; j++) q1[j] = 0.f;
    }
  }

  // aggregation thread mappings
  const int h0 = t >> 5;                 // z heads 0..7
  const int h1 = 8 + (t >> 5);           // z heads 8..11 (t < 128)
  const int zc = t & 31;
  const int g   = t / 84;                // 0..3 (g==3: idle in VE loop)
  const int vth = t - g*84;
  const int s0  = vth*8;
  const int myh = (s0 < 384) ? (s0 >> 5) : ((s0 - 384) / 24);
  float a0 = 0.f, a1 = 0.f;
  float acc8[8] = {};

  for (int c0 = beg; c0 < end; c0 += 64) {
    const int cn = min(64, end - c0);
    __syncthreads();
    if (t < cn) sD[t] = ei[EE + eidx[c0 + t]];
    #pragma unroll
    for (int u = 0; u < 2; u++) {            // stage z rows as bf16
      int idx = t + 256*u;
      int j = idx >> 3, c4 = idx & 7;
      if (j < cn) {
        int e = eidx[c0 + j];
        float4 zz = ((const float4*)(z + (size_t)e*32))[c4];
        sZ[j][c4*4+0] = __float2bfloat16(zz.x);
        sZ[j][c4*4+1] = __float2bfloat16(zz.y);
        sZ[j][c4*4+2] = __float2bfloat16(zz.z);
        sZ[j][c4*4+3] = __float2bfloat16(zz.w);
      }
    }
    __syncthreads();
    // pair logits -> sLA
    #pragma unroll
    for (int u = 0; u < 3; u++) {
      int idx = t + 256*u;
      int q = idx / 12, h = idx - 12*q;
      if (q < cn) {
        float acc = 0.f;
        #pragma unroll
        for (int c = 0; c < 32; c++) acc += __bfloat162float(sZ[q][c]) * wpT[h*33 + c];
        sLA[q][h] = acc;
      }
    }
    // KE logits -> sLB (skkp + Aconst folded into the dot)
    #pragma unroll 2
    for (int q = wid; q < cn; q += 4) {
      int dst = sD[q];
      const uint4* ke = (const uint4*)(KE + (size_t)dst*KE_COLS);
      uint4 L0 = ke[lane];
      uint4 L1 = make_uint4(0,0,0,0);
      if (lane < 32) L1 = ke[64 + lane];
      float p0 = dot8(q0, L0);
      p0 += __shfl_xor(p0, 1); p0 += __shfl_xor(p0, 2); p0 += __shfl_xor(p0, 4);
      float p1 = dot8(q1, L1);
      p1 += __shfl_xor(p1, 1); p1 += __shfl_xor(p1, 2); p1 += __shfl_xor(p1, 4);
      if ((lane & 7) == 0) {
        sLB[q][lane >> 3] = p0;
        if (lane < 32) sLB[q][8 + (lane >> 3)] = p1;
      }
    }
    __syncthreads();
    // chunk max per head
    if (t < 192) {
      int h = t >> 4, i = t & 15;
      float mx = -1e30f;
      for (int q = i; q < cn; q += 16) mx = fmaxf(mx, sLA[q][h] + sLB[q][h]);
      #pragma unroll
      for (int m2 = 8; m2 >= 1; m2 >>= 1) mx = fmaxf(mx, __shfl_xor(mx, m2));
      if (i == 0) mch[h] = mx;
    }
    __syncthreads();
    if (t < 12) {
      float mn = fmaxf(mh[t], mch[t]);
      rh[t] = expf(mh[t] - mn);
      mh[t] = mn;
    }
    __syncthreads();
    // weights (overwrite sLA) + running sum
    if (t < 192) {
      int h = t >> 4, i = t & 15;
      float ps = 0.f;
      for (int q = i; q < cn; q += 16) {
        float w = expf(sLA[q][h] + sLB[q][h] - mh[h]);
        sLA[q][h] = w;
        ps += w;
      }
      #pragma unroll
      for (int m2 = 8; m2 >= 1; m2 >>= 1) ps += __shfl_xor(ps, m2);
      if (i == 0) sh[h] = sh[h]*rh[h] + ps;
    }
    __syncthreads();
    // rescale + aggregate
    a0 *= rh[h0];
    if (t < 128) a1 *= rh[h1];
    for (int q = 0; q < cn; q++) {
      float zv = __bfloat162float(sZ[q][zc]);
      a0 += sLA[q][h0] * zv;
      if (t < 128) a1 += sLA[q][h1] * zv;
    }
    if (g < 3) {
      #pragma unroll
      for (int j = 0; j < 8; j++) acc8[j] *= rh[myh];
      #pragma unroll 4
      for (int qq = g; qq < cn; qq += 3) {
        float w = sLA[qq][myh];
        const uint4* ve = (const uint4*)(VE + (size_t)sD[qq]*VE_COLS);
        uint4 L = ve[vth];
        acc8[0] += w * b2f((unsigned short)(L.x & 0xffffu));
        acc8[1] += w * b2f((unsigned short)(L.x >> 16));
        acc8[2] += w * b2f((unsigned short)(L.y & 0xffffu));
        acc8[3] += w * b2f((unsigned short)(L.y >> 16));
        acc8[4] += w * b2f((unsigned short)(L.z & 0xffffu));
        acc8[5] += w * b2f((unsigned short)(L.z >> 16));
        acc8[6] += w * b2f((unsigned short)(L.w & 0xffffu));
        acc8[7] += w * b2f((unsigned short)(L.w >> 16));
      }
    }
  }
  __syncthreads();
  if (t < 12) rh[t] = (sh[t] > 0.f) ? 1.f/sh[t] : 0.f;
  __syncthreads();
  __hip_bfloat16* fr = featB + (size_t)n*FCOLS;
  a0 *= rh[h0];
  fr[t] = __float2bfloat16(a0);
  if (t < 128) { a1 *= rh[h1]; fr[256 + t] = __float2bfloat16(a1); }
  if (g < 3) {
    #pragma unroll
    for (int j = 0; j < 8; j++) sVE[g][s0 + j] = acc8[j] * rh[myh];
  }
  __syncthreads();
  for (int s = t; s < 672; s += 256) {
    float tot = sVE[0][s] + sVE[1][s] + sVE[2][s];
    if (s < 384) fr[384 + s] = __float2bfloat16(tot);
    else sAgg[s - 384] = tot;
  }
  __syncthreads();
  if (t < 96) {
    int pt = t;
    const float* Rn = R + (size_t)n*9;
    float d0 = sAgg[pt*3+0] - tr[n*3+0];
    float d1 = sAgg[pt*3+1] - tr[n*3+1];
    float d2 = sAgg[pt*3+2] - tr[n*3+2];
    float l0 = Rn[0]*d0 + Rn[3]*d1 + Rn[6]*d2;
    float l1 = Rn[1]*d0 + Rn[4]*d1 + Rn[7]*d2;
    float l2 = Rn[2]*d0 + Rn[5]*d1 + Rn[8]*d2;
    float nr = sqrtf(l0*l0 + l1*l1 + l2*l2);
    float inv = 1.f / fmaxf(nr, 1e-8f);
    fr[768 + pt*3+0] = __float2bfloat16(l0);
    fr[768 + pt*3+1] = __float2bfloat16(l1);
    fr[768 + pt*3+2] = __float2bfloat16(l2);
    fr[1056 + pt]    = __float2bfloat16(nr);
    fr[1152 + pt*3+0] = __float2bfloat16(l0*inv);
    fr[1152 + pt*3+1] = __float2bfloat16(l1*inv);
    fr[1152 + pt*3+2] = __float2bfloat16(l2*inv);
  }
}

// ---------------- xo = x + featB @ Wo + bo   (32x128 tile, 4x4 register block)
__global__ __launch_bounds__(256) void wo_gemm(
    const __hip_bfloat16* __restrict__ featB, const float* __restrict__ Wo,
    const float* __restrict__ bo, const float* __restrict__ x, float* __restrict__ xo)
{
  __shared__ float Ast[32][36];
  __shared__ float Bs[32][132];
  const int t = threadIdx.x;
  const int n0 = blockIdx.x * 32;
  const int tx = t & 31, ty = t >> 5;
  const int cl = t & 127, kset = t >> 7;
  float acc[4][4] = {};
  const int ar = t >> 3, akc = (t & 7) * 4;
  for (int k0 = 0; k0 < FCOLS; k0 += 32) {
    {
      const __hip_bfloat16* ap = featB + (size_t)(n0 + ar)*FCOLS + k0 + akc;
      short4 raw = *(const short4*)(const void*)ap;
      Ast[akc+0][ar] = b2f((unsigned short)raw.x);
      Ast[akc+1][ar] = b2f((unsigned short)raw.y);
      Ast[akc+2][ar] = b2f((unsigned short)raw.z);
      Ast[akc+3][ar] = b2f((unsigned short)raw.w);
    }
    #pragma unroll
    for (int u = 0; u < 16; u++) {
      int kk = kset + 2*u;
      Bs[kk][cl] = Wo[(size_t)(k0 + kk)*128 + cl];
    }
    __syncthreads();
    #pragma unroll
    for (int kk = 0; kk < 32; kk++) {
      float4 a4 = *(const float4*)&Ast[kk][ty*4];
      float4 b4 = *(const float4*)&Bs[kk][tx*4];
      float av[4] = {a4.x, a4.y, a4.z, a4.w};
      float bv[4] = {b4.x, b4.y, b4.z, b4.w};
      #pragma unroll
      for (int i2 = 0; i2 < 4; i2++)
        #pragma unroll
        for (int j2 = 0; j2 < 4; j2++)
          acc[i2][j2] += av[i2] * bv[j2];
    }
    __syncthreads();
  }
  const int gc = tx*4;
  #pragma unroll
  for (int i2 = 0; i2 < 4; i2++) {
    int r = n0 + ty*4 + i2;
    float4 xr = *(const float4*)&x[(size_t)r*128 + gc];
    float xv[4] = {xr.x, xr.y, xr.z, xr.w};
    #pragma unroll
    for (int j2 = 0; j2 < 4; j2++)
      xo[(size_t)r*128 + gc + j2] = acc[i2][j2] + bo[gc + j2] + xv[j2];
  }
}

// ---------------- LN1 -> MLP -> residual -> LN2, 32 rows/block, 4x4 micro-GEMM
__global__ __launch_bounds__(256) void lnmlp2(
    const float* __restrict__ xo,
    const float* __restrict__ g1, const float* __restrict__ b1v,
    const float* __restrict__ w1, const float* __restrict__ bb1,
    const float* __restrict__ w2, const float* __restrict__ bb2,
    const float* __restrict__ w3, const float* __restrict__ bb3,
    const float* __restrict__ g2, const float* __restrict__ b2v,
    float* __restrict__ out)
{
  __shared__ float smem[17344];
  float* hs   = smem;           // 32 x 132 (LN1 output, kept for residual)
  float* AT   = smem + 4224;    // 128 x 36 (transposed A panel)
  float* bA   = smem + 8832;    // 32 x 132
  float* bB   = smem + 13056;   // 32 x 132
  float* mu_s = smem + 17280;   // 32
  float* rs_s = smem + 17312;   // 32

  const int t = threadIdx.x, n0 = blockIdx.x * 32;
  const int tx = t & 31, ty = t >> 5;
  const int c = t & 127, rhalf = t >> 7;
  const int w = t >> 6, lane = t & 63;

  for (int e = t; e < 4096; e += 256) {
    int r = e >> 7, cc = e & 127;
    hs[r*132 + cc] = xo[(size_t)(n0 + r)*128 + cc];
  }
  __syncthreads();
  // LN1 stats: wave w handles rows w*8..w*8+7
  for (int q = 0; q < 8; q++) {
    int r = w*8 + q;
    float v0 = hs[r*132 + lane], v1 = hs[r*132 + lane + 64];
    float s = v0 + v1, ss = v0*v0 + v1*v1;
    #pragma unroll
    for (int m2 = 32; m2 >= 1; m2 >>= 1) { s += __shfl_xor(s, m2); ss += __shfl_xor(ss, m2); }
    if (lane == 0) { float mu = s*(1.f/128.f); mu_s[r] = mu; rs_s[r] = rsqrtf(ss*(1.f/128.f) - mu*mu + 1e-5f); }
  }
  __syncthreads();
  for (int r = rhalf; r < 32; r += 2)
    hs[r*132 + c] = (hs[r*132 + c] - mu_s[r]) * rs_s[r] * g1[c] + b1v[c];
  __syncthreads();

#define MLP_LAYER(INB, OUTB, WG, BG, DO_RELU, DO_RES)                          \
  {                                                                            \
    for (int e = t; e < 4096; e += 256) {                                      \
      int kk = e >> 5, r = e & 31;                                             \
      AT[kk*36 + r] = INB[r*132 + kk];                                         \
    }                                                                          \
    __syncthreads();                                                           \
    float acc[4][4] = {};                                                      \
    const float4* Wg4 = (const float4*)(WG);                                   \
    for (int kk = 0; kk < 128; kk++) {                                         \
      float4 a4 = *(const float4*)&AT[kk*36 + ty*4];                           \
      float4 b4 = Wg4[kk*32 + tx];                                             \
      float av[4] = {a4.x, a4.y, a4.z, a4.w};                                  \
      float bv[4] = {b4.x, b4.y, b4.z, b4.w};                                  \
      _Pragma("unroll")                                                        \
      for (int i2 = 0; i2 < 4; i2++)                                           \
        _Pragma("unroll")                                                      \
        for (int j2 = 0; j2 < 4; j2++)                                         \
          acc[i2][j2] += av[i2] * bv[j2];                                      \
    }                                                                          \
    _Pragma("unroll")                                                          \
    for (int i2 = 0; i2 < 4; i2++) {                                           \
      int r = ty*4 + i2;                                                       \
      _Pragma("unroll")                                                        \
      for (int j2 = 0; j2 < 4; j2++) {                                         \
        int cc2 = tx*4 + j2;                                                   \
        float v = acc[i2][j2] + BG[cc2];                                       \
        if (DO_RES) v += hs[r*132 + cc2];                                      \
        OUTB[r*132 + cc2] = DO_RELU ? fmaxf(v, 0.f) : v;                       \
      }                                                                        \
    }                                                                          \
    __syncthreads();                                                           \
  }

  MLP_LAYER(hs, bA, w1, bb1, 1, 0)
  MLP_LAYER(bA, bB, w2, bb2, 1, 0)
  MLP_LAYER(bB, bA, w3, bb3, 0, 1)
#undef MLP_LAYER

  // LN2 on bA
  for (int q = 0; q < 8; q++) {
    int r = w*8 + q;
    float v0 = bA[r*132 + lane], v1 = bA[r*132 + lane + 64];
    float s = v0 + v1, ss = v0*v0 + v1*v1;
    #pragma unroll
    for (int m2 = 32; m2 >= 1; m2 >>= 1) { s += __shfl_xor(s, m2); ss += __shfl_xor(ss, m2); }
    if (lane == 0) { float mu = s*(1.f/128.f); mu_s[r] = mu; rs_s[r] = rsqrtf(ss*(1.f/128.f) - mu*mu + 1e-5f); }
  }
  __syncthreads();
  for (int r = rhalf; r < 32; r += 2)
    out[(size_t)(n0 + r)*128 + c] = (bA[r*132 + c] - mu_s[r]) * rs_s[r] * g2[c] + b2v[c];
}

__global__ void diag_ws(float* out, float v)
{
  if (blockIdx.x == 0 && threadIdx.x == 0) out[0] = v;
}

// ---------------- host side ----------------
struct Args {
  const float *R, *tr, *x, *z, *Wq, *Wk, *Wv, *Wpair, *spc, *Wqp, *Wkp, *Wvp;
  const float *Wo, *bo, *g1, *b1v, *w1, *bb1, *w2, *bb2, *w3, *bb3, *g2, *b2v;
  const int* ei;
  float* out;
};

static inline size_t alup(size_t v) { return (v + 255) & ~(size_t)255; }

template<typename TA, typename TP>
static void run_all(const Args& a, char* ws, hipStream_t stream)
{
  size_t off = 0;
  TA* Pq = (TA*)(ws + off);          off += alup((size_t)NN*PQ_COLS*sizeof(TA));
  TP* Pqp = (TP*)(ws + off);         off += alup((size_t)NN*PQP_COLS*sizeof(TP));
  __hip_bfloat16* VE = (__hip_bfloat16*)(ws + off); off += alup((size_t)NN*VE_COLS*2);
  __hip_bfloat16* KE = (__hip_bfloat16*)(ws + off); off += alup((size_t)NN*KE_COLS*2);
  int* cnt = (int*)(ws + off);       off += alup((size_t)NN*sizeof(int));
  int* rowptr = (int*)(ws + off);    off += alup((size_t)(NN+1)*sizeof(int));
  int* cursor = (int*)(ws + off);    off += alup((size_t)NN*sizeof(int));
  int* eidx = (int*)(ws + off);      off += alup((size_t)EE*sizeof(int));
  __hip_bfloat16* featB = (__hip_bfloat16*)(ws + off);
  float* xo = a.out;   // alias output buffer for the pre-LN activations

  hipMemsetAsync(cnt, 0, (size_t)NN*sizeof(int), stream);

  proj_gemm<TA,TP><<<dim3(NN/32, 16), 256, 0, stream>>>(a.x, a.Wq, a.Wk, a.Wv, a.Wqp, a.Wkp, a.Wvp,
                                                        Pq, Pqp, KE, VE);
  transform_pts<TP><<<(NN*288)/256, 256, 0, stream>>>(a.R, a.tr, Pqp, KE, VE);
  count_edges<<<EE/256, 256, 0, stream>>>(a.ei, cnt);
  scan_csr<<<1, 1024, 0, stream>>>(cnt, rowptr, cursor);
  fill_csr<<<EE/256, 256, 0, stream>>>(a.ei, cursor, eidx);
  build_skkp<<<NN, 256, 0, stream>>>(KE, a.spc);
  attn_fused<TA,TP><<<NN, 256, 0, stream>>>(Pq, Pqp, KE, VE, a.z, a.ei, a.Wpair, a.spc,
                                            rowptr, eidx, a.R, a.tr, featB);
  wo_gemm<<<NN/32, 256, 0, stream>>>(featB, a.Wo, a.bo, a.x, xo);
  lnmlp2<<<NN/32, 256, 0, stream>>>(xo, a.g1, a.b1v, a.w1, a.bb1, a.w2, a.bb2,
                                    a.w3, a.bb3, a.g2, a.b2v, a.out);
}

extern "C" void kernel_launch(void* const* d_in, const int* in_sizes, int n_in,
                              void* d_out, int out_size, void* d_ws, size_t ws_size,
                              hipStream_t stream)
{
  Args a;
  a.R     = (const float*)d_in[0];
  a.tr    = (const float*)d_in[1];
  a.x     = (const float*)d_in[2];
  a.z     = (const float*)d_in[3];
  a.ei    = (const int*)  d_in[4];
  a.Wq    = (const float*)d_in[5];
  a.Wk    = (const float*)d_in[6];
  a.Wv    = (const float*)d_in[7];
  a.Wpair = (const float*)d_in[8];
  a.spc   = (const float*)d_in[9];
  a.Wqp   = (const float*)d_in[10];
  a.Wkp   = (const float*)d_in[11];
  a.Wvp   = (const float*)d_in[12];
  a.Wo    = (const float*)d_in[13];
  a.bo    = (const float*)d_in[14];
  a.g1    = (const float*)d_in[15];
  a.b1v   = (const float*)d_in[16];
  a.w1    = (const float*)d_in[17];
  a.bb1   = (const float*)d_in[18];
  a.w2    = (const float*)d_in[19];
  a.bb2   = (const float*)d_in[20];
  a.w3    = (const float*)d_in[21];
  a.bb3   = (const float*)d_in[22];
  a.g2    = (const float*)d_in[23];
  a.b2v   = (const float*)d_in[24];
  a.out   = (float*)d_out;

  size_t common = alup((size_t)NN*VE_COLS*2) + alup((size_t)NN*KE_COLS*2) +
                  alup((size_t)NN*4)*2 + alup((size_t)(NN+1)*4) + alup((size_t)EE*4) +
                  alup((size_t)NN*FCOLS*2);
  size_t needA = alup((size_t)NN*PQ_COLS*4) + alup((size_t)NN*PQP_COLS*4) + common;
  size_t needB = alup((size_t)NN*PQ_COLS*2) + alup((size_t)NN*PQP_COLS*4) + common;
  size_t needC = alup((size_t)NN*PQ_COLS*2) + alup((size_t)NN*PQP_COLS*2) + common;

  if (ws_size >= needA)      run_all<float, float>(a, (char*)d_ws, stream);
  else if (ws_size >= needB) run_all<__hip_bfloat16, float>(a, (char*)d_ws, stream);
  else if (ws_size >= needC) run_all<__hip_bfloat16, __hip_bfloat16>(a, (char*)d_ws, stream);
  else diag_ws<<<1, 64, 0, stream>>>((float*)d_out, (float)((double)ws_size / (1024.0*1024.0)));
}

// Round 8
// 806.436 us; speedup vs baseline: 1.2044x; 1.2044x over previous
//
#include <hip/hip_runtime.h>
#include <hip/hip_bf16.h>
#include <math.h>

#define NN 20000
#define EE 320000
#define PQ_COLS  384    // q (f32 panel, dead after build_qe)
#define PQP_COLS 288    // qp (f32, global after transform, dead after build_qe)
#define PKP_COLS 288    // kp local (f32, dead after transform)
#define QE_COLS  768    // 12 heads x 64 bf16: [c1*q 32 | c2*cf*qp 24 | 0 x8]
#define VE_COLS  672    // [v 384 | vp 288] bf16
#define KE_COLS  768    // 12 heads x 64 bf16: [k 32 | kp_global 24 | 0 x8]
#define FCOLS 1440      // [p2n 384 | node 384 | loc 288 | nrm 96 | dirn 288]

__device__ __forceinline__ float b2f(unsigned short u) {
  return __uint_as_float(((unsigned)u) << 16);
}

template<typename PT> __device__ __forceinline__ float ldp(const PT* p);
template<> __device__ __forceinline__ float ldp<float>(const float* p) { return *p; }
template<> __device__ __forceinline__ float ldp<__hip_bfloat16>(const __hip_bfloat16* p) { return __bfloat162float(*p); }
template<typename PT> __device__ __forceinline__ void stp(PT* p, float v);
template<> __device__ __forceinline__ void stp<float>(float* p, float v) { *p = v; }
template<> __device__ __forceinline__ void stp<__hip_bfloat16>(__hip_bfloat16* p, float v) { *p = __float2bfloat16(v); }

// ---------------- projections: x @ [Wq|Wk|Wv|Wqp|Wkp|Wvp]
//   -> Pq f32 | KE.k bf16 | VE.v bf16 | Pqp f32 | Pkp f32 | VE.vp bf16(local)
template<typename TA, typename TP>
__global__ __launch_bounds__(256) void proj_gemm(
    const float* __restrict__ x,
    const float* __restrict__ Wq, const float* __restrict__ Wk, const float* __restrict__ Wv,
    const float* __restrict__ Wqp, const float* __restrict__ Wkp, const float* __restrict__ Wvp,
    TA* __restrict__ Pq, TP* __restrict__ Pqp, TP* __restrict__ Pkp,
    __hip_bfloat16* __restrict__ KE, __hip_bfloat16* __restrict__ VE)
{
  __shared__ float Ast[32][36];
  __shared__ float Bs[32][132];
  const int t = threadIdx.x;
  const int n0 = blockIdx.x * 32;
  const int c0 = blockIdx.y * 128;
  const int tx = t & 31, ty = t >> 5;
  const int cl = t & 127, kset = t >> 7;
  const int c = c0 + cl;
  const float* wcol = nullptr; int wstr = 0;
  if      (c < 384)  { wcol = Wq  + c;        wstr = 384; }
  else if (c < 768)  { wcol = Wk  + (c-384);  wstr = 384; }
  else if (c < 1152) { wcol = Wv  + (c-768);  wstr = 384; }
  else if (c < 1440) { wcol = Wqp + (c-1152); wstr = 288; }
  else if (c < 1728) { wcol = Wkp + (c-1440); wstr = 288; }
  else if (c < 2016) { wcol = Wvp + (c-1728); wstr = 288; }
  float acc[4][4] = {};
  const int ar = t >> 3, akc = (t & 7) * 4;
  for (int k0 = 0; k0 < 128; k0 += 32) {
    float4 av4 = *(const float4*)&x[(size_t)(n0 + ar)*128 + k0 + akc];
    Ast[akc+0][ar] = av4.x; Ast[akc+1][ar] = av4.y;
    Ast[akc+2][ar] = av4.z; Ast[akc+3][ar] = av4.w;
    #pragma unroll
    for (int u = 0; u < 16; u++) {
      int kk = kset + 2*u;
      Bs[kk][cl] = wcol ? wcol[(size_t)(k0 + kk)*wstr] : 0.f;
    }
    __syncthreads();
    #pragma unroll
    for (int kk = 0; kk < 32; kk++) {
      float4 a4 = *(const float4*)&Ast[kk][ty*4];
      float4 b4 = *(const float4*)&Bs[kk][tx*4];
      float av[4] = {a4.x, a4.y, a4.z, a4.w};
      float bv[4] = {b4.x, b4.y, b4.z, b4.w};
      #pragma unroll
      for (int i2 = 0; i2 < 4; i2++)
        #pragma unroll
        for (int j2 = 0; j2 < 4; j2++)
          acc[i2][j2] += av[i2] * bv[j2];
    }
    __syncthreads();
  }
  const int gc = c0 + tx*4;
  #pragma unroll
  for (int i2 = 0; i2 < 4; i2++) {
    int r = n0 + ty*4 + i2;
    if (gc < 384) {
      TA* dp = Pq + (size_t)r*PQ_COLS + gc;
      #pragma unroll
      for (int j2 = 0; j2 < 4; j2++) stp(&dp[j2], acc[i2][j2]);
    } else if (gc < 768) {                 // k -> KE slots
      int d = gc - 384, h = d >> 5, i = d & 31;
      __hip_bfloat16* dp = KE + (size_t)r*KE_COLS + h*64 + i;
      #pragma unroll
      for (int j2 = 0; j2 < 4; j2++) dp[j2] = __float2bfloat16(acc[i2][j2]);
    } else if (gc < 1152) {                // v -> VE[0..383]
      __hip_bfloat16* dp = VE + (size_t)r*VE_COLS + (gc - 768);
      #pragma unroll
      for (int j2 = 0; j2 < 4; j2++) dp[j2] = __float2bfloat16(acc[i2][j2]);
    } else if (gc < 1440) {                // qp (local) f32
      TP* dp = Pqp + (size_t)r*PQP_COLS + (gc - 1152);
      #pragma unroll
      for (int j2 = 0; j2 < 4; j2++) stp(&dp[j2], acc[i2][j2]);
    } else if (gc < 1728) {                // kp (local) f32
      TP* dp = Pkp + (size_t)r*PKP_COLS + (gc - 1440);
      #pragma unroll
      for (int j2 = 0; j2 < 4; j2++) stp(&dp[j2], acc[i2][j2]);
    } else {                               // vp (local) -> VE[384..671]
      __hip_bfloat16* dp = VE + (size_t)r*VE_COLS + 384 + (gc - 1728);
      #pragma unroll
      for (int j2 = 0; j2 < 4; j2++) if (gc + j2 < 2016) dp[j2] = __float2bfloat16(acc[i2][j2]);
    }
  }
}

// ---------------- point transform: qp in place (f32); kp: Pkp f32 -> KE bf16 (single rounding); vp: VE RMW
template<typename TP>
__global__ void transform_pts(const float* __restrict__ R, const float* __restrict__ tr,
                              TP* __restrict__ Pqp, const TP* __restrict__ Pkp,
                              __hip_bfloat16* __restrict__ KE, __hip_bfloat16* __restrict__ VE)
{
  int idx = blockIdx.x*256 + threadIdx.x;   // N * 288 point-triples
  if (idx >= NN*288) return;
  int n = idx / 288, rem = idx - n*288;
  const float* Rn = R + (size_t)n*9;
  float t0 = tr[n*3], t1 = tr[n*3+1], t2 = tr[n*3+2];
  if (rem < 96) {
    TP* p = Pqp + (size_t)n*PQP_COLS + rem*3;
    float l0 = ldp(p), l1 = ldp(p+1), l2 = ldp(p+2);
    stp(p,   Rn[0]*l0 + Rn[1]*l1 + Rn[2]*l2 + t0);
    stp(p+1, Rn[3]*l0 + Rn[4]*l1 + Rn[5]*l2 + t1);
    stp(p+2, Rn[6]*l0 + Rn[7]*l1 + Rn[8]*l2 + t2);
  } else if (rem < 192) {
    int j = rem - 96, h = j >> 3, jj = j & 7;
    const TP* p = Pkp + (size_t)n*PKP_COLS + h*24 + jj*3;
    float l0 = ldp(p), l1 = ldp(p+1), l2 = ldp(p+2);
    __hip_bfloat16* o = KE + (size_t)n*KE_COLS + h*64 + 32 + jj*3;
    o[0] = __float2bfloat16(Rn[0]*l0 + Rn[1]*l1 + Rn[2]*l2 + t0);
    o[1] = __float2bfloat16(Rn[3]*l0 + Rn[4]*l1 + Rn[5]*l2 + t1);
    o[2] = __float2bfloat16(Rn[6]*l0 + Rn[7]*l1 + Rn[8]*l2 + t2);
  } else {
    __hip_bfloat16* p = VE + (size_t)n*VE_COLS + 384 + (rem-192)*3;
    float l0 = __bfloat162float(p[0]), l1 = __bfloat162float(p[1]), l2 = __bfloat162float(p[2]);
    p[0] = __float2bfloat16(Rn[0]*l0 + Rn[1]*l1 + Rn[2]*l2 + t0);
    p[1] = __float2bfloat16(Rn[3]*l0 + Rn[4]*l1 + Rn[5]*l2 + t1);
    p[2] = __float2bfloat16(Rn[6]*l0 + Rn[7]*l1 + Rn[8]*l2 + t2);
  }
}

// ---------------- build QE panel (bf16): [c1*q | 2*cf*sqrt(1/3)*qp | 0 x8] per head.
// Sum(qp^2) term is constant per (src,h) and cancels in softmax -> dropped.
template<typename TA, typename TP>
__global__ __launch_bounds__(256) void build_qe(
    const TA* __restrict__ Pq, const TP* __restrict__ Pqp,
    const float* __restrict__ spc, __hip_bfloat16* __restrict__ QE)
{
  __shared__ float cfs[12];
  const int n = blockIdx.x, t = threadIdx.x;
  if (t < 12) cfs[t] = log1pf(expf(spc[t])) * (1.f/12.f);
  __syncthreads();
  #pragma unroll
  for (int u = 0; u < 3; u++) {
    int s = t + 256*u;
    int h = s >> 6, i = s & 63;
    float val = 0.f;
    if (i < 32)      val = 0.1020620726f * ldp(&Pq[(size_t)n*PQ_COLS + h*32 + i]);
    else if (i < 56) val = 1.15470053838f * cfs[h] * ldp(&Pqp[(size_t)n*PQP_COLS + h*24 + (i-32)]);
    QE[(size_t)n*QE_COLS + s] = __float2bfloat16(val);
  }
}

// ---------------- SKKP[n*12+h] = -sqrt(1/3)*cf_h*sum(kp_global^2); zero KE pad slots
__global__ __launch_bounds__(256) void build_skkp(
    __hip_bfloat16* __restrict__ KE, const float* __restrict__ spc, float* __restrict__ SKKP)
{
  __shared__ float skk[12], cfb[12];
  const int n = blockIdx.x, t = threadIdx.x;
  if (t < 12) { cfb[t] = log1pf(expf(spc[t])) * (1.f/12.f); skk[t] = 0.f; }
  __syncthreads();
  for (int s = t; s < 288; s += 256) {
    int h = s / 24, j = s - 24*h;
    float v = __bfloat162float(KE[(size_t)n*KE_COLS + h*64 + 32 + j]);
    atomicAdd(&skk[h], v*v);
  }
  __syncthreads();
  if (t < 96) {
    int h = t >> 3, i = t & 7;
    KE[(size_t)n*KE_COLS + h*64 + 56 + i] = __float2bfloat16(0.0f);
    if (i == 0) SKKP[(size_t)n*12 + h] = -0.57735026919f * cfb[h] * skk[h];
  }
}

// ---------------- CSR build
__global__ void count_edges(const int* __restrict__ ei, int* __restrict__ cnt)
{
  int e = blockIdx.x*256 + threadIdx.x;
  if (e < EE) atomicAdd(&cnt[ei[e]], 1);
}

__global__ __launch_bounds__(1024) void scan_csr(const int* __restrict__ cnt,
                                                 int* __restrict__ rowptr,
                                                 int* __restrict__ cursor)
{
  __shared__ int part[1024];
  int t = threadIdx.x;
  int base = t*20;
  int loc[20];
  int s = 0;
  #pragma unroll
  for (int i = 0; i < 20; i++) {
    int idx = base + i;
    int cc = (idx < NN) ? cnt[idx] : 0;
    loc[i] = s; s += cc;
  }
  part[t] = s;
  __syncthreads();
  for (int off = 1; off < 1024; off <<= 1) {
    int v = (t >= off) ? part[t-off] : 0;
    __syncthreads();
    part[t] += v;
    __syncthreads();
  }
  int pre = (t == 0) ? 0 : part[t-1];
  #pragma unroll
  for (int i = 0; i < 20; i++) {
    int idx = base + i;
    if (idx < NN) { rowptr[idx] = pre + loc[i]; cursor[idx] = pre + loc[i]; }
  }
  if (t == 1023) rowptr[NN] = part[1023];
}

__global__ void fill_csr(const int* __restrict__ ei, int* __restrict__ cursor,
                         int* __restrict__ eidx)
{
  int e = blockIdx.x*256 + threadIdx.x;
  if (e >= EE) return;
  int pos = atomicAdd(&cursor[ei[e]], 1);
  eidx[pos] = e;
}

__device__ __forceinline__ float dot8(const float* qr, uint4 v) {
  float s;
  s  = qr[0]*b2f((unsigned short)(v.x & 0xffffu));
  s += qr[1]*b2f((unsigned short)(v.x >> 16));
  s += qr[2]*b2f((unsigned short)(v.y & 0xffffu));
  s += qr[3]*b2f((unsigned short)(v.y >> 16));
  s += qr[4]*b2f((unsigned short)(v.z & 0xffffu));
  s += qr[5]*b2f((unsigned short)(v.z >> 16));
  s += qr[6]*b2f((unsigned short)(v.w & 0xffffu));
  s += qr[7]*b2f((unsigned short)(v.w >> 16));
  return s;
}

// ---------------- fused attention (round-6 body + slim QE prologue)
__global__ __launch_bounds__(256) void attn_fused(
    const __hip_bfloat16* __restrict__ QE,
    const __hip_bfloat16* __restrict__ KE, const float* __restrict__ SKKP,
    const __hip_bfloat16* __restrict__ VE,
    const float* __restrict__ z, const int* __restrict__ ei,
    const float* __restrict__ Wpair,
    const int* __restrict__ rowptr, const int* __restrict__ eidx,
    const float* __restrict__ R, const float* __restrict__ tr,
    __hip_bfloat16* __restrict__ featB)
{
  __shared__ float wpT[12*33];
  __shared__ float sZ[64][33];
  __shared__ float sLA[64][13];   // pair-bias logits
  __shared__ float sLB[64][13];   // KE-dot logits (incl. skkp)
  __shared__ float sW[64][13];
  __shared__ int   sD[64];
  __shared__ float mh[12], sh[12], rh[12], mch[12];
  __shared__ float sVE[3][672];
  __shared__ float sAgg[288];

  const int n = blockIdx.x, t = threadIdx.x;
  const int beg = rowptr[n], end = rowptr[n+1];
  const int lane = t & 63, wid = t >> 6;
  const float inv_sqrt3 = 0.57735026919f;

  if (t < 12) { mh[t] = -1e30f; sh[t] = 0.f; }
  for (int i = t; i < 384; i += 256) {
    int c = i / 12, h = i - 12*c;
    wpT[h*33 + c] = Wpair[i] * inv_sqrt3;
  }
  // per-lane Qe registers from precomputed QE panel (coalesced uint4 loads)
  float q0[8], q1[8];
  {
    const uint4* qrow = (const uint4*)(QE + (size_t)n*QE_COLS);
    uint4 Q0 = qrow[lane];
    q0[0]=b2f((unsigned short)(Q0.x&0xffffu)); q0[1]=b2f((unsigned short)(Q0.x>>16));
    q0[2]=b2f((unsigned short)(Q0.y&0xffffu)); q0[3]=b2f((unsigned short)(Q0.y>>16));
    q0[4]=b2f((unsigned short)(Q0.z&0xffffu)); q0[5]=b2f((unsigned short)(Q0.z>>16));
    q0[6]=b2f((unsigned short)(Q0.w&0xffffu)); q0[7]=b2f((unsigned short)(Q0.w>>16));
    if (lane < 32) {
      uint4 Q1 = qrow[64 + lane];
      q1[0]=b2f((unsigned short)(Q1.x&0xffffu)); q1[1]=b2f((unsigned short)(Q1.x>>16));
      q1[2]=b2f((unsigned short)(Q1.y&0xffffu)); q1[3]=b2f((unsigned short)(Q1.y>>16));
      q1[4]=b2f((unsigned short)(Q1.z&0xffffu)); q1[5]=b2f((unsigned short)(Q1.z>>16));
      q1[6]=b2f((unsigned short)(Q1.w&0xffffu)); q1[7]=b2f((unsigned short)(Q1.w>>16));
    } else {
      #pragma unroll
      for (int j = 0; j < 8; j++) q1[j] = 0.f;
    }
  }

  // aggregation thread mappings
  const int h0 = t >> 5;                 // z heads 0..7
  const int h1 = 8 + (t >> 5);           // z heads 8..11 (t < 128)
  const int zc = t & 31;
  const int g   = t / 84;                // 0..3 (g==3: idle in VE loop)
  const int vth = t - g*84;
  const int s0  = vth*8;
  const int myh = (s0 < 384) ? (s0 >> 5) : ((s0 - 384) / 24);
  float a0 = 0.f, a1 = 0.f;
  float acc8[8] = {};

  for (int c0 = beg; c0 < end; c0 += 64) {
    const int cn = min(64, end - c0);
    __syncthreads();
    if (t < cn) sD[t] = ei[EE + eidx[c0 + t]];
    #pragma unroll
    for (int u = 0; u < 2; u++) {            // stage z rows f32
      int idx = t + 256*u;
      int j = idx >> 3, c4 = idx & 7;
      if (j < cn) {
        int e = eidx[c0 + j];
        float4 zz = ((const float4*)(z + (size_t)e*32))[c4];
        sZ[j][c4*4+0] = zz.x; sZ[j][c4*4+1] = zz.y;
        sZ[j][c4*4+2] = zz.z; sZ[j][c4*4+3] = zz.w;
      }
    }
    __syncthreads();
    // pair logits -> sLA
    #pragma unroll
    for (int u = 0; u < 3; u++) {
      int idx = t + 256*u;
      int q = idx / 12, h = idx - 12*q;
      if (q < cn) {
        float acc = 0.f;
        #pragma unroll
        for (int c = 0; c < 32; c++) acc += sZ[q][c] * wpT[h*33 + c];
        sLA[q][h] = acc;
      }
    }
    // KE logits -> sLB
    #pragma unroll 2
    for (int q = wid; q < cn; q += 4) {
      int dst = sD[q];
      const uint4* ke = (const uint4*)(KE + (size_t)dst*KE_COLS);
      uint4 L0 = ke[lane];
      uint4 L1 = make_uint4(0,0,0,0);
      if (lane < 32) L1 = ke[64 + lane];
      float bc0 = 0.f, bc1 = 0.f;
      if ((lane & 7) == 0) {
        bc0 = SKKP[(size_t)dst*12 + (lane >> 3)];
        if (lane < 32) bc1 = SKKP[(size_t)dst*12 + 8 + (lane >> 3)];
      }
      float p0 = dot8(q0, L0);
      p0 += __shfl_xor(p0, 1); p0 += __shfl_xor(p0, 2); p0 += __shfl_xor(p0, 4);
      float p1 = dot8(q1, L1);
      p1 += __shfl_xor(p1, 1); p1 += __shfl_xor(p1, 2); p1 += __shfl_xor(p1, 4);
      if ((lane & 7) == 0) {
        sLB[q][lane >> 3] = p0 + bc0;
        if (lane < 32) sLB[q][8 + (lane >> 3)] = p1 + bc1;
      }
    }
    __syncthreads();
    // chunk max per head
    if (t < 192) {
      int h = t >> 4, i = t & 15;
      float mx = -1e30f;
      for (int q = i; q < cn; q += 16) mx = fmaxf(mx, sLA[q][h] + sLB[q][h]);
      #pragma unroll
      for (int m2 = 8; m2 >= 1; m2 >>= 1) mx = fmaxf(mx, __shfl_xor(mx, m2));
      if (i == 0) mch[h] = mx;
    }
    __syncthreads();
    if (t < 12) {
      float mn = fmaxf(mh[t], mch[t]);
      rh[t] = expf(mh[t] - mn);
      mh[t] = mn;
    }
    __syncthreads();
    // weights + running sum
    if (t < 192) {
      int h = t >> 4, i = t & 15;
      float ps = 0.f;
      for (int q = i; q < cn; q += 16) {
        float w = expf(sLA[q][h] + sLB[q][h] - mh[h]);
        sW[q][h] = w;
        ps += w;
      }
      #pragma unroll
      for (int m2 = 8; m2 >= 1; m2 >>= 1) ps += __shfl_xor(ps, m2);
      if (i == 0) sh[h] = sh[h]*rh[h] + ps;
    }
    __syncthreads();
    // rescale + aggregate
    a0 *= rh[h0];
    if (t < 128) a1 *= rh[h1];
    for (int q = 0; q < cn; q++) {
      float zv = sZ[q][zc];
      a0 += sW[q][h0] * zv;
      if (t < 128) a1 += sW[q][h1] * zv;
    }
    if (g < 3) {
      #pragma unroll
      for (int j = 0; j < 8; j++) acc8[j] *= rh[myh];
      #pragma unroll 2
      for (int qq = g; qq < cn; qq += 3) {
        float w = sW[qq][myh];
        const uint4* ve = (const uint4*)(VE + (size_t)sD[qq]*VE_COLS);
        uint4 L = ve[vth];
        acc8[0] += w * b2f((unsigned short)(L.x & 0xffffu));
        acc8[1] += w * b2f((unsigned short)(L.x >> 16));
        acc8[2] += w * b2f((unsigned short)(L.y & 0xffffu));
        acc8[3] += w * b2f((unsigned short)(L.y >> 16));
        acc8[4] += w * b2f((unsigned short)(L.z & 0xffffu));
        acc8[5] += w * b2f((unsigned short)(L.z >> 16));
        acc8[6] += w * b2f((unsigned short)(L.w & 0xffffu));
        acc8[7] += w * b2f((unsigned short)(L.w >> 16));
      }
    }
  }
  __syncthreads();
  if (t < 12) rh[t] = (sh[t] > 0.f) ? 1.f/sh[t] : 0.f;
  __syncthreads();
  __hip_bfloat16* fr = featB + (size_t)n*FCOLS;
  a0 *= rh[h0];
  fr[t] = __float2bfloat16(a0);
  if (t < 128) { a1 *= rh[h1]; fr[256 + t] = __float2bfloat16(a1); }
  if (g < 3) {
    #pragma unroll
    for (int j = 0; j < 8; j++) sVE[g][s0 + j] = acc8[j] * rh[myh];
  }
  __syncthreads();
  for (int s = t; s < 672; s += 256) {
    float tot = sVE[0][s] + sVE[1][s] + sVE[2][s];
    if (s < 384) fr[384 + s] = __float2bfloat16(tot);
    else sAgg[s - 384] = tot;
  }
  __syncthreads();
  if (t < 96) {
    int pt = t;
    const float* Rn = R + (size_t)n*9;
    float d0 = sAgg[pt*3+0] - tr[n*3+0];
    float d1 = sAgg[pt*3+1] - tr[n*3+1];
    float d2 = sAgg[pt*3+2] - tr[n*3+2];
    float l0 = Rn[0]*d0 + Rn[3]*d1 + Rn[6]*d2;
    float l1 = Rn[1]*d0 + Rn[4]*d1 + Rn[7]*d2;
    float l2 = Rn[2]*d0 + Rn[5]*d1 + Rn[8]*d2;
    float nr = sqrtf(l0*l0 + l1*l1 + l2*l2);
    float inv = 1.f / fmaxf(nr, 1e-8f);
    fr[768 + pt*3+0] = __float2bfloat16(l0);
    fr[768 + pt*3+1] = __float2bfloat16(l1);
    fr[768 + pt*3+2] = __float2bfloat16(l2);
    fr[1056 + pt]    = __float2bfloat16(nr);
    fr[1152 + pt*3+0] = __float2bfloat16(l0*inv);
    fr[1152 + pt*3+1] = __float2bfloat16(l1*inv);
    fr[1152 + pt*3+2] = __float2bfloat16(l2*inv);
  }
}

// ---------------- xo = x + featB @ Wo + bo   (32x128 tile, 4x4 register block)
__global__ __launch_bounds__(256) void wo_gemm(
    const __hip_bfloat16* __restrict__ featB, const float* __restrict__ Wo,
    const float* __restrict__ bo, const float* __restrict__ x, float* __restrict__ xo)
{
  __shared__ float Ast[32][36];
  __shared__ float Bs[32][132];
  const int t = threadIdx.x;
  const int n0 = blockIdx.x * 32;
  const int tx = t & 31, ty = t >> 5;
  const int cl = t & 127, kset = t >> 7;
  float acc[4][4] = {};
  const int ar = t >> 3, akc = (t & 7) * 4;
  for (int k0 = 0; k0 < FCOLS; k0 += 32) {
    {
      const __hip_bfloat16* ap = featB + (size_t)(n0 + ar)*FCOLS + k0 + akc;
      short4 raw = *(const short4*)(const void*)ap;
      Ast[akc+0][ar] = b2f((unsigned short)raw.x);
      Ast[akc+1][ar] = b2f((unsigned short)raw.y);
      Ast[akc+2][ar] = b2f((unsigned short)raw.z);
      Ast[akc+3][ar] = b2f((unsigned short)raw.w);
    }
    #pragma unroll
    for (int u = 0; u < 16; u++) {
      int kk = kset + 2*u;
      Bs[kk][cl] = Wo[(size_t)(k0 + kk)*128 + cl];
    }
    __syncthreads();
    #pragma unroll
    for (int kk = 0; kk < 32; kk++) {
      float4 a4 = *(const float4*)&Ast[kk][ty*4];
      float4 b4 = *(const float4*)&Bs[kk][tx*4];
      float av[4] = {a4.x, a4.y, a4.z, a4.w};
      float bv[4] = {b4.x, b4.y, b4.z, b4.w};
      #pragma unroll
      for (int i2 = 0; i2 < 4; i2++)
        #pragma unroll
        for (int j2 = 0; j2 < 4; j2++)
          acc[i2][j2] += av[i2] * bv[j2];
    }
    __syncthreads();
  }
  const int gc = tx*4;
  #pragma unroll
  for (int i2 = 0; i2 < 4; i2++) {
    int r = n0 + ty*4 + i2;
    float4 xr = *(const float4*)&x[(size_t)r*128 + gc];
    float xv[4] = {xr.x, xr.y, xr.z, xr.w};
    #pragma unroll
    for (int j2 = 0; j2 < 4; j2++)
      xo[(size_t)r*128 + gc + j2] = acc[i2][j2] + bo[gc + j2] + xv[j2];
  }
}

// ---------------- LN1 -> MLP -> residual -> LN2, 32 rows/block, 4x4 micro-GEMM
__global__ __launch_bounds__(256) void lnmlp2(
    const float* __restrict__ xo,
    const float* __restrict__ g1, const float* __restrict__ b1v,
    const float* __restrict__ w1, const float* __restrict__ bb1,
    const float* __restrict__ w2, const float* __restrict__ bb2,
    const float* __restrict__ w3, const float* __restrict__ bb3,
    const float* __restrict__ g2, const float* __restrict__ b2v,
    float* __restrict__ out)
{
  __shared__ float smem[17344];
  float* hs   = smem;           // 32 x 132
  float* AT   = smem + 4224;    // 128 x 36
  float* bA   = smem + 8832;    // 32 x 132
  float* bB   = smem + 13056;   // 32 x 132
  float* mu_s = smem + 17280;   // 32
  float* rs_s = smem + 17312;   // 32

  const int t = threadIdx.x, n0 = blockIdx.x * 32;
  const int tx = t & 31, ty = t >> 5;
  const int c = t & 127, rhalf = t >> 7;
  const int w = t >> 6, lane = t & 63;

  for (int e = t; e < 4096; e += 256) {
    int r = e >> 7, cc = e & 127;
    hs[r*132 + cc] = xo[(size_t)(n0 + r)*128 + cc];
  }
  __syncthreads();
  for (int q = 0; q < 8; q++) {
    int r = w*8 + q;
    float v0 = hs[r*132 + lane], v1 = hs[r*132 + lane + 64];
    float s = v0 + v1, ss = v0*v0 + v1*v1;
    #pragma unroll
    for (int m2 = 32; m2 >= 1; m2 >>= 1) { s += __shfl_xor(s, m2); ss += __shfl_xor(ss, m2); }
    if (lane == 0) { float mu = s*(1.f/128.f); mu_s[r] = mu; rs_s[r] = rsqrtf(ss*(1.f/128.f) - mu*mu + 1e-5f); }
  }
  __syncthreads();
  for (int r = rhalf; r < 32; r += 2)
    hs[r*132 + c] = (hs[r*132 + c] - mu_s[r]) * rs_s[r] * g1[c] + b1v[c];
  __syncthreads();

#define MLP_LAYER(INB, OUTB, WG, BG, DO_RELU, DO_RES)                          \
  {                                                                            \
    for (int e = t; e < 4096; e += 256) {                                      \
      int kk = e >> 5, r = e & 31;                                             \
      AT[kk*36 + r] = INB[r*132 + kk];                                         \
    }                                                                          \
    __syncthreads();                                                           \
    float acc[4][4] = {};                                                      \
    const float4* Wg4 = (const float4*)(WG);                                   \
    for (int kk = 0; kk < 128; kk++) {                                         \
      float4 a4 = *(const float4*)&AT[kk*36 + ty*4];                           \
      float4 b4 = Wg4[kk*32 + tx];                                             \
      float av[4] = {a4.x, a4.y, a4.z, a4.w};                                  \
      float bv[4] = {b4.x, b4.y, b4.z, b4.w};                                  \
      _Pragma("unroll")                                                        \
      for (int i2 = 0; i2 < 4; i2++)                                           \
        _Pragma("unroll")                                                      \
        for (int j2 = 0; j2 < 4; j2++)                                         \
          acc[i2][j2] += av[i2] * bv[j2];                                      \
    }                                                                          \
    _Pragma("unroll")                                                          \
    for (int i2 = 0; i2 < 4; i2++) {                                           \
      int r = ty*4 + i2;                                                       \
      _Pragma("unroll")                                                        \
      for (int j2 = 0; j2 < 4; j2++) {                                         \
        int cc2 = tx*4 + j2;                                                   \
        float v = acc[i2][j2] + BG[cc2];                                       \
        if (DO_RES) v += hs[r*132 + cc2];                                      \
        OUTB[r*132 + cc2] = DO_RELU ? fmaxf(v, 0.f) : v;                       \
      }                                                                        \
    }                                                                          \
    __syncthreads();                                                           \
  }

  MLP_LAYER(hs, bA, w1, bb1, 1, 0)
  MLP_LAYER(bA, bB, w2, bb2, 1, 0)
  MLP_LAYER(bB, bA, w3, bb3, 0, 1)
#undef MLP_LAYER

  for (int q = 0; q < 8; q++) {
    int r = w*8 + q;
    float v0 = bA[r*132 + lane], v1 = bA[r*132 + lane + 64];
    float s = v0 + v1, ss = v0*v0 + v1*v1;
    #pragma unroll
    for (int m2 = 32; m2 >= 1; m2 >>= 1) { s += __shfl_xor(s, m2); ss += __shfl_xor(ss, m2); }
    if (lane == 0) { float mu = s*(1.f/128.f); mu_s[r] = mu; rs_s[r] = rsqrtf(ss*(1.f/128.f) - mu*mu + 1e-5f); }
  }
  __syncthreads();
  for (int r = rhalf; r < 32; r += 2)
    out[(size_t)(n0 + r)*128 + c] = (bA[r*132 + c] - mu_s[r]) * rs_s[r] * g2[c] + b2v[c];
}

__global__ void diag_ws(float* out, float v)
{
  if (blockIdx.x == 0 && threadIdx.x == 0) out[0] = v;
}

// ---------------- host side ----------------
struct Args {
  const float *R, *tr, *x, *z, *Wq, *Wk, *Wv, *Wpair, *spc, *Wqp, *Wkp, *Wvp;
  const float *Wo, *bo, *g1, *b1v, *w1, *bb1, *w2, *bb2, *w3, *bb3, *g2, *b2v;
  const int* ei;
  float* out;
};

static inline size_t alup(size_t v) { return (v + 255) & ~(size_t)255; }

template<typename TA, typename TP>
static void run_all(const Args& a, char* ws, hipStream_t stream)
{
  // region 0: Pq | Pqp | Pkp  (dead after build_qe/transform) -> reused as featB
  size_t pq_b  = alup((size_t)NN*PQ_COLS*sizeof(TA));
  size_t pqp_b = alup((size_t)NN*PQP_COLS*sizeof(TP));
  size_t pkp_b = alup((size_t)NN*PKP_COLS*sizeof(TP));
  size_t region = pq_b + pqp_b + pkp_b;
  size_t fb_b = alup((size_t)NN*FCOLS*2);
  if (fb_b > region) region = fb_b;

  TA* Pq  = (TA*)ws;
  TP* Pqp = (TP*)(ws + pq_b);
  TP* Pkp = (TP*)(ws + pq_b + pqp_b);
  __hip_bfloat16* featB = (__hip_bfloat16*)ws;

  size_t off = region;
  __hip_bfloat16* QE = (__hip_bfloat16*)(ws + off); off += alup((size_t)NN*QE_COLS*2);
  __hip_bfloat16* VE = (__hip_bfloat16*)(ws + off); off += alup((size_t)NN*VE_COLS*2);
  __hip_bfloat16* KE = (__hip_bfloat16*)(ws + off); off += alup((size_t)NN*KE_COLS*2);
  float* SKKP = (float*)(ws + off);  off += alup((size_t)NN*12*sizeof(float));
  int* cnt = (int*)(ws + off);       off += alup((size_t)NN*sizeof(int));
  int* rowptr = (int*)(ws + off);    off += alup((size_t)(NN+1)*sizeof(int));
  int* cursor = (int*)(ws + off);    off += alup((size_t)NN*sizeof(int));
  int* eidx = (int*)(ws + off);      off += alup((size_t)EE*sizeof(int));
  float* xo = a.out;

  hipMemsetAsync(cnt, 0, (size_t)NN*sizeof(int), stream);

  proj_gemm<TA,TP><<<dim3(NN/32, 16), 256, 0, stream>>>(a.x, a.Wq, a.Wk, a.Wv, a.Wqp, a.Wkp, a.Wvp,
                                                        Pq, Pqp, Pkp, KE, VE);
  transform_pts<TP><<<(NN*288)/256, 256, 0, stream>>>(a.R, a.tr, Pqp, Pkp, KE, VE);
  build_qe<TA,TP><<<NN, 256, 0, stream>>>(Pq, Pqp, a.spc, QE);
  build_skkp<<<NN, 256, 0, stream>>>(KE, a.spc, SKKP);
  count_edges<<<EE/256, 256, 0, stream>>>(a.ei, cnt);
  scan_csr<<<1, 1024, 0, stream>>>(cnt, rowptr, cursor);
  fill_csr<<<EE/256, 256, 0, stream>>>(a.ei, cursor, eidx);
  attn_fused<<<NN, 256, 0, stream>>>(QE, KE, SKKP, VE, a.z, a.ei, a.Wpair,
                                     rowptr, eidx, a.R, a.tr, featB);
  wo_gemm<<<NN/32, 256, 0, stream>>>(featB, a.Wo, a.bo, a.x, xo);
  lnmlp2<<<NN/32, 256, 0, stream>>>(xo, a.g1, a.b1v, a.w1, a.bb1, a.w2, a.bb2,
                                    a.w3, a.bb3, a.g2, a.b2v, a.out);
}

template<typename TA, typename TP>
static size_t need_bytes()
{
  size_t region = alup((size_t)NN*PQ_COLS*sizeof(TA)) + alup((size_t)NN*PQP_COLS*sizeof(TP)) +
                  alup((size_t)NN*PKP_COLS*sizeof(TP));
  size_t fb_b = alup((size_t)NN*FCOLS*2);
  if (fb_b > region) region = fb_b;
  return region + alup((size_t)NN*QE_COLS*2) + alup((size_t)NN*VE_COLS*2) +
         alup((size_t)NN*KE_COLS*2) + alup((size_t)NN*12*4) +
         alup((size_t)NN*4)*2 + alup((size_t)(NN+1)*4) + alup((size_t)EE*4);
}

extern "C" void kernel_launch(void* const* d_in, const int* in_sizes, int n_in,
                              void* d_out, int out_size, void* d_ws, size_t ws_size,
                              hipStream_t stream)
{
  Args a;
  a.R     = (const float*)d_in[0];
  a.tr    = (const float*)d_in[1];
  a.x     = (const float*)d_in[2];
  a.z     = (const float*)d_in[3];
  a.ei    = (const int*)  d_in[4];
  a.Wq    = (const float*)d_in[5];
  a.Wk    = (const float*)d_in[6];
  a.Wv    = (const float*)d_in[7];
  a.Wpair = (const float*)d_in[8];
  a.spc   = (const float*)d_in[9];
  a.Wqp   = (const float*)d_in[10];
  a.Wkp   = (const float*)d_in[11];
  a.Wvp   = (const float*)d_in[12];
  a.Wo    = (const float*)d_in[13];
  a.bo    = (const float*)d_in[14];
  a.g1    = (const float*)d_in[15];
  a.b1v   = (const float*)d_in[16];
  a.w1    = (const float*)d_in[17];
  a.bb1   = (const float*)d_in[18];
  a.w2    = (const float*)d_in[19];
  a.bb2   = (const float*)d_in[20];
  a.w3    = (const float*)d_in[21];
  a.bb3   = (const float*)d_in[22];
  a.g2    = (const float*)d_in[23];
  a.b2v   = (const float*)d_in[24];
  a.out   = (float*)d_out;

  if (ws_size >= need_bytes<float, float>()) {
    run_all<float, float>(a, (char*)d_ws, stream);
  } else if (ws_size >= need_bytes<__hip_bfloat16, float>()) {
    run_all<__hip_bfloat16, float>(a, (char*)d_ws, stream);
  } else if (ws_size >= need_bytes<__hip_bfloat16, __hip_bfloat16>()) {
    run_all<__hip_bfloat16, __hip_bfloat16>(a, (char*)d_ws, stream);
  } else {
    diag_ws<<<1, 64, 0, stream>>>((float*)d_out, (float)((double)ws_size / (1024.0*1024.0)));
  }
}

// Round 9
// 616.494 us; speedup vs baseline: 1.5754x; 1.3081x over previous
//
#include <hip/hip_runtime.h>
#include <hip/hip_bf16.h>
#include <math.h>

#define NN 20000
#define EE 320000
#define PQ_COLS  384    // q f32 (dead after build_qe)
#define PQP_COLS 288    // qp f32 (global after transform; dead after build_qe)
#define PKP_COLS 288    // kp local f32 (dead after transform)
#define QE_COLS  768    // 12 heads x 64 bf16
#define VE_COLS  672    // [v 384 | vp 288] bf16
#define KE_COLS  768    // 12 heads x 64 bf16: [k 32 | kp_global 24 | 0 x8]
#define FCOLS 1440      // [p2n 384 | node 384 | loc 288 | nrm 96 | dirn 288]

typedef __attribute__((ext_vector_type(8))) short bf16x8v;
typedef __attribute__((ext_vector_type(4))) float f32x4v;

__device__ __forceinline__ float b2f(unsigned short u) {
  return __uint_as_float(((unsigned)u) << 16);
}

// ---------------- dtype conversion prekernels
__global__ void cvt_x(const float* __restrict__ x, __hip_bfloat16* __restrict__ XB)
{
  int i = (blockIdx.x*256 + threadIdx.x) * 4;
  if (i >= NN*128) return;
  float4 v = *(const float4*)&x[i];
  XB[i+0] = __float2bfloat16(v.x); XB[i+1] = __float2bfloat16(v.y);
  XB[i+2] = __float2bfloat16(v.z); XB[i+3] = __float2bfloat16(v.w);
}

// WBt[c][k] = W_cat[k][c], bf16, c in [0,2016), k in [0,128)
__global__ void cvt_wt(const float* __restrict__ Wq, const float* __restrict__ Wk,
                       const float* __restrict__ Wv, const float* __restrict__ Wqp,
                       const float* __restrict__ Wkp, const float* __restrict__ Wvp,
                       __hip_bfloat16* __restrict__ WBt)
{
  int idx = blockIdx.x*256 + threadIdx.x;
  if (idx >= 2016*128) return;
  int c = idx >> 7, k = idx & 127;
  float v;
  if      (c < 384)  v = Wq [k*384 + c];
  else if (c < 768)  v = Wk [k*384 + (c-384)];
  else if (c < 1152) v = Wv [k*384 + (c-768)];
  else if (c < 1440) v = Wqp[k*288 + (c-1152)];
  else if (c < 1728) v = Wkp[k*288 + (c-1440)];
  else               v = Wvp[k*288 + (c-1728)];
  WBt[idx] = __float2bfloat16(v);
}

// WoT[c][k] = Wo[k][c], c in [0,128), k in [0,1440)
__global__ void cvt_wot(const float* __restrict__ Wo, __hip_bfloat16* __restrict__ WoT)
{
  int idx = blockIdx.x*256 + threadIdx.x;
  if (idx >= 128*1440) return;
  int c = idx / 1440, k = idx - c*1440;
  WoT[idx] = __float2bfloat16(Wo[k*128 + c]);
}

// ---------------- MFMA projection: [XB 20000x128] @ [W 128x2016] -> routed panels
__global__ __launch_bounds__(256) void proj_mfma(
    const __hip_bfloat16* __restrict__ XB, const __hip_bfloat16* __restrict__ WBt,
    float* __restrict__ Pq, float* __restrict__ Pqp, float* __restrict__ Pkp,
    __hip_bfloat16* __restrict__ KE, __hip_bfloat16* __restrict__ VE)
{
  __shared__ short A_lds[64*136];
  __shared__ short B_lds[128*136];
  const int t = threadIdx.x;
  const int n0 = blockIdx.x * 64;
  const int c0 = blockIdx.y * 128;
  // stage A (64 x 128 bf16)
  {
    int r = t >> 2, kc = (t & 3) * 32;
    int gr = n0 + r; if (gr >= NN) gr = NN-1;
    const uint4* src = (const uint4*)(XB + (size_t)gr*128 + kc);
    uint4 v0 = src[0], v1 = src[1], v2 = src[2], v3 = src[3];
    *(uint4*)&A_lds[r*136 + kc +  0] = v0;
    *(uint4*)&A_lds[r*136 + kc +  8] = v1;
    *(uint4*)&A_lds[r*136 + kc + 16] = v2;
    *(uint4*)&A_lds[r*136 + kc + 24] = v3;
  }
  // stage B transposed (128 out-cols x 128 k)
  {
    int cI = t >> 1, ko = (t & 1) * 64;
    int gc = c0 + cI; if (gc > 2015) gc = 2015;
    const uint4* src = (const uint4*)(WBt + (size_t)gc*128 + ko);
    #pragma unroll
    for (int j = 0; j < 8; j++)
      *(uint4*)&B_lds[cI*136 + ko + j*8] = src[j];
  }
  __syncthreads();
  const int lane = t & 63, wid = t >> 6;
  const int wm = wid >> 1, wn = wid & 1;
  const int lrow = lane >> 4, lcol = lane & 15;
  f32x4v zero = {0.f, 0.f, 0.f, 0.f};
  f32x4v acc[2][4];
  #pragma unroll
  for (int i = 0; i < 2; i++)
    #pragma unroll
    for (int j = 0; j < 4; j++) acc[i][j] = zero;
  #pragma unroll
  for (int ks = 0; ks < 4; ks++) {
    int kb = ks*32 + lrow*8;
    bf16x8v a0 = *(const bf16x8v*)&A_lds[(wm*32 +      lcol)*136 + kb];
    bf16x8v a1 = *(const bf16x8v*)&A_lds[(wm*32 + 16 + lcol)*136 + kb];
    #pragma unroll
    for (int nt = 0; nt < 4; nt++) {
      bf16x8v b = *(const bf16x8v*)&B_lds[(wn*64 + nt*16 + lcol)*136 + kb];
      acc[0][nt] = __builtin_amdgcn_mfma_f32_16x16x32_bf16(a0, b, acc[0][nt], 0, 0, 0);
      acc[1][nt] = __builtin_amdgcn_mfma_f32_16x16x32_bf16(a1, b, acc[1][nt], 0, 0, 0);
    }
  }
  // epilogue: route by column class (class uniform per nt: boundaries 16-aligned)
  #pragma unroll
  for (int nt = 0; nt < 4; nt++) {
    int colb = c0 + wn*64 + nt*16;
    if (colb >= 2016) continue;
    int col = colb + lcol;
    #pragma unroll
    for (int mt = 0; mt < 2; mt++) {
      #pragma unroll
      for (int r = 0; r < 4; r++) {
        int grow = n0 + wm*32 + mt*16 + lrow*4 + r;
        if (grow >= NN) continue;
        float v = acc[mt][nt][r];
        if      (col < 384)  Pq[(size_t)grow*PQ_COLS + col] = v;
        else if (col < 768)  { int d = col-384; KE[(size_t)grow*KE_COLS + (d>>5)*64 + (d&31)] = __float2bfloat16(v); }
        else if (col < 1152) VE[(size_t)grow*VE_COLS + (col-768)] = __float2bfloat16(v);
        else if (col < 1440) Pqp[(size_t)grow*PQP_COLS + (col-1152)] = v;
        else if (col < 1728) Pkp[(size_t)grow*PKP_COLS + (col-1440)] = v;
        else                 VE[(size_t)grow*VE_COLS + 384 + (col-1728)] = __float2bfloat16(v);
      }
    }
  }
}

// ---------------- point transform: qp in place (f32); kp: Pkp f32 -> KE bf16; vp: VE RMW
__global__ void transform_pts(const float* __restrict__ R, const float* __restrict__ tr,
                              float* __restrict__ Pqp, const float* __restrict__ Pkp,
                              __hip_bfloat16* __restrict__ KE, __hip_bfloat16* __restrict__ VE)
{
  int idx = blockIdx.x*256 + threadIdx.x;   // N * 288 point-triples
  if (idx >= NN*288) return;
  int n = idx / 288, rem = idx - n*288;
  const float* Rn = R + (size_t)n*9;
  float t0 = tr[n*3], t1 = tr[n*3+1], t2 = tr[n*3+2];
  if (rem < 96) {
    float* p = Pqp + (size_t)n*PQP_COLS + rem*3;
    float l0 = p[0], l1 = p[1], l2 = p[2];
    p[0] = Rn[0]*l0 + Rn[1]*l1 + Rn[2]*l2 + t0;
    p[1] = Rn[3]*l0 + Rn[4]*l1 + Rn[5]*l2 + t1;
    p[2] = Rn[6]*l0 + Rn[7]*l1 + Rn[8]*l2 + t2;
  } else if (rem < 192) {
    int j = rem - 96, h = j >> 3, jj = j & 7;
    const float* p = Pkp + (size_t)n*PKP_COLS + h*24 + jj*3;
    float l0 = p[0], l1 = p[1], l2 = p[2];
    __hip_bfloat16* o = KE + (size_t)n*KE_COLS + h*64 + 32 + jj*3;
    o[0] = __float2bfloat16(Rn[0]*l0 + Rn[1]*l1 + Rn[2]*l2 + t0);
    o[1] = __float2bfloat16(Rn[3]*l0 + Rn[4]*l1 + Rn[5]*l2 + t1);
    o[2] = __float2bfloat16(Rn[6]*l0 + Rn[7]*l1 + Rn[8]*l2 + t2);
  } else {
    __hip_bfloat16* p = VE + (size_t)n*VE_COLS + 384 + (rem-192)*3;
    float l0 = __bfloat162float(p[0]), l1 = __bfloat162float(p[1]), l2 = __bfloat162float(p[2]);
    p[0] = __float2bfloat16(Rn[0]*l0 + Rn[1]*l1 + Rn[2]*l2 + t0);
    p[1] = __float2bfloat16(Rn[3]*l0 + Rn[4]*l1 + Rn[5]*l2 + t1);
    p[2] = __float2bfloat16(Rn[6]*l0 + Rn[7]*l1 + Rn[8]*l2 + t2);
  }
}

// ---------------- build QE panel (bf16)
__global__ __launch_bounds__(256) void build_qe(
    const float* __restrict__ Pq, const float* __restrict__ Pqp,
    const float* __restrict__ spc, __hip_bfloat16* __restrict__ QE)
{
  __shared__ float cfs[12];
  const int n = blockIdx.x, t = threadIdx.x;
  if (t < 12) cfs[t] = log1pf(expf(spc[t])) * (1.f/12.f);
  __syncthreads();
  #pragma unroll
  for (int u = 0; u < 3; u++) {
    int s = t + 256*u;
    int h = s >> 6, i = s & 63;
    float val = 0.f;
    if (i < 32)      val = 0.1020620726f * Pq[(size_t)n*PQ_COLS + h*32 + i];
    else if (i < 56) val = 1.15470053838f * cfs[h] * Pqp[(size_t)n*PQP_COLS + h*24 + (i-32)];
    QE[(size_t)n*QE_COLS + s] = __float2bfloat16(val);
  }
}

// ---------------- SKKP + zero KE pad slots
__global__ __launch_bounds__(256) void build_skkp(
    __hip_bfloat16* __restrict__ KE, const float* __restrict__ spc, float* __restrict__ SKKP)
{
  __shared__ float skk[12], cfb[12];
  const int n = blockIdx.x, t = threadIdx.x;
  if (t < 12) { cfb[t] = log1pf(expf(spc[t])) * (1.f/12.f); skk[t] = 0.f; }
  __syncthreads();
  for (int s = t; s < 288; s += 256) {
    int h = s / 24, j = s - 24*h;
    float v = __bfloat162float(KE[(size_t)n*KE_COLS + h*64 + 32 + j]);
    atomicAdd(&skk[h], v*v);
  }
  __syncthreads();
  if (t < 96) {
    int h = t >> 3, i = t & 7;
    KE[(size_t)n*KE_COLS + h*64 + 56 + i] = __float2bfloat16(0.0f);
    if (i == 0) SKKP[(size_t)n*12 + h] = -0.57735026919f * cfb[h] * skk[h];
  }
}

// ---------------- CSR build
__global__ void count_edges(const int* __restrict__ ei, int* __restrict__ cnt)
{
  int e = blockIdx.x*256 + threadIdx.x;
  if (e < EE) atomicAdd(&cnt[ei[e]], 1);
}

__global__ __launch_bounds__(1024) void scan_csr(const int* __restrict__ cnt,
                                                 int* __restrict__ rowptr,
                                                 int* __restrict__ cursor)
{
  __shared__ int part[1024];
  int t = threadIdx.x;
  int base = t*20;
  int loc[20];
  int s = 0;
  #pragma unroll
  for (int i = 0; i < 20; i++) {
    int idx = base + i;
    int cc = (idx < NN) ? cnt[idx] : 0;
    loc[i] = s; s += cc;
  }
  part[t] = s;
  __syncthreads();
  for (int off = 1; off < 1024; off <<= 1) {
    int v = (t >= off) ? part[t-off] : 0;
    __syncthreads();
    part[t] += v;
    __syncthreads();
  }
  int pre = (t == 0) ? 0 : part[t-1];
  #pragma unroll
  for (int i = 0; i < 20; i++) {
    int idx = base + i;
    if (idx < NN) { rowptr[idx] = pre + loc[i]; cursor[idx] = pre + loc[i]; }
  }
  if (t == 1023) rowptr[NN] = part[1023];
}

__global__ void fill_csr(const int* __restrict__ ei, int* __restrict__ cursor,
                         int* __restrict__ eidx)
{
  int e = blockIdx.x*256 + threadIdx.x;
  if (e >= EE) return;
  int pos = atomicAdd(&cursor[ei[e]], 1);
  eidx[pos] = e;
}

__device__ __forceinline__ float dot8(const float* qr, uint4 v) {
  float s;
  s  = qr[0]*b2f((unsigned short)(v.x & 0xffffu));
  s += qr[1]*b2f((unsigned short)(v.x >> 16));
  s += qr[2]*b2f((unsigned short)(v.y & 0xffffu));
  s += qr[3]*b2f((unsigned short)(v.y >> 16));
  s += qr[4]*b2f((unsigned short)(v.z & 0xffffu));
  s += qr[5]*b2f((unsigned short)(v.z >> 16));
  s += qr[6]*b2f((unsigned short)(v.w & 0xffffu));
  s += qr[7]*b2f((unsigned short)(v.w >> 16));
  return s;
}

// ---------------- fused attention (round-8 body, unchanged)
__global__ __launch_bounds__(256) void attn_fused(
    const __hip_bfloat16* __restrict__ QE,
    const __hip_bfloat16* __restrict__ KE, const float* __restrict__ SKKP,
    const __hip_bfloat16* __restrict__ VE,
    const float* __restrict__ z, const int* __restrict__ ei,
    const float* __restrict__ Wpair,
    const int* __restrict__ rowptr, const int* __restrict__ eidx,
    const float* __restrict__ R, const float* __restrict__ tr,
    __hip_bfloat16* __restrict__ featB)
{
  __shared__ float wpT[12*33];
  __shared__ float sZ[64][33];
  __shared__ float sLA[64][13];
  __shared__ float sLB[64][13];
  __shared__ float sW[64][13];
  __shared__ int   sD[64];
  __shared__ float mh[12], sh[12], rh[12], mch[12];
  __shared__ float sVE[3][672];
  __shared__ float sAgg[288];

  const int n = blockIdx.x, t = threadIdx.x;
  const int beg = rowptr[n], end = rowptr[n+1];
  const int lane = t & 63, wid = t >> 6;
  const float inv_sqrt3 = 0.57735026919f;

  if (t < 12) { mh[t] = -1e30f; sh[t] = 0.f; }
  for (int i = t; i < 384; i += 256) {
    int c = i / 12, h = i - 12*c;
    wpT[h*33 + c] = Wpair[i] * inv_sqrt3;
  }
  float q0[8], q1[8];
  {
    const uint4* qrow = (const uint4*)(QE + (size_t)n*QE_COLS);
    uint4 Q0 = qrow[lane];
    q0[0]=b2f((unsigned short)(Q0.x&0xffffu)); q0[1]=b2f((unsigned short)(Q0.x>>16));
    q0[2]=b2f((unsigned short)(Q0.y&0xffffu)); q0[3]=b2f((unsigned short)(Q0.y>>16));
    q0[4]=b2f((unsigned short)(Q0.z&0xffffu)); q0[5]=b2f((unsigned short)(Q0.z>>16));
    q0[6]=b2f((unsigned short)(Q0.w&0xffffu)); q0[7]=b2f((unsigned short)(Q0.w>>16));
    if (lane < 32) {
      uint4 Q1 = qrow[64 + lane];
      q1[0]=b2f((unsigned short)(Q1.x&0xffffu)); q1[1]=b2f((unsigned short)(Q1.x>>16));
      q1[2]=b2f((unsigned short)(Q1.y&0xffffu)); q1[3]=b2f((unsigned short)(Q1.y>>16));
      q1[4]=b2f((unsigned short)(Q1.z&0xffffu)); q1[5]=b2f((unsigned short)(Q1.z>>16));
      q1[6]=b2f((unsigned short)(Q1.w&0xffffu)); q1[7]=b2f((unsigned short)(Q1.w>>16));
    } else {
      #pragma unroll
      for (int j = 0; j < 8; j++) q1[j] = 0.f;
    }
  }

  const int h0 = t >> 5;
  const int h1 = 8 + (t >> 5);
  const int zc = t & 31;
  const int g   = t / 84;
  const int vth = t - g*84;
  const int s0  = vth*8;
  const int myh = (s0 < 384) ? (s0 >> 5) : ((s0 - 384) / 24);
  float a0 = 0.f, a1 = 0.f;
  float acc8[8] = {};

  for (int c0 = beg; c0 < end; c0 += 64) {
    const int cn = min(64, end - c0);
    __syncthreads();
    if (t < cn) sD[t] = ei[EE + eidx[c0 + t]];
    #pragma unroll
    for (int u = 0; u < 2; u++) {
      int idx = t + 256*u;
      int j = idx >> 3, c4 = idx & 7;
      if (j < cn) {
        int e = eidx[c0 + j];
        float4 zz = ((const float4*)(z + (size_t)e*32))[c4];
        sZ[j][c4*4+0] = zz.x; sZ[j][c4*4+1] = zz.y;
        sZ[j][c4*4+2] = zz.z; sZ[j][c4*4+3] = zz.w;
      }
    }
    __syncthreads();
    #pragma unroll
    for (int u = 0; u < 3; u++) {
      int idx = t + 256*u;
      int q = idx / 12, h = idx - 12*q;
      if (q < cn) {
        float acc = 0.f;
        #pragma unroll
        for (int c = 0; c < 32; c++) acc += sZ[q][c] * wpT[h*33 + c];
        sLA[q][h] = acc;
      }
    }
    #pragma unroll 2
    for (int q = wid; q < cn; q += 4) {
      int dst = sD[q];
      const uint4* ke = (const uint4*)(KE + (size_t)dst*KE_COLS);
      uint4 L0 = ke[lane];
      uint4 L1 = make_uint4(0,0,0,0);
      if (lane < 32) L1 = ke[64 + lane];
      float bc0 = 0.f, bc1 = 0.f;
      if ((lane & 7) == 0) {
        bc0 = SKKP[(size_t)dst*12 + (lane >> 3)];
        if (lane < 32) bc1 = SKKP[(size_t)dst*12 + 8 + (lane >> 3)];
      }
      float p0 = dot8(q0, L0);
      p0 += __shfl_xor(p0, 1); p0 += __shfl_xor(p0, 2); p0 += __shfl_xor(p0, 4);
      float p1 = dot8(q1, L1);
      p1 += __shfl_xor(p1, 1); p1 += __shfl_xor(p1, 2); p1 += __shfl_xor(p1, 4);
      if ((lane & 7) == 0) {
        sLB[q][lane >> 3] = p0 + bc0;
        if (lane < 32) sLB[q][8 + (lane >> 3)] = p1 + bc1;
      }
    }
    __syncthreads();
    if (t < 192) {
      int h = t >> 4, i = t & 15;
      float mx = -1e30f;
      for (int q = i; q < cn; q += 16) mx = fmaxf(mx, sLA[q][h] + sLB[q][h]);
      #pragma unroll
      for (int m2 = 8; m2 >= 1; m2 >>= 1) mx = fmaxf(mx, __shfl_xor(mx, m2));
      if (i == 0) mch[h] = mx;
    }
    __syncthreads();
    if (t < 12) {
      float mn = fmaxf(mh[t], mch[t]);
      rh[t] = expf(mh[t] - mn);
      mh[t] = mn;
    }
    __syncthreads();
    if (t < 192) {
      int h = t >> 4, i = t & 15;
      float ps = 0.f;
      for (int q = i; q < cn; q += 16) {
        float w = expf(sLA[q][h] + sLB[q][h] - mh[h]);
        sW[q][h] = w;
        ps += w;
      }
      #pragma unroll
      for (int m2 = 8; m2 >= 1; m2 >>= 1) ps += __shfl_xor(ps, m2);
      if (i == 0) sh[h] = sh[h]*rh[h] + ps;
    }
    __syncthreads();
    a0 *= rh[h0];
    if (t < 128) a1 *= rh[h1];
    for (int q = 0; q < cn; q++) {
      float zv = sZ[q][zc];
      a0 += sW[q][h0] * zv;
      if (t < 128) a1 += sW[q][h1] * zv;
    }
    if (g < 3) {
      #pragma unroll
      for (int j = 0; j < 8; j++) acc8[j] *= rh[myh];
      #pragma unroll 2
      for (int qq = g; qq < cn; qq += 3) {
        float w = sW[qq][myh];
        const uint4* ve = (const uint4*)(VE + (size_t)sD[qq]*VE_COLS);
        uint4 L = ve[vth];
        acc8[0] += w * b2f((unsigned short)(L.x & 0xffffu));
        acc8[1] += w * b2f((unsigned short)(L.x >> 16));
        acc8[2] += w * b2f((unsigned short)(L.y & 0xffffu));
        acc8[3] += w * b2f((unsigned short)(L.y >> 16));
        acc8[4] += w * b2f((unsigned short)(L.z & 0xffffu));
        acc8[5] += w * b2f((unsigned short)(L.z >> 16));
        acc8[6] += w * b2f((unsigned short)(L.w & 0xffffu));
        acc8[7] += w * b2f((unsigned short)(L.w >> 16));
      }
    }
  }
  __syncthreads();
  if (t < 12) rh[t] = (sh[t] > 0.f) ? 1.f/sh[t] : 0.f;
  __syncthreads();
  __hip_bfloat16* fr = featB + (size_t)n*FCOLS;
  a0 *= rh[h0];
  fr[t] = __float2bfloat16(a0);
  if (t < 128) { a1 *= rh[h1]; fr[256 + t] = __float2bfloat16(a1); }
  if (g < 3) {
    #pragma unroll
    for (int j = 0; j < 8; j++) sVE[g][s0 + j] = acc8[j] * rh[myh];
  }
  __syncthreads();
  for (int s = t; s < 672; s += 256) {
    float tot = sVE[0][s] + sVE[1][s] + sVE[2][s];
    if (s < 384) fr[384 + s] = __float2bfloat16(tot);
    else sAgg[s - 384] = tot;
  }
  __syncthreads();
  if (t < 96) {
    int pt = t;
    const float* Rn = R + (size_t)n*9;
    float d0 = sAgg[pt*3+0] - tr[n*3+0];
    float d1 = sAgg[pt*3+1] - tr[n*3+1];
    float d2 = sAgg[pt*3+2] - tr[n*3+2];
    float l0 = Rn[0]*d0 + Rn[3]*d1 + Rn[6]*d2;
    float l1 = Rn[1]*d0 + Rn[4]*d1 + Rn[7]*d2;
    float l2 = Rn[2]*d0 + Rn[5]*d1 + Rn[8]*d2;
    float nr = sqrtf(l0*l0 + l1*l1 + l2*l2);
    float inv = 1.f / fmaxf(nr, 1e-8f);
    fr[768 + pt*3+0] = __float2bfloat16(l0);
    fr[768 + pt*3+1] = __float2bfloat16(l1);
    fr[768 + pt*3+2] = __float2bfloat16(l2);
    fr[1056 + pt]    = __float2bfloat16(nr);
    fr[1152 + pt*3+0] = __float2bfloat16(l0*inv);
    fr[1152 + pt*3+1] = __float2bfloat16(l1*inv);
    fr[1152 + pt*3+2] = __float2bfloat16(l2*inv);
  }
}

// ---------------- MFMA wo: xo = x + featB(20000x1440 bf16) @ Wo + bo
__global__ __launch_bounds__(256) void wo_mfma(
    const __hip_bfloat16* __restrict__ featB, const __hip_bfloat16* __restrict__ WoT,
    const float* __restrict__ bo, const float* __restrict__ x, float* __restrict__ xo)
{
  __shared__ short A_lds[64*104];
  __shared__ short B_lds[128*104];
  const int t = threadIdx.x;
  const int n0 = blockIdx.x * 64;
  const int lane = t & 63, wid = t >> 6;
  const int wm = wid >> 1, wn = wid & 1;
  const int lrow = lane >> 4, lcol = lane & 15;
  f32x4v zero = {0.f, 0.f, 0.f, 0.f};
  f32x4v acc[2][4];
  #pragma unroll
  for (int i = 0; i < 2; i++)
    #pragma unroll
    for (int j = 0; j < 4; j++) acc[i][j] = zero;
  for (int k0 = 0; k0 < 1440; k0 += 96) {
    __syncthreads();
    {
      int r = t >> 2, kc = (t & 3) * 24;
      int gr = n0 + r; if (gr >= NN) gr = NN-1;
      const uint4* src = (const uint4*)(featB + (size_t)gr*FCOLS + k0 + kc);
      uint4 v0 = src[0], v1 = src[1], v2 = src[2];
      *(uint4*)&A_lds[r*104 + kc +  0] = v0;
      *(uint4*)&A_lds[r*104 + kc +  8] = v1;
      *(uint4*)&A_lds[r*104 + kc + 16] = v2;
    }
    {
      int cI = t >> 1, ko = (t & 1) * 48;
      const uint4* src = (const uint4*)(WoT + (size_t)cI*1440 + k0 + ko);
      #pragma unroll
      for (int j = 0; j < 6; j++)
        *(uint4*)&B_lds[cI*104 + ko + j*8] = src[j];
    }
    __syncthreads();
    #pragma unroll
    for (int ks = 0; ks < 3; ks++) {
      int kb = ks*32 + lrow*8;
      bf16x8v a0 = *(const bf16x8v*)&A_lds[(wm*32 +      lcol)*104 + kb];
      bf16x8v a1 = *(const bf16x8v*)&A_lds[(wm*32 + 16 + lcol)*104 + kb];
      #pragma unroll
      for (int nt = 0; nt < 4; nt++) {
        bf16x8v b = *(const bf16x8v*)&B_lds[(wn*64 + nt*16 + lcol)*104 + kb];
        acc[0][nt] = __builtin_amdgcn_mfma_f32_16x16x32_bf16(a0, b, acc[0][nt], 0, 0, 0);
        acc[1][nt] = __builtin_amdgcn_mfma_f32_16x16x32_bf16(a1, b, acc[1][nt], 0, 0, 0);
      }
    }
  }
  #pragma unroll
  for (int nt = 0; nt < 4; nt++) {
    int col = wn*64 + nt*16 + lcol;
    float bv = bo[col];
    #pragma unroll
    for (int mt = 0; mt < 2; mt++) {
      #pragma unroll
      for (int r = 0; r < 4; r++) {
        int grow = n0 + wm*32 + mt*16 + lrow*4 + r;
        if (grow < NN)
          xo[(size_t)grow*128 + col] = acc[mt][nt][r] + bv + x[(size_t)grow*128 + col];
      }
    }
  }
}

// ---------------- LN1 -> MLP -> residual -> LN2, 32 rows/block, 4x4 micro-GEMM
__global__ __launch_bounds__(256) void lnmlp2(
    const float* __restrict__ xo,
    const float* __restrict__ g1, const float* __restrict__ b1v,
    const float* __restrict__ w1, const float* __restrict__ bb1,
    const float* __restrict__ w2, const float* __restrict__ bb2,
    const float* __restrict__ w3, const float* __restrict__ bb3,
    const float* __restrict__ g2, const float* __restrict__ b2v,
    float* __restrict__ out)
{
  __shared__ float smem[17344];
  float* hs   = smem;           // 32 x 132
  float* AT   = smem + 4224;    // 128 x 36
  float* bA   = smem + 8832;    // 32 x 132
  float* bB   = smem + 13056;   // 32 x 132
  float* mu_s = smem + 17280;   // 32
  float* rs_s = smem + 17312;   // 32

  const int t = threadIdx.x, n0 = blockIdx.x * 32;
  const int tx = t & 31, ty = t >> 5;
  const int c = t & 127, rhalf = t >> 7;
  const int w = t >> 6, lane = t & 63;

  for (int e = t; e < 4096; e += 256) {
    int r = e >> 7, cc = e & 127;
    hs[r*132 + cc] = xo[(size_t)(n0 + r)*128 + cc];
  }
  __syncthreads();
  for (int q = 0; q < 8; q++) {
    int r = w*8 + q;
    float v0 = hs[r*132 + lane], v1 = hs[r*132 + lane + 64];
    float s = v0 + v1, ss = v0*v0 + v1*v1;
    #pragma unroll
    for (int m2 = 32; m2 >= 1; m2 >>= 1) { s += __shfl_xor(s, m2); ss += __shfl_xor(ss, m2); }
    if (lane == 0) { float mu = s*(1.f/128.f); mu_s[r] = mu; rs_s[r] = rsqrtf(ss*(1.f/128.f) - mu*mu + 1e-5f); }
  }
  __syncthreads();
  for (int r = rhalf; r < 32; r += 2)
    hs[r*132 + c] = (hs[r*132 + c] - mu_s[r]) * rs_s[r] * g1[c] + b1v[c];
  __syncthreads();

#define MLP_LAYER(INB, OUTB, WG, BG, DO_RELU, DO_RES)                          \
  {                                                                            \
    for (int e = t; e < 4096; e += 256) {                                      \
      int kk = e >> 5, r = e & 31;                                             \
      AT[kk*36 + r] = INB[r*132 + kk];                                         \
    }                                                                          \
    __syncthreads();                                                           \
    float acc[4][4] = {};                                                      \
    const float4* Wg4 = (const float4*)(WG);                                   \
    for (int kk = 0; kk < 128; kk++) {                                         \
      float4 a4 = *(const float4*)&AT[kk*36 + ty*4];                           \
      float4 b4 = Wg4[kk*32 + tx];                                             \
      float av[4] = {a4.x, a4.y, a4.z, a4.w};                                  \
      float bv[4] = {b4.x, b4.y, b4.z, b4.w};                                  \
      _Pragma("unroll")                                                        \
      for (int i2 = 0; i2 < 4; i2++)                                           \
        _Pragma("unroll")                                                      \
        for (int j2 = 0; j2 < 4; j2++)                                         \
          acc[i2][j2] += av[i2] * bv[j2];                                      \
    }                                                                          \
    _Pragma("unroll")                                                          \
    for (int i2 = 0; i2 < 4; i2++) {                                           \
      int r = ty*4 + i2;                                                       \
      _Pragma("unroll")                                                        \
      for (int j2 = 0; j2 < 4; j2++) {                                         \
        int cc2 = tx*4 + j2;                                                   \
        float v = acc[i2][j2] + BG[cc2];                                       \
        if (DO_RES) v += hs[r*132 + cc2];                                      \
        OUTB[r*132 + cc2] = DO_RELU ? fmaxf(v, 0.f) : v;                       \
      }                                                                        \
    }                                                                          \
    __syncthreads();                                                           \
  }

  MLP_LAYER(hs, bA, w1, bb1, 1, 0)
  MLP_LAYER(bA, bB, w2, bb2, 1, 0)
  MLP_LAYER(bB, bA, w3, bb3, 0, 1)
#undef MLP_LAYER

  for (int q = 0; q < 8; q++) {
    int r = w*8 + q;
    float v0 = bA[r*132 + lane], v1 = bA[r*132 + lane + 64];
    float s = v0 + v1, ss = v0*v0 + v1*v1;
    #pragma unroll
    for (int m2 = 32; m2 >= 1; m2 >>= 1) { s += __shfl_xor(s, m2); ss += __shfl_xor(ss, m2); }
    if (lane == 0) { float mu = s*(1.f/128.f); mu_s[r] = mu; rs_s[r] = rsqrtf(ss*(1.f/128.f) - mu*mu + 1e-5f); }
  }
  __syncthreads();
  for (int r = rhalf; r < 32; r += 2)
    out[(size_t)(n0 + r)*128 + c] = (bA[r*132 + c] - mu_s[r]) * rs_s[r] * g2[c] + b2v[c];
}

__global__ void diag_ws(float* out, float v)
{
  if (blockIdx.x == 0 && threadIdx.x == 0) out[0] = v;
}

// ---------------- host side ----------------
static inline size_t alup(size_t v) { return (v + 255) & ~(size_t)255; }

extern "C" void kernel_launch(void* const* d_in, const int* in_sizes, int n_in,
                              void* d_out, int out_size, void* d_ws, size_t ws_size,
                              hipStream_t stream)
{
  const float* R     = (const float*)d_in[0];
  const float* tr    = (const float*)d_in[1];
  const float* x     = (const float*)d_in[2];
  const float* z     = (const float*)d_in[3];
  const int*   ei    = (const int*)  d_in[4];
  const float* Wq    = (const float*)d_in[5];
  const float* Wk    = (const float*)d_in[6];
  const float* Wv    = (const float*)d_in[7];
  const float* Wpair = (const float*)d_in[8];
  const float* spc   = (const float*)d_in[9];
  const float* Wqp   = (const float*)d_in[10];
  const float* Wkp   = (const float*)d_in[11];
  const float* Wvp   = (const float*)d_in[12];
  const float* Wo    = (const float*)d_in[13];
  const float* bo    = (const float*)d_in[14];
  const float* g1    = (const float*)d_in[15];
  const float* b1v   = (const float*)d_in[16];
  const float* w1    = (const float*)d_in[17];
  const float* bb1   = (const float*)d_in[18];
  const float* w2    = (const float*)d_in[19];
  const float* bb2   = (const float*)d_in[20];
  const float* w3    = (const float*)d_in[21];
  const float* bb3   = (const float*)d_in[22];
  const float* g2    = (const float*)d_in[23];
  const float* b2v   = (const float*)d_in[24];
  float* out = (float*)d_out;
  char* ws = (char*)d_ws;

  // region 0: Pq | Pqp | Pkp (f32, dead after build_qe) -> reused as featB
  size_t pq_b  = alup((size_t)NN*PQ_COLS*4);
  size_t pqp_b = alup((size_t)NN*PQP_COLS*4);
  size_t pkp_b = alup((size_t)NN*PKP_COLS*4);
  size_t region = pq_b + pqp_b + pkp_b;
  size_t fb_b = alup((size_t)NN*FCOLS*2);
  if (fb_b > region) region = fb_b;

  float* Pq  = (float*)ws;
  float* Pqp = (float*)(ws + pq_b);
  float* Pkp = (float*)(ws + pq_b + pqp_b);
  __hip_bfloat16* featB = (__hip_bfloat16*)ws;

  size_t off = region;
  __hip_bfloat16* QE = (__hip_bfloat16*)(ws + off); off += alup((size_t)NN*QE_COLS*2);
  __hip_bfloat16* VE = (__hip_bfloat16*)(ws + off); off += alup((size_t)NN*VE_COLS*2);
  __hip_bfloat16* KE = (__hip_bfloat16*)(ws + off); off += alup((size_t)NN*KE_COLS*2);
  float* SKKP = (float*)(ws + off);  off += alup((size_t)NN*12*4);
  int* cnt = (int*)(ws + off);       off += alup((size_t)NN*4);
  int* rowptr = (int*)(ws + off);    off += alup((size_t)(NN+1)*4);
  int* cursor = (int*)(ws + off);    off += alup((size_t)NN*4);
  int* eidx = (int*)(ws + off);      off += alup((size_t)EE*4);
  __hip_bfloat16* XB  = (__hip_bfloat16*)(ws + off); off += alup((size_t)NN*128*2);
  __hip_bfloat16* WBt = (__hip_bfloat16*)(ws + off); off += alup((size_t)2016*128*2);
  __hip_bfloat16* WoT = (__hip_bfloat16*)(ws + off); off += alup((size_t)128*1440*2);
  float* xo = out;

  if (ws_size < off) {
    diag_ws<<<1, 64, 0, stream>>>(out, (float)((double)ws_size / (1024.0*1024.0)));
    return;
  }

  hipMemsetAsync(cnt, 0, (size_t)NN*4, stream);

  cvt_x<<<(NN*128/4 + 255)/256, 256, 0, stream>>>(x, XB);
  cvt_wt<<<(2016*128 + 255)/256, 256, 0, stream>>>(Wq, Wk, Wv, Wqp, Wkp, Wvp, WBt);
  cvt_wot<<<(128*1440 + 255)/256, 256, 0, stream>>>(Wo, WoT);
  proj_mfma<<<dim3((NN + 63)/64, 16), 256, 0, stream>>>(XB, WBt, Pq, Pqp, Pkp, KE, VE);
  transform_pts<<<(NN*288)/256, 256, 0, stream>>>(R, tr, Pqp, Pkp, KE, VE);
  build_qe<<<NN, 256, 0, stream>>>(Pq, Pqp, spc, QE);
  build_skkp<<<NN, 256, 0, stream>>>(KE, spc, SKKP);
  count_edges<<<EE/256, 256, 0, stream>>>(ei, cnt);
  scan_csr<<<1, 1024, 0, stream>>>(cnt, rowptr, cursor);
  fill_csr<<<EE/256, 256, 0, stream>>>(ei, cursor, eidx);
  attn_fused<<<NN, 256, 0, stream>>>(QE, KE, SKKP, VE, z, ei, Wpair,
                                     rowptr, eidx, R, tr, featB);
  wo_mfma<<<(NN + 63)/64, 256, 0, stream>>>(featB, WoT, bo, x, xo);
  lnmlp2<<<NN/32, 256, 0, stream>>>(xo, g1, b1v, w1, bb1, w2, bb2,
                                    w3, bb3, g2, b2v, out);
}

// Round 10
// 550.899 us; speedup vs baseline: 1.7630x; 1.1191x over previous
//
#include <hip/hip_runtime.h>
#include <hip/hip_bf16.h>
#include <math.h>

#define NN 20000
#define EE 320000
#define PQ_COLS  384    // q f32 (dead after prep_node)
#define PQP_COLS 288    // qp local f32 (dead after prep_node)
#define PKP_COLS 288    // kp local f32 (dead after prep_node)
#define QE_COLS  768    // 12 heads x 64 bf16
#define VE_COLS  672    // [v 384 | vp 288] bf16
#define KE_COLS  768    // 12 heads x 64 bf16: [k 32 | kp_global 24 | 0 x8]
#define FCOLS 1440      // [p2n 384 | node 384 | loc 288 | nrm 96 | dirn 288]

typedef __attribute__((ext_vector_type(8))) short bf16x8v;
typedef __attribute__((ext_vector_type(4))) float f32x4v;

__device__ __forceinline__ float b2f(unsigned short u) {
  return __uint_as_float(((unsigned)u) << 16);
}

// ---------------- dtype conversion prekernels
__global__ void cvt_x(const float* __restrict__ x, __hip_bfloat16* __restrict__ XB)
{
  int i = (blockIdx.x*256 + threadIdx.x) * 4;
  if (i >= NN*128) return;
  float4 v = *(const float4*)&x[i];
  XB[i+0] = __float2bfloat16(v.x); XB[i+1] = __float2bfloat16(v.y);
  XB[i+2] = __float2bfloat16(v.z); XB[i+3] = __float2bfloat16(v.w);
}

// merged: WBt[c][k] = W_cat[k][c] (2016x128) and WoT[c][k] = Wo[k][c] (128x1440)
__global__ void cvt_w(const float* __restrict__ Wq, const float* __restrict__ Wk,
                      const float* __restrict__ Wv, const float* __restrict__ Wqp,
                      const float* __restrict__ Wkp, const float* __restrict__ Wvp,
                      const float* __restrict__ Wo,
                      __hip_bfloat16* __restrict__ WBt, __hip_bfloat16* __restrict__ WoT)
{
  int idx = blockIdx.x*256 + threadIdx.x;
  if (idx < 2016*128) {
    int c = idx >> 7, k = idx & 127;
    float v;
    if      (c < 384)  v = Wq [k*384 + c];
    else if (c < 768)  v = Wk [k*384 + (c-384)];
    else if (c < 1152) v = Wv [k*384 + (c-768)];
    else if (c < 1440) v = Wqp[k*288 + (c-1152)];
    else if (c < 1728) v = Wkp[k*288 + (c-1440)];
    else               v = Wvp[k*288 + (c-1728)];
    WBt[idx] = __float2bfloat16(v);
  } else {
    int j = idx - 2016*128;
    if (j < 128*1440) {
      int c = j / 1440, k = j - c*1440;
      WoT[j] = __float2bfloat16(Wo[k*128 + c]);
    }
  }
}

// ---------------- MFMA projection: [XB 20000x128] @ [W 128x2016] -> routed panels
__global__ __launch_bounds__(256) void proj_mfma(
    const __hip_bfloat16* __restrict__ XB, const __hip_bfloat16* __restrict__ WBt,
    float* __restrict__ Pq, float* __restrict__ Pqp, float* __restrict__ Pkp,
    __hip_bfloat16* __restrict__ KE, __hip_bfloat16* __restrict__ VE)
{
  __shared__ short A_lds[64*136];
  __shared__ short B_lds[128*136];
  const int t = threadIdx.x;
  const int n0 = blockIdx.x * 64;
  const int c0 = blockIdx.y * 128;
  {
    int r = t >> 2, kc = (t & 3) * 32;
    int gr = n0 + r; if (gr >= NN) gr = NN-1;
    const uint4* src = (const uint4*)(XB + (size_t)gr*128 + kc);
    uint4 v0 = src[0], v1 = src[1], v2 = src[2], v3 = src[3];
    *(uint4*)&A_lds[r*136 + kc +  0] = v0;
    *(uint4*)&A_lds[r*136 + kc +  8] = v1;
    *(uint4*)&A_lds[r*136 + kc + 16] = v2;
    *(uint4*)&A_lds[r*136 + kc + 24] = v3;
  }
  {
    int cI = t >> 1, ko = (t & 1) * 64;
    int gc = c0 + cI; if (gc > 2015) gc = 2015;
    const uint4* src = (const uint4*)(WBt + (size_t)gc*128 + ko);
    #pragma unroll
    for (int j = 0; j < 8; j++)
      *(uint4*)&B_lds[cI*136 + ko + j*8] = src[j];
  }
  __syncthreads();
  const int lane = t & 63, wid = t >> 6;
  const int wm = wid >> 1, wn = wid & 1;
  const int lrow = lane >> 4, lcol = lane & 15;
  f32x4v zero = {0.f, 0.f, 0.f, 0.f};
  f32x4v acc[2][4];
  #pragma unroll
  for (int i = 0; i < 2; i++)
    #pragma unroll
    for (int j = 0; j < 4; j++) acc[i][j] = zero;
  #pragma unroll
  for (int ks = 0; ks < 4; ks++) {
    int kb = ks*32 + lrow*8;
    bf16x8v a0 = *(const bf16x8v*)&A_lds[(wm*32 +      lcol)*136 + kb];
    bf16x8v a1 = *(const bf16x8v*)&A_lds[(wm*32 + 16 + lcol)*136 + kb];
    #pragma unroll
    for (int nt = 0; nt < 4; nt++) {
      bf16x8v b = *(const bf16x8v*)&B_lds[(wn*64 + nt*16 + lcol)*136 + kb];
      acc[0][nt] = __builtin_amdgcn_mfma_f32_16x16x32_bf16(a0, b, acc[0][nt], 0, 0, 0);
      acc[1][nt] = __builtin_amdgcn_mfma_f32_16x16x32_bf16(a1, b, acc[1][nt], 0, 0, 0);
    }
  }
  #pragma unroll
  for (int nt = 0; nt < 4; nt++) {
    int colb = c0 + wn*64 + nt*16;
    if (colb >= 2016) continue;
    int col = colb + lcol;
    #pragma unroll
    for (int mt = 0; mt < 2; mt++) {
      #pragma unroll
      for (int r = 0; r < 4; r++) {
        int grow = n0 + wm*32 + mt*16 + lrow*4 + r;
        if (grow >= NN) continue;
        float v = acc[mt][nt][r];
        if      (col < 384)  Pq[(size_t)grow*PQ_COLS + col] = v;
        else if (col < 768)  { int d = col-384; KE[(size_t)grow*KE_COLS + (d>>5)*64 + (d&31)] = __float2bfloat16(v); }
        else if (col < 1152) VE[(size_t)grow*VE_COLS + (col-768)] = __float2bfloat16(v);
        else if (col < 1440) Pqp[(size_t)grow*PQP_COLS + (col-1152)] = v;
        else if (col < 1728) Pkp[(size_t)grow*PKP_COLS + (col-1440)] = v;
        else                 VE[(size_t)grow*VE_COLS + 384 + (col-1728)] = __float2bfloat16(v);
      }
    }
  }
}

// ---------------- fused per-node prep: transforms + QE build + SKKP (replaces 3 kernels)
__global__ __launch_bounds__(256) void prep_node(
    const float* __restrict__ Pq, const float* __restrict__ Pqp, const float* __restrict__ Pkp,
    const float* __restrict__ R, const float* __restrict__ tr, const float* __restrict__ spc,
    __hip_bfloat16* __restrict__ QE, __hip_bfloat16* __restrict__ KE,
    __hip_bfloat16* __restrict__ VE, float* __restrict__ SKKP)
{
  __shared__ float qpg[288];
  __shared__ float skk[12], cf[12];
  const int n = blockIdx.x, t = threadIdx.x;
  if (t < 12) { cf[t] = log1pf(expf(spc[t])) * (1.f/12.f); skk[t] = 0.f; }
  __syncthreads();
  const float* Rn = R + (size_t)n*9;
  const float r0=Rn[0],r1=Rn[1],r2=Rn[2],r3=Rn[3],r4=Rn[4],r5=Rn[5],r6=Rn[6],r7=Rn[7],r8=Rn[8];
  const float t0=tr[n*3],t1=tr[n*3+1],t2=tr[n*3+2];
  for (int task = t; task < 288; task += 256) {
    if (task < 96) {
      const float* p = Pqp + (size_t)n*PQP_COLS + task*3;
      float l0=p[0],l1=p[1],l2=p[2];
      qpg[task*3+0] = r0*l0+r1*l1+r2*l2+t0;
      qpg[task*3+1] = r3*l0+r4*l1+r5*l2+t1;
      qpg[task*3+2] = r6*l0+r7*l1+r8*l2+t2;
    } else if (task < 192) {
      int j = task-96, h = j>>3, jj = j&7;
      const float* p = Pkp + (size_t)n*PKP_COLS + h*24 + jj*3;
      float l0=p[0],l1=p[1],l2=p[2];
      __hip_bfloat16 b0=__float2bfloat16(r0*l0+r1*l1+r2*l2+t0);
      __hip_bfloat16 b1=__float2bfloat16(r3*l0+r4*l1+r5*l2+t1);
      __hip_bfloat16 b2=__float2bfloat16(r6*l0+r7*l1+r8*l2+t2);
      __hip_bfloat16* o = KE + (size_t)n*KE_COLS + h*64 + 32 + jj*3;
      o[0]=b0; o[1]=b1; o[2]=b2;
      float f0=__bfloat162float(b0), f1=__bfloat162float(b1), f2=__bfloat162float(b2);
      atomicAdd(&skk[h], f0*f0 + f1*f1 + f2*f2);   // same numerics as before (skk from bf16 kp)
    } else {
      __hip_bfloat16* p = VE + (size_t)n*VE_COLS + 384 + (task-192)*3;
      float l0=__bfloat162float(p[0]), l1=__bfloat162float(p[1]), l2=__bfloat162float(p[2]);
      p[0] = __float2bfloat16(r0*l0+r1*l1+r2*l2+t0);
      p[1] = __float2bfloat16(r3*l0+r4*l1+r5*l2+t1);
      p[2] = __float2bfloat16(r6*l0+r7*l1+r8*l2+t2);
    }
  }
  __syncthreads();
  #pragma unroll
  for (int u = 0; u < 3; u++) {
    int s = t + 256*u;
    int h = s >> 6, i = s & 63;
    float val = 0.f;
    if (i < 32)      val = 0.1020620726f * Pq[(size_t)n*PQ_COLS + h*32 + i];
    else if (i < 56) val = 1.15470053838f * cf[h] * qpg[h*24 + (i-32)];
    QE[(size_t)n*QE_COLS + s] = __float2bfloat16(val);
  }
  if (t < 96) {
    int h = t >> 3, i = t & 7;
    KE[(size_t)n*KE_COLS + h*64 + 56 + i] = __float2bfloat16(0.0f);
    if (i == 0) SKKP[(size_t)n*12 + h] = -0.57735026919f * cf[h] * skk[h];
  }
}

// ---------------- CSR build
__global__ void count_edges(const int* __restrict__ ei, int* __restrict__ cnt)
{
  int e = blockIdx.x*256 + threadIdx.x;
  if (e < EE) atomicAdd(&cnt[ei[e]], 1);
}

__global__ __launch_bounds__(1024) void scan_csr(const int* __restrict__ cnt,
                                                 int* __restrict__ rowptr,
                                                 int* __restrict__ cursor)
{
  __shared__ int part[1024];
  int t = threadIdx.x;
  int base = t*20;
  int loc[20];
  int s = 0;
  #pragma unroll
  for (int i = 0; i < 20; i++) {
    int idx = base + i;
    int cc = (idx < NN) ? cnt[idx] : 0;
    loc[i] = s; s += cc;
  }
  part[t] = s;
  __syncthreads();
  for (int off = 1; off < 1024; off <<= 1) {
    int v = (t >= off) ? part[t-off] : 0;
    __syncthreads();
    part[t] += v;
    __syncthreads();
  }
  int pre = (t == 0) ? 0 : part[t-1];
  #pragma unroll
  for (int i = 0; i < 20; i++) {
    int idx = base + i;
    if (idx < NN) { rowptr[idx] = pre + loc[i]; cursor[idx] = pre + loc[i]; }
  }
  if (t == 1023) rowptr[NN] = part[1023];
}

__global__ void fill_csr(const int* __restrict__ ei, int* __restrict__ cursor,
                         int* __restrict__ eidx)
{
  int e = blockIdx.x*256 + threadIdx.x;
  if (e >= EE) return;
  int pos = atomicAdd(&cursor[ei[e]], 1);
  eidx[pos] = e;
}

__device__ __forceinline__ float dot8(const float* qr, uint4 v) {
  float s;
  s  = qr[0]*b2f((unsigned short)(v.x & 0xffffu));
  s += qr[1]*b2f((unsigned short)(v.x >> 16));
  s += qr[2]*b2f((unsigned short)(v.y & 0xffffu));
  s += qr[3]*b2f((unsigned short)(v.y >> 16));
  s += qr[4]*b2f((unsigned short)(v.z & 0xffffu));
  s += qr[5]*b2f((unsigned short)(v.z >> 16));
  s += qr[6]*b2f((unsigned short)(v.w & 0xffffu));
  s += qr[7]*b2f((unsigned short)(v.w >> 16));
  return s;
}

// ---------------- fused attention: LDS unions + merged max/weights (4 barriers/chunk)
__global__ __launch_bounds__(256) void attn_fused(
    const __hip_bfloat16* __restrict__ QE,
    const __hip_bfloat16* __restrict__ KE, const float* __restrict__ SKKP,
    const __hip_bfloat16* __restrict__ VE,
    const float* __restrict__ z, const int* __restrict__ ei,
    const float* __restrict__ Wpair,
    const int* __restrict__ rowptr, const int* __restrict__ eidx,
    const float* __restrict__ R, const float* __restrict__ tr,
    __hip_bfloat16* __restrict__ featB)
{
  __shared__ float wpT[12*33];
  __shared__ float uBUF[2112];     // z staging [64][33]; after loop: sVE [3][672]
  __shared__ float sLA[64][13];    // pair logits -> weights (in place)
  __shared__ float sLB[64][13];    // KE logits; after loop: sAgg (288 f32)
  __shared__ int   sD[64];
  __shared__ float mh[12], sh[12], rh[12];

  const int n = blockIdx.x, t = threadIdx.x;
  const int beg = rowptr[n], end = rowptr[n+1];
  const int lane = t & 63, wid = t >> 6;
  const float inv_sqrt3 = 0.57735026919f;

  if (t < 12) { mh[t] = -1e30f; sh[t] = 0.f; rh[t] = 0.f; }
  for (int i = t; i < 384; i += 256) {
    int c = i / 12, h = i - 12*c;
    wpT[h*33 + c] = Wpair[i] * inv_sqrt3;
  }
  // per-lane Qe registers (coalesced uint4 loads from QE panel)
  float q0[8], q1[8];
  {
    const uint4* qrow = (const uint4*)(QE + (size_t)n*QE_COLS);
    uint4 Q0 = qrow[lane];
    q0[0]=b2f((unsigned short)(Q0.x&0xffffu)); q0[1]=b2f((unsigned short)(Q0.x>>16));
    q0[2]=b2f((unsigned short)(Q0.y&0xffffu)); q0[3]=b2f((unsigned short)(Q0.y>>16));
    q0[4]=b2f((unsigned short)(Q0.z&0xffffu)); q0[5]=b2f((unsigned short)(Q0.z>>16));
    q0[6]=b2f((unsigned short)(Q0.w&0xffffu)); q0[7]=b2f((unsigned short)(Q0.w>>16));
    if (lane < 32) {
      uint4 Q1 = qrow[64 + lane];
      q1[0]=b2f((unsigned short)(Q1.x&0xffffu)); q1[1]=b2f((unsigned short)(Q1.x>>16));
      q1[2]=b2f((unsigned short)(Q1.y&0xffffu)); q1[3]=b2f((unsigned short)(Q1.y>>16));
      q1[4]=b2f((unsigned short)(Q1.z&0xffffu)); q1[5]=b2f((unsigned short)(Q1.z>>16));
      q1[6]=b2f((unsigned short)(Q1.w&0xffffu)); q1[7]=b2f((unsigned short)(Q1.w>>16));
    } else {
      #pragma unroll
      for (int j = 0; j < 8; j++) q1[j] = 0.f;
    }
  }

  const int h0 = t >> 5;                 // z heads 0..7
  const int h1 = 8 + (t >> 5);           // z heads 8..11 (t < 128)
  const int zc = t & 31;
  const int g   = t / 84;                // 0..3 (g==3: idle in VE loop)
  const int vth = t - g*84;
  const int s0  = vth*8;
  const int myh = (s0 < 384) ? (s0 >> 5) : ((s0 - 384) / 24);
  float a0 = 0.f, a1 = 0.f;
  float acc8[8] = {};

  for (int c0 = beg; c0 < end; c0 += 64) {
    const int cn = min(64, end - c0);
    __syncthreads();                      // B1: protect reused LDS
    if (t < cn) sD[t] = ei[EE + eidx[c0 + t]];
    #pragma unroll
    for (int u = 0; u < 2; u++) {         // stage z rows (f32)
      int idx = t + 256*u;
      int j = idx >> 3, c4 = idx & 7;
      if (j < cn) {
        int e = eidx[c0 + j];
        float4 zz = ((const float4*)(z + (size_t)e*32))[c4];
        uBUF[j*33 + c4*4+0] = zz.x; uBUF[j*33 + c4*4+1] = zz.y;
        uBUF[j*33 + c4*4+2] = zz.z; uBUF[j*33 + c4*4+3] = zz.w;
      }
    }
    __syncthreads();                      // B2
    // pair logits -> sLA
    #pragma unroll
    for (int u = 0; u < 3; u++) {
      int idx = t + 256*u;
      int q = idx / 12, h = idx - 12*q;
      if (q < cn) {
        float acc = 0.f;
        #pragma unroll
        for (int c = 0; c < 32; c++) acc += uBUF[q*33 + c] * wpT[h*33 + c];
        sLA[q][h] = acc;
      }
    }
    // KE logits -> sLB
    #pragma unroll 2
    for (int q = wid; q < cn; q += 4) {
      int dst = sD[q];
      const uint4* ke = (const uint4*)(KE + (size_t)dst*KE_COLS);
      uint4 L0 = ke[lane];
      uint4 L1 = make_uint4(0,0,0,0);
      if (lane < 32) L1 = ke[64 + lane];
      float bc0 = 0.f, bc1 = 0.f;
      if ((lane & 7) == 0) {
        bc0 = SKKP[(size_t)dst*12 + (lane >> 3)];
        if (lane < 32) bc1 = SKKP[(size_t)dst*12 + 8 + (lane >> 3)];
      }
      float p0 = dot8(q0, L0);
      p0 += __shfl_xor(p0, 1); p0 += __shfl_xor(p0, 2); p0 += __shfl_xor(p0, 4);
      float p1 = dot8(q1, L1);
      p1 += __shfl_xor(p1, 1); p1 += __shfl_xor(p1, 2); p1 += __shfl_xor(p1, 4);
      if ((lane & 7) == 0) {
        sLB[q][lane >> 3] = p0 + bc0;
        if (lane < 32) sLB[q][8 + (lane >> 3)] = p1 + bc1;
      }
    }
    __syncthreads();                      // B3
    // merged max + weights + running sums (16-thread head groups, wave-aligned)
    if (t < 192) {
      int h = t >> 4, i = t & 15;
      float mx = -1e30f;
      for (int q = i; q < cn; q += 16) mx = fmaxf(mx, sLA[q][h] + sLB[q][h]);
      #pragma unroll
      for (int m2 = 8; m2 >= 1; m2 >>= 1) mx = fmaxf(mx, __shfl_xor(mx, m2));
      float mn = fmaxf(mh[h], mx);
      float r  = expf(mh[h] - mn);
      float ps = 0.f;
      for (int q = i; q < cn; q += 16) {
        float w = expf(sLA[q][h] + sLB[q][h] - mn);
        sLA[q][h] = w;
        ps += w;
      }
      #pragma unroll
      for (int m2 = 8; m2 >= 1; m2 >>= 1) ps += __shfl_xor(ps, m2);
      if (i == 0) { sh[h] = sh[h]*r + ps; mh[h] = mn; rh[h] = r; }
    }
    __syncthreads();                      // B4
    // rescale + aggregate
    a0 *= rh[h0];
    if (t < 128) a1 *= rh[h1];
    for (int q = 0; q < cn; q++) {
      float zv = uBUF[q*33 + zc];
      a0 += sLA[q][h0] * zv;
      if (t < 128) a1 += sLA[q][h1] * zv;
    }
    if (g < 3) {
      #pragma unroll
      for (int j = 0; j < 8; j++) acc8[j] *= rh[myh];
      #pragma unroll 2
      for (int qq = g; qq < cn; qq += 3) {
        float w = sLA[qq][myh];
        const uint4* ve = (const uint4*)(VE + (size_t)sD[qq]*VE_COLS);
        uint4 L = ve[vth];
        acc8[0] += w * b2f((unsigned short)(L.x & 0xffffu));
        acc8[1] += w * b2f((unsigned short)(L.x >> 16));
        acc8[2] += w * b2f((unsigned short)(L.y & 0xffffu));
        acc8[3] += w * b2f((unsigned short)(L.y >> 16));
        acc8[4] += w * b2f((unsigned short)(L.z & 0xffffu));
        acc8[5] += w * b2f((unsigned short)(L.z >> 16));
        acc8[6] += w * b2f((unsigned short)(L.w & 0xffffu));
        acc8[7] += w * b2f((unsigned short)(L.w >> 16));
      }
    }
  }
  __syncthreads();                        // loop-era LDS reads complete
  if (t < 12) rh[t] = (sh[t] > 0.f) ? 1.f/sh[t] : 0.f;
  __syncthreads();
  __hip_bfloat16* fr = featB + (size_t)n*FCOLS;
  a0 *= rh[h0];
  fr[t] = __float2bfloat16(a0);
  if (t < 128) { a1 *= rh[h1]; fr[256 + t] = __float2bfloat16(a1); }
  if (g < 3) {                            // sVE role of uBUF
    #pragma unroll
    for (int j = 0; j < 8; j++) uBUF[g*672 + s0 + j] = acc8[j] * rh[myh];
  }
  __syncthreads();
  float* sAgg = (float*)sLB;              // sAgg role of sLB
  for (int s = t; s < 672; s += 256) {
    float tot = uBUF[s] + uBUF[672 + s] + uBUF[1344 + s];
    if (s < 384) fr[384 + s] = __float2bfloat16(tot);
    else sAgg[s - 384] = tot;
  }
  __syncthreads();
  if (t < 96) {
    int pt = t;
    const float* Rn = R + (size_t)n*9;
    float d0 = sAgg[pt*3+0] - tr[n*3+0];
    float d1 = sAgg[pt*3+1] - tr[n*3+1];
    float d2 = sAgg[pt*3+2] - tr[n*3+2];
    float l0 = Rn[0]*d0 + Rn[3]*d1 + Rn[6]*d2;
    float l1 = Rn[1]*d0 + Rn[4]*d1 + Rn[7]*d2;
    float l2 = Rn[2]*d0 + Rn[5]*d1 + Rn[8]*d2;
    float nr = sqrtf(l0*l0 + l1*l1 + l2*l2);
    float inv = 1.f / fmaxf(nr, 1e-8f);
    fr[768 + pt*3+0] = __float2bfloat16(l0);
    fr[768 + pt*3+1] = __float2bfloat16(l1);
    fr[768 + pt*3+2] = __float2bfloat16(l2);
    fr[1056 + pt]    = __float2bfloat16(nr);
    fr[1152 + pt*3+0] = __float2bfloat16(l0*inv);
    fr[1152 + pt*3+1] = __float2bfloat16(l1*inv);
    fr[1152 + pt*3+2] = __float2bfloat16(l2*inv);
  }
}

// ---------------- MFMA wo: xo = x + featB(20000x1440 bf16) @ Wo + bo
__global__ __launch_bounds__(256) void wo_mfma(
    const __hip_bfloat16* __restrict__ featB, const __hip_bfloat16* __restrict__ WoT,
    const float* __restrict__ bo, const float* __restrict__ x, float* __restrict__ xo)
{
  __shared__ short A_lds[64*104];
  __shared__ short B_lds[128*104];
  const int t = threadIdx.x;
  const int n0 = blockIdx.x * 64;
  const int lane = t & 63, wid = t >> 6;
  const int wm = wid >> 1, wn = wid & 1;
  const int lrow = lane >> 4, lcol = lane & 15;
  f32x4v zero = {0.f, 0.f, 0.f, 0.f};
  f32x4v acc[2][4];
  #pragma unroll
  for (int i = 0; i < 2; i++)
    #pragma unroll
    for (int j = 0; j < 4; j++) acc[i][j] = zero;
  for (int k0 = 0; k0 < 1440; k0 += 96) {
    __syncthreads();
    {
      int r = t >> 2, kc = (t & 3) * 24;
      int gr = n0 + r; if (gr >= NN) gr = NN-1;
      const uint4* src = (const uint4*)(featB + (size_t)gr*FCOLS + k0 + kc);
      uint4 v0 = src[0], v1 = src[1], v2 = src[2];
      *(uint4*)&A_lds[r*104 + kc +  0] = v0;
      *(uint4*)&A_lds[r*104 + kc +  8] = v1;
      *(uint4*)&A_lds[r*104 + kc + 16] = v2;
    }
    {
      int cI = t >> 1, ko = (t & 1) * 48;
      const uint4* src = (const uint4*)(WoT + (size_t)cI*1440 + k0 + ko);
      #pragma unroll
      for (int j = 0; j < 6; j++)
        *(uint4*)&B_lds[cI*104 + ko + j*8] = src[j];
    }
    __syncthreads();
    #pragma unroll
    for (int ks = 0; ks < 3; ks++) {
      int kb = ks*32 + lrow*8;
      bf16x8v a0 = *(const bf16x8v*)&A_lds[(wm*32 +      lcol)*104 + kb];
      bf16x8v a1 = *(const bf16x8v*)&A_lds[(wm*32 + 16 + lcol)*104 + kb];
      #pragma unroll
      for (int nt = 0; nt < 4; nt++) {
        bf16x8v b = *(const bf16x8v*)&B_lds[(wn*64 + nt*16 + lcol)*104 + kb];
        acc[0][nt] = __builtin_amdgcn_mfma_f32_16x16x32_bf16(a0, b, acc[0][nt], 0, 0, 0);
        acc[1][nt] = __builtin_amdgcn_mfma_f32_16x16x32_bf16(a1, b, acc[1][nt], 0, 0, 0);
      }
    }
  }
  #pragma unroll
  for (int nt = 0; nt < 4; nt++) {
    int col = wn*64 + nt*16 + lcol;
    float bv = bo[col];
    #pragma unroll
    for (int mt = 0; mt < 2; mt++) {
      #pragma unroll
      for (int r = 0; r < 4; r++) {
        int grow = n0 + wm*32 + mt*16 + lrow*4 + r;
        if (grow < NN)
          xo[(size_t)grow*128 + col] = acc[mt][nt][r] + bv + x[(size_t)grow*128 + col];
      }
    }
  }
}

// ---------------- LN1 -> MLP -> residual -> LN2, 32 rows/block, 4x4 micro-GEMM
__global__ __launch_bounds__(256) void lnmlp2(
    const float* __restrict__ xo,
    const float* __restrict__ g1, const float* __restrict__ b1v,
    const float* __restrict__ w1, const float* __restrict__ bb1,
    const float* __restrict__ w2, const float* __restrict__ bb2,
    const float* __restrict__ w3, const float* __restrict__ bb3,
    const float* __restrict__ g2, const float* __restrict__ b2v,
    float* __restrict__ out)
{
  __shared__ float smem[17344];
  float* hs   = smem;           // 32 x 132
  float* AT   = smem + 4224;    // 128 x 36
  float* bA   = smem + 8832;    // 32 x 132
  float* bB   = smem + 13056;   // 32 x 132
  float* mu_s = smem + 17280;   // 32
  float* rs_s = smem + 17312;   // 32

  const int t = threadIdx.x, n0 = blockIdx.x * 32;
  const int tx = t & 31, ty = t >> 5;
  const int c = t & 127, rhalf = t >> 7;
  const int w = t >> 6, lane = t & 63;

  for (int e = t; e < 4096; e += 256) {
    int r = e >> 7, cc = e & 127;
    hs[r*132 + cc] = xo[(size_t)(n0 + r)*128 + cc];
  }
  __syncthreads();
  for (int q = 0; q < 8; q++) {
    int r = w*8 + q;
    float v0 = hs[r*132 + lane], v1 = hs[r*132 + lane + 64];
    float s = v0 + v1, ss = v0*v0 + v1*v1;
    #pragma unroll
    for (int m2 = 32; m2 >= 1; m2 >>= 1) { s += __shfl_xor(s, m2); ss += __shfl_xor(ss, m2); }
    if (lane == 0) { float mu = s*(1.f/128.f); mu_s[r] = mu; rs_s[r] = rsqrtf(ss*(1.f/128.f) - mu*mu + 1e-5f); }
  }
  __syncthreads();
  for (int r = rhalf; r < 32; r += 2)
    hs[r*132 + c] = (hs[r*132 + c] - mu_s[r]) * rs_s[r] * g1[c] + b1v[c];
  __syncthreads();

#define MLP_LAYER(INB, OUTB, WG, BG, DO_RELU, DO_RES)                          \
  {                                                                            \
    for (int e = t; e < 4096; e += 256) {                                      \
      int kk = e >> 5, r = e & 31;                                             \
      AT[kk*36 + r] = INB[r*132 + kk];                                         \
    }                                                                          \
    __syncthreads();                                                           \
    float acc[4][4] = {};                                                      \
    const float4* Wg4 = (const float4*)(WG);                                   \
    for (int kk = 0; kk < 128; kk++) {                                         \
      float4 a4 = *(const float4*)&AT[kk*36 + ty*4];                           \
      float4 b4 = Wg4[kk*32 + tx];                                             \
      float av[4] = {a4.x, a4.y, a4.z, a4.w};                                  \
      float bv[4] = {b4.x, b4.y, b4.z, b4.w};                                  \
      _Pragma("unroll")                                                        \
      for (int i2 = 0; i2 < 4; i2++)                                           \
        _Pragma("unroll")                                                      \
        for (int j2 = 0; j2 < 4; j2++)                                         \
          acc[i2][j2] += av[i2] * bv[j2];                                      \
    }                                                                          \
    _Pragma("unroll")                                                          \
    for (int i2 = 0; i2 < 4; i2++) {                                           \
      int r = ty*4 + i2;                                                       \
      _Pragma("unroll")                                                        \
      for (int j2 = 0; j2 < 4; j2++) {                                         \
        int cc2 = tx*4 + j2;                                                   \
        float v = acc[i2][j2] + BG[cc2];                                       \
        if (DO_RES) v += hs[r*132 + cc2];                                      \
        OUTB[r*132 + cc2] = DO_RELU ? fmaxf(v, 0.f) : v;                       \
      }                                                                        \
    }                                                                          \
    __syncthreads();                                                           \
  }

  MLP_LAYER(hs, bA, w1, bb1, 1, 0)
  MLP_LAYER(bA, bB, w2, bb2, 1, 0)
  MLP_LAYER(bB, bA, w3, bb3, 0, 1)
#undef MLP_LAYER

  for (int q = 0; q < 8; q++) {
    int r = w*8 + q;
    float v0 = bA[r*132 + lane], v1 = bA[r*132 + lane + 64];
    float s = v0 + v1, ss = v0*v0 + v1*v1;
    #pragma unroll
    for (int m2 = 32; m2 >= 1; m2 >>= 1) { s += __shfl_xor(s, m2); ss += __shfl_xor(ss, m2); }
    if (lane == 0) { float mu = s*(1.f/128.f); mu_s[r] = mu; rs_s[r] = rsqrtf(ss*(1.f/128.f) - mu*mu + 1e-5f); }
  }
  __syncthreads();
  for (int r = rhalf; r < 32; r += 2)
    out[(size_t)(n0 + r)*128 + c] = (bA[r*132 + c] - mu_s[r]) * rs_s[r] * g2[c] + b2v[c];
}

__global__ void diag_ws(float* out, float v)
{
  if (blockIdx.x == 0 && threadIdx.x == 0) out[0] = v;
}

// ---------------- host side ----------------
static inline size_t alup(size_t v) { return (v + 255) & ~(size_t)255; }

extern "C" void kernel_launch(void* const* d_in, const int* in_sizes, int n_in,
                              void* d_out, int out_size, void* d_ws, size_t ws_size,
                              hipStream_t stream)
{
  const float* R     = (const float*)d_in[0];
  const float* tr    = (const float*)d_in[1];
  const float* x     = (const float*)d_in[2];
  const float* z     = (const float*)d_in[3];
  const int*   ei    = (const int*)  d_in[4];
  const float* Wq    = (const float*)d_in[5];
  const float* Wk    = (const float*)d_in[6];
  const float* Wv    = (const float*)d_in[7];
  const float* Wpair = (const float*)d_in[8];
  const float* spc   = (const float*)d_in[9];
  const float* Wqp   = (const float*)d_in[10];
  const float* Wkp   = (const float*)d_in[11];
  const float* Wvp   = (const float*)d_in[12];
  const float* Wo    = (const float*)d_in[13];
  const float* bo    = (const float*)d_in[14];
  const float* g1    = (const float*)d_in[15];
  const float* b1v   = (const float*)d_in[16];
  const float* w1    = (const float*)d_in[17];
  const float* bb1   = (const float*)d_in[18];
  const float* w2    = (const float*)d_in[19];
  const float* bb2   = (const float*)d_in[20];
  const float* w3    = (const float*)d_in[21];
  const float* bb3   = (const float*)d_in[22];
  const float* g2    = (const float*)d_in[23];
  const float* b2v   = (const float*)d_in[24];
  float* out = (float*)d_out;
  char* ws = (char*)d_ws;

  // region 0: Pq | Pqp | Pkp (f32, dead after prep_node) -> reused as featB
  size_t pq_b  = alup((size_t)NN*PQ_COLS*4);
  size_t pqp_b = alup((size_t)NN*PQP_COLS*4);
  size_t pkp_b = alup((size_t)NN*PKP_COLS*4);
  size_t region = pq_b + pqp_b + pkp_b;
  size_t fb_b = alup((size_t)NN*FCOLS*2);
  if (fb_b > region) region = fb_b;

  float* Pq  = (float*)ws;
  float* Pqp = (float*)(ws + pq_b);
  float* Pkp = (float*)(ws + pq_b + pqp_b);
  __hip_bfloat16* featB = (__hip_bfloat16*)ws;

  size_t off = region;
  __hip_bfloat16* QE = (__hip_bfloat16*)(ws + off); off += alup((size_t)NN*QE_COLS*2);
  __hip_bfloat16* VE = (__hip_bfloat16*)(ws + off); off += alup((size_t)NN*VE_COLS*2);
  __hip_bfloat16* KE = (__hip_bfloat16*)(ws + off); off += alup((size_t)NN*KE_COLS*2);
  float* SKKP = (float*)(ws + off);  off += alup((size_t)NN*12*4);
  int* cnt = (int*)(ws + off);       off += alup((size_t)NN*4);
  int* rowptr = (int*)(ws + off);    off += alup((size_t)(NN+1)*4);
  int* cursor = (int*)(ws + off);    off += alup((size_t)NN*4);
  int* eidx = (int*)(ws + off);      off += alup((size_t)EE*4);
  __hip_bfloat16* XB  = (__hip_bfloat16*)(ws + off); off += alup((size_t)NN*128*2);
  __hip_bfloat16* WBt = (__hip_bfloat16*)(ws + off); off += alup((size_t)2016*128*2);
  __hip_bfloat16* WoT = (__hip_bfloat16*)(ws + off); off += alup((size_t)128*1440*2);
  float* xo = out;

  if (ws_size < off) {
    diag_ws<<<1, 64, 0, stream>>>(out, (float)((double)ws_size / (1024.0*1024.0)));
    return;
  }

  hipMemsetAsync(cnt, 0, (size_t)NN*4, stream);

  cvt_x<<<(NN*128/4 + 255)/256, 256, 0, stream>>>(x, XB);
  cvt_w<<<(2016*128 + 128*1440 + 255)/256, 256, 0, stream>>>(Wq, Wk, Wv, Wqp, Wkp, Wvp, Wo, WBt, WoT);
  proj_mfma<<<dim3((NN + 63)/64, 16), 256, 0, stream>>>(XB, WBt, Pq, Pqp, Pkp, KE, VE);
  prep_node<<<NN, 256, 0, stream>>>(Pq, Pqp, Pkp, R, tr, spc, QE, KE, VE, SKKP);
  count_edges<<<EE/256, 256, 0, stream>>>(ei, cnt);
  scan_csr<<<1, 1024, 0, stream>>>(cnt, rowptr, cursor);
  fill_csr<<<EE/256, 256, 0, stream>>>(ei, cursor, eidx);
  attn_fused<<<NN, 256, 0, stream>>>(QE, KE, SKKP, VE, z, ei, Wpair,
                                     rowptr, eidx, R, tr, featB);
  wo_mfma<<<(NN + 63)/64, 256, 0, stream>>>(featB, WoT, bo, x, xo);
  lnmlp2<<<NN/32, 256, 0, stream>>>(xo, g1, b1v, w1, bb1, w2, bb2,
                                    w3, bb3, g2, b2v, out);
}

// Round 11
// 452.938 us; speedup vs baseline: 2.1443x; 1.2163x over previous
//
#include <hip/hip_runtime.h>
#include <hip/hip_bf16.h>
#include <math.h>

#define NN 20000
#define EE 320000
#define PQ_COLS  384    // q f32 (dead after prep_node)
#define PQP_COLS 288    // qp local f32 (dead after prep_node)
#define PKP_COLS 288    // kp local f32 (dead after prep_node)
#define QE_COLS  768    // 12 heads x 64 bf16: [c1*q 32 | c2*cf*qp 24 | 0 0 | 1 1 | 0 x4]
#define VE_COLS  672    // [v 384 | vp 288] bf16
#define KE_COLS  768    // 12 heads x 64 bf16: [k 32 | kp_glob 24 | 0 0 | skkp_hi skkp_res | 0 x4]
#define FCOLS 1440      // [p2n 384 | node 384 | loc 288 | nrm 96 | dirn 288]

typedef __attribute__((ext_vector_type(8))) short bf16x8v;
typedef __attribute__((ext_vector_type(4))) float f32x4v;

__device__ __forceinline__ float b2f(unsigned short u) {
  return __uint_as_float(((unsigned)u) << 16);
}
__device__ __forceinline__ unsigned short f2bu(float f) {
  __hip_bfloat16 h = __float2bfloat16(f);
  return *reinterpret_cast<unsigned short*>(&h);
}

// ---------------- dtype conversion prekernels
__global__ void cvt_x(const float* __restrict__ x, __hip_bfloat16* __restrict__ XB)
{
  int i = (blockIdx.x*256 + threadIdx.x) * 4;
  if (i >= NN*128) return;
  float4 v = *(const float4*)&x[i];
  XB[i+0] = __float2bfloat16(v.x); XB[i+1] = __float2bfloat16(v.y);
  XB[i+2] = __float2bfloat16(v.z); XB[i+3] = __float2bfloat16(v.w);
}

__global__ void cvt_w(const float* __restrict__ Wq, const float* __restrict__ Wk,
                      const float* __restrict__ Wv, const float* __restrict__ Wqp,
                      const float* __restrict__ Wkp, const float* __restrict__ Wvp,
                      const float* __restrict__ Wo,
                      __hip_bfloat16* __restrict__ WBt, __hip_bfloat16* __restrict__ WoT)
{
  int idx = blockIdx.x*256 + threadIdx.x;
  if (idx < 2016*128) {
    int c = idx >> 7, k = idx & 127;
    float v;
    if      (c < 384)  v = Wq [k*384 + c];
    else if (c < 768)  v = Wk [k*384 + (c-384)];
    else if (c < 1152) v = Wv [k*384 + (c-768)];
    else if (c < 1440) v = Wqp[k*288 + (c-1152)];
    else if (c < 1728) v = Wkp[k*288 + (c-1440)];
    else               v = Wvp[k*288 + (c-1728)];
    WBt[idx] = __float2bfloat16(v);
  } else {
    int j = idx - 2016*128;
    if (j < 128*1440) {
      int c = j / 1440, k = j - c*1440;
      WoT[j] = __float2bfloat16(Wo[k*128 + c]);
    }
  }
}

// ---------------- MFMA projection (unchanged from r9/r10)
__global__ __launch_bounds__(256) void proj_mfma(
    const __hip_bfloat16* __restrict__ XB, const __hip_bfloat16* __restrict__ WBt,
    float* __restrict__ Pq, float* __restrict__ Pqp, float* __restrict__ Pkp,
    __hip_bfloat16* __restrict__ KE, __hip_bfloat16* __restrict__ VE)
{
  __shared__ short A_lds[64*136];
  __shared__ short B_lds[128*136];
  const int t = threadIdx.x;
  const int n0 = blockIdx.x * 64;
  const int c0 = blockIdx.y * 128;
  {
    int r = t >> 2, kc = (t & 3) * 32;
    int gr = n0 + r; if (gr >= NN) gr = NN-1;
    const uint4* src = (const uint4*)(XB + (size_t)gr*128 + kc);
    uint4 v0 = src[0], v1 = src[1], v2 = src[2], v3 = src[3];
    *(uint4*)&A_lds[r*136 + kc +  0] = v0;
    *(uint4*)&A_lds[r*136 + kc +  8] = v1;
    *(uint4*)&A_lds[r*136 + kc + 16] = v2;
    *(uint4*)&A_lds[r*136 + kc + 24] = v3;
  }
  {
    int cI = t >> 1, ko = (t & 1) * 64;
    int gc = c0 + cI; if (gc > 2015) gc = 2015;
    const uint4* src = (const uint4*)(WBt + (size_t)gc*128 + ko);
    #pragma unroll
    for (int j = 0; j < 8; j++)
      *(uint4*)&B_lds[cI*136 + ko + j*8] = src[j];
  }
  __syncthreads();
  const int lane = t & 63, wid = t >> 6;
  const int wm = wid >> 1, wn = wid & 1;
  const int lrow = lane >> 4, lcol = lane & 15;
  f32x4v zero = {0.f, 0.f, 0.f, 0.f};
  f32x4v acc[2][4];
  #pragma unroll
  for (int i = 0; i < 2; i++)
    #pragma unroll
    for (int j = 0; j < 4; j++) acc[i][j] = zero;
  #pragma unroll
  for (int ks = 0; ks < 4; ks++) {
    int kb = ks*32 + lrow*8;
    bf16x8v a0 = *(const bf16x8v*)&A_lds[(wm*32 +      lcol)*136 + kb];
    bf16x8v a1 = *(const bf16x8v*)&A_lds[(wm*32 + 16 + lcol)*136 + kb];
    #pragma unroll
    for (int nt = 0; nt < 4; nt++) {
      bf16x8v b = *(const bf16x8v*)&B_lds[(wn*64 + nt*16 + lcol)*136 + kb];
      acc[0][nt] = __builtin_amdgcn_mfma_f32_16x16x32_bf16(a0, b, acc[0][nt], 0, 0, 0);
      acc[1][nt] = __builtin_amdgcn_mfma_f32_16x16x32_bf16(a1, b, acc[1][nt], 0, 0, 0);
    }
  }
  #pragma unroll
  for (int nt = 0; nt < 4; nt++) {
    int colb = c0 + wn*64 + nt*16;
    if (colb >= 2016) continue;
    int col = colb + lcol;
    #pragma unroll
    for (int mt = 0; mt < 2; mt++) {
      #pragma unroll
      for (int r = 0; r < 4; r++) {
        int grow = n0 + wm*32 + mt*16 + lrow*4 + r;
        if (grow >= NN) continue;
        float v = acc[mt][nt][r];
        if      (col < 384)  Pq[(size_t)grow*PQ_COLS + col] = v;
        else if (col < 768)  { int d = col-384; KE[(size_t)grow*KE_COLS + (d>>5)*64 + (d&31)] = __float2bfloat16(v); }
        else if (col < 1152) VE[(size_t)grow*VE_COLS + (col-768)] = __float2bfloat16(v);
        else if (col < 1440) Pqp[(size_t)grow*PQP_COLS + (col-1152)] = v;
        else if (col < 1728) Pkp[(size_t)grow*PKP_COLS + (col-1440)] = v;
        else                 VE[(size_t)grow*VE_COLS + 384 + (col-1728)] = __float2bfloat16(v);
      }
    }
  }
}

// ---------------- fused per-node prep: transforms + QE + skkp-in-KE(58,59)
__global__ __launch_bounds__(256) void prep_node(
    const float* __restrict__ Pq, const float* __restrict__ Pqp, const float* __restrict__ Pkp,
    const float* __restrict__ R, const float* __restrict__ tr, const float* __restrict__ spc,
    __hip_bfloat16* __restrict__ QE, __hip_bfloat16* __restrict__ KE,
    __hip_bfloat16* __restrict__ VE)
{
  __shared__ float qpg[288];
  __shared__ float skk[12], cf[12];
  const int n = blockIdx.x, t = threadIdx.x;
  if (t < 12) { cf[t] = log1pf(expf(spc[t])) * (1.f/12.f); skk[t] = 0.f; }
  __syncthreads();
  const float* Rn = R + (size_t)n*9;
  const float r0=Rn[0],r1=Rn[1],r2=Rn[2],r3=Rn[3],r4=Rn[4],r5=Rn[5],r6=Rn[6],r7=Rn[7],r8=Rn[8];
  const float t0=tr[n*3],t1=tr[n*3+1],t2=tr[n*3+2];
  for (int task = t; task < 288; task += 256) {
    if (task < 96) {
      const float* p = Pqp + (size_t)n*PQP_COLS + task*3;
      float l0=p[0],l1=p[1],l2=p[2];
      qpg[task*3+0] = r0*l0+r1*l1+r2*l2+t0;
      qpg[task*3+1] = r3*l0+r4*l1+r5*l2+t1;
      qpg[task*3+2] = r6*l0+r7*l1+r8*l2+t2;
    } else if (task < 192) {
      int j = task-96, h = j>>3, jj = j&7;
      const float* p = Pkp + (size_t)n*PKP_COLS + h*24 + jj*3;
      float l0=p[0],l1=p[1],l2=p[2];
      __hip_bfloat16 b0=__float2bfloat16(r0*l0+r1*l1+r2*l2+t0);
      __hip_bfloat16 b1=__float2bfloat16(r3*l0+r4*l1+r5*l2+t1);
      __hip_bfloat16 b2=__float2bfloat16(r6*l0+r7*l1+r8*l2+t2);
      __hip_bfloat16* o = KE + (size_t)n*KE_COLS + h*64 + 32 + jj*3;
      o[0]=b0; o[1]=b1; o[2]=b2;
      float f0=__bfloat162float(b0), f1=__bfloat162float(b1), f2=__bfloat162float(b2);
      atomicAdd(&skk[h], f0*f0 + f1*f1 + f2*f2);
    } else {
      __hip_bfloat16* p = VE + (size_t)n*VE_COLS + 384 + (task-192)*3;
      float l0=__bfloat162float(p[0]), l1=__bfloat162float(p[1]), l2=__bfloat162float(p[2]);
      p[0] = __float2bfloat16(r0*l0+r1*l1+r2*l2+t0);
      p[1] = __float2bfloat16(r3*l0+r4*l1+r5*l2+t1);
      p[2] = __float2bfloat16(r6*l0+r7*l1+r8*l2+t2);
    }
  }
  __syncthreads();
  #pragma unroll
  for (int u = 0; u < 3; u++) {
    int s = t + 256*u;
    int h = s >> 6, i = s & 63;
    float val = 0.f;
    if (i < 32)      val = 0.1020620726f * Pq[(size_t)n*PQ_COLS + h*32 + i];
    else if (i < 56) val = 1.15470053838f * cf[h] * qpg[h*24 + (i-32)];
    else if (i == 58 || i == 59) val = 1.0f;     // multiplies skkp_hi/res in KE
    QE[(size_t)n*QE_COLS + s] = __float2bfloat16(val);
  }
  if (t < 96) {
    int h = t >> 3, i = t & 7;                    // pad slot 56+i
    float skkp = -0.57735026919f * cf[h] * skk[h];
    __hip_bfloat16 hi = __float2bfloat16(skkp);
    float res = skkp - __bfloat162float(hi);
    __hip_bfloat16 outv;
    if (i == 2)      outv = hi;
    else if (i == 3) outv = __float2bfloat16(res);
    else             outv = __float2bfloat16(0.0f);
    KE[(size_t)n*KE_COLS + h*64 + 56 + i] = outv;
  }
}

// ---------------- pair-logit panel: PL[e][h] = sqrt(1/3) * z[e] . Wpair[:,h]
__global__ __launch_bounds__(256) void pl_kernel(
    const float* __restrict__ z, const float* __restrict__ Wpair, float* __restrict__ PL)
{
  __shared__ float wp[384];
  const int t = threadIdx.x;
  for (int i = t; i < 384; i += 256) wp[i] = Wpair[i] * 0.57735026919f;
  __syncthreads();
  int e0 = blockIdx.x * 64;
  #pragma unroll
  for (int u = 0; u < 3; u++) {
    int idx = t + 256*u;
    int q = idx / 12, h = idx - 12*q;
    int e = e0 + q;
    if (q < 64 && e < EE) {
      const float* zr = z + (size_t)e*32;
      float s = 0.f;
      #pragma unroll
      for (int c = 0; c < 32; c++) s += zr[c] * wp[c*12 + h];
      PL[(size_t)e*12 + h] = s;
    }
  }
}

// ---------------- CSR build
__global__ void count_edges(const int* __restrict__ ei, int* __restrict__ cnt)
{
  int e = blockIdx.x*256 + threadIdx.x;
  if (e < EE) atomicAdd(&cnt[ei[e]], 1);
}

__global__ __launch_bounds__(1024) void scan_csr(const int* __restrict__ cnt,
                                                 int* __restrict__ rowptr,
                                                 int* __restrict__ cursor)
{
  __shared__ int part[1024];
  int t = threadIdx.x;
  int base = t*20;
  int loc[20];
  int s = 0;
  #pragma unroll
  for (int i = 0; i < 20; i++) {
    int idx = base + i;
    int cc = (idx < NN) ? cnt[idx] : 0;
    loc[i] = s; s += cc;
  }
  part[t] = s;
  __syncthreads();
  for (int off = 1; off < 1024; off <<= 1) {
    int v = (t >= off) ? part[t-off] : 0;
    __syncthreads();
    part[t] += v;
    __syncthreads();
  }
  int pre = (t == 0) ? 0 : part[t-1];
  #pragma unroll
  for (int i = 0; i < 20; i++) {
    int idx = base + i;
    if (idx < NN) { rowptr[idx] = pre + loc[i]; cursor[idx] = pre + loc[i]; }
  }
  if (t == 1023) rowptr[NN] = part[1023];
}

__global__ void fill_csr(const int* __restrict__ ei, int* __restrict__ cursor,
                         int* __restrict__ eidx, int* __restrict__ dstE)
{
  int e = blockIdx.x*256 + threadIdx.x;
  if (e >= EE) return;
  int pos = atomicAdd(&cursor[ei[e]], 1);
  eidx[pos] = e;
  dstE[pos] = ei[EE + e];
}

__device__ __forceinline__ float dot8(const float* qr, uint4 v) {
  float s;
  s  = qr[0]*b2f((unsigned short)(v.x & 0xffffu));
  s += qr[1]*b2f((unsigned short)(v.x >> 16));
  s += qr[2]*b2f((unsigned short)(v.y & 0xffffu));
  s += qr[3]*b2f((unsigned short)(v.y >> 16));
  s += qr[4]*b2f((unsigned short)(v.z & 0xffffu));
  s += qr[5]*b2f((unsigned short)(v.z >> 16));
  s += qr[6]*b2f((unsigned short)(v.w & 0xffffu));
  s += qr[7]*b2f((unsigned short)(v.w >> 16));
  return s;
}

// ---------------- wave-per-node fused attention (no barriers in edge loop)
__global__ __launch_bounds__(256) void attn_wave(
    const __hip_bfloat16* __restrict__ QE,
    const __hip_bfloat16* __restrict__ KE,
    const __hip_bfloat16* __restrict__ VE,
    const float* __restrict__ z, const float* __restrict__ PL,
    const int* __restrict__ rowptr, const int* __restrict__ eidx,
    const int* __restrict__ dstE,
    const float* __restrict__ R, const float* __restrict__ tr,
    __hip_bfloat16* __restrict__ featB)
{
  __shared__ float sAgg[4][288];
  const int wid = threadIdx.x >> 6, lane = threadIdx.x & 63;
  const int n = blockIdx.x*4 + wid;          // grid = 5000, exact

  // per-lane Qe regs (heads 0-7 in q0 over all lanes; heads 8-11 in q1 over lanes<32)
  float q0[8], q1[8];
  {
    const uint4* qrow = (const uint4*)(QE + (size_t)n*QE_COLS);
    uint4 Q0 = qrow[lane];
    q0[0]=b2f((unsigned short)(Q0.x&0xffffu)); q0[1]=b2f((unsigned short)(Q0.x>>16));
    q0[2]=b2f((unsigned short)(Q0.y&0xffffu)); q0[3]=b2f((unsigned short)(Q0.y>>16));
    q0[4]=b2f((unsigned short)(Q0.z&0xffffu)); q0[5]=b2f((unsigned short)(Q0.z>>16));
    q0[6]=b2f((unsigned short)(Q0.w&0xffffu)); q0[7]=b2f((unsigned short)(Q0.w>>16));
    if (lane < 32) {
      uint4 Q1 = qrow[64 + lane];
      q1[0]=b2f((unsigned short)(Q1.x&0xffffu)); q1[1]=b2f((unsigned short)(Q1.x>>16));
      q1[2]=b2f((unsigned short)(Q1.y&0xffffu)); q1[3]=b2f((unsigned short)(Q1.y>>16));
      q1[4]=b2f((unsigned short)(Q1.z&0xffffu)); q1[5]=b2f((unsigned short)(Q1.z>>16));
      q1[6]=b2f((unsigned short)(Q1.w&0xffffu)); q1[7]=b2f((unsigned short)(Q1.w>>16));
    } else {
      #pragma unroll
      for (int j = 0; j < 8; j++) q1[j] = 0.f;
    }
  }

  // accumulator slot->head maps
  const int myh0 = (lane < 48) ? (lane >> 2) : ((8*lane - 384) / 24);  // uint4 slot `lane`
  const int myh1 = (128 + 8*lane) / 24;                                // uint4 slot 64+lane (<20)

  float mreg = -1e30f, sreg = 0.f;
  float accV0[8] = {}, accV1[8] = {}, accZ[12] = {};

  const int beg = rowptr[n], end = rowptr[n+1];
  for (int c0 = beg; c0 < end; c0 += 64) {
    const int cn = min(64, end - c0);
    int eL = (lane < cn) ? eidx[c0 + lane] : 0;
    int dL = (lane < cn) ? dstE[c0 + lane] : 0;
    for (int j = 0; j < cn; j++) {
      const int e   = __shfl(eL, j);
      const int dst = __shfl(dL, j);
      // gathers (independent across j -> pipelined)
      const uint4* ke = (const uint4*)(KE + (size_t)dst*KE_COLS);
      uint4 K0 = ke[lane];
      uint4 K1 = make_uint4(0,0,0,0);
      if (lane < 32) K1 = ke[64 + lane];
      const uint4* ve = (const uint4*)(VE + (size_t)dst*VE_COLS);
      uint4 V0 = ve[lane];                       // 64 of 84 uint4
      uint4 V1 = make_uint4(0,0,0,0);
      if (lane < 20) V1 = ve[64 + lane];
      float zc = (lane < 32) ? z[(size_t)e*32 + lane] : 0.f;
      float pl = (lane < 12) ? PL[(size_t)e*12 + lane] : 0.f;
      // KE-dot logits (node + spatial + skkp, all folded)
      float p0 = dot8(q0, K0);
      p0 += __shfl_xor(p0, 1); p0 += __shfl_xor(p0, 2); p0 += __shfl_xor(p0, 4);
      float p1 = dot8(q1, K1);
      p1 += __shfl_xor(p1, 1); p1 += __shfl_xor(p1, 2); p1 += __shfl_xor(p1, 4);
      float pa = __shfl(p0, (lane & 7) * 8);
      float pb = __shfl(p1, (lane & 3) * 8);
      float lg = ((lane < 8) ? pa : pb) + pl;    // lanes 0-11 hold head logits
      // online softmax (lanes 0-11 meaningful)
      float mn = fmaxf(mreg, lg);
      unsigned long long chg = __ballot(mn > mreg) & 0xFFFull;
      float w = expf(lg - mn);
      float r = expf(mreg - mn);
      mreg = mn;
      sreg = sreg * r + w;
      if (chg) {                                  // wave-uniform
        float rv0 = __shfl(r, myh0);
        #pragma unroll
        for (int q2 = 0; q2 < 8; q2++) accV0[q2] *= rv0;
        float rv1 = __shfl(r, myh1);
        if (lane < 20) {
          #pragma unroll
          for (int q2 = 0; q2 < 8; q2++) accV1[q2] *= rv1;
        }
        #pragma unroll
        for (int h = 0; h < 12; h++) accZ[h] *= __shfl(r, h);
      }
      // accumulate
      float wv0 = __shfl(w, myh0);
      accV0[0] += wv0 * b2f((unsigned short)(V0.x & 0xffffu));
      accV0[1] += wv0 * b2f((unsigned short)(V0.x >> 16));
      accV0[2] += wv0 * b2f((unsigned short)(V0.y & 0xffffu));
      accV0[3] += wv0 * b2f((unsigned short)(V0.y >> 16));
      accV0[4] += wv0 * b2f((unsigned short)(V0.z & 0xffffu));
      accV0[5] += wv0 * b2f((unsigned short)(V0.z >> 16));
      accV0[6] += wv0 * b2f((unsigned short)(V0.w & 0xffffu));
      accV0[7] += wv0 * b2f((unsigned short)(V0.w >> 16));
      float wv1 = __shfl(w, myh1);
      if (lane < 20) {
        accV1[0] += wv1 * b2f((unsigned short)(V1.x & 0xffffu));
        accV1[1] += wv1 * b2f((unsigned short)(V1.x >> 16));
        accV1[2] += wv1 * b2f((unsigned short)(V1.y & 0xffffu));
        accV1[3] += wv1 * b2f((unsigned short)(V1.y >> 16));
        accV1[4] += wv1 * b2f((unsigned short)(V1.z & 0xffffu));
        accV1[5] += wv1 * b2f((unsigned short)(V1.z >> 16));
        accV1[6] += wv1 * b2f((unsigned short)(V1.w & 0xffffu));
        accV1[7] += wv1 * b2f((unsigned short)(V1.w >> 16));
      }
      #pragma unroll
      for (int h = 0; h < 12; h++) accZ[h] += __shfl(w, h) * zc;
    }
  }

  // epilogue
  float inv = 0.f;
  if (lane < 12) inv = (sreg > 0.f) ? 1.f/sreg : 0.f;
  __hip_bfloat16* fr = featB + (size_t)n*FCOLS;
  // p2n: fr[h*32+c]
  #pragma unroll
  for (int h = 0; h < 12; h++) {
    float iv = __shfl(inv, h);
    if (lane < 32) fr[h*32 + lane] = __float2bfloat16(accZ[h] * iv);
  }
  float iv0 = __shfl(inv, myh0);
  if (lane < 48) {         // v part -> fr[384 + lane*8 ..]
    uint4 P;
    P.x = (unsigned)f2bu(accV0[0]*iv0) | ((unsigned)f2bu(accV0[1]*iv0) << 16);
    P.y = (unsigned)f2bu(accV0[2]*iv0) | ((unsigned)f2bu(accV0[3]*iv0) << 16);
    P.z = (unsigned)f2bu(accV0[4]*iv0) | ((unsigned)f2bu(accV0[5]*iv0) << 16);
    P.w = (unsigned)f2bu(accV0[6]*iv0) | ((unsigned)f2bu(accV0[7]*iv0) << 16);
    *(uint4*)(fr + 384 + lane*8) = P;
  } else {                 // vp slots 0..127 -> LDS
    #pragma unroll
    for (int j2 = 0; j2 < 8; j2++) sAgg[wid][(lane-48)*8 + j2] = accV0[j2]*iv0;
  }
  float iv1 = __shfl(inv, myh1);
  if (lane < 20) {         // vp slots 128..287 -> LDS
    #pragma unroll
    for (int j2 = 0; j2 < 8; j2++) sAgg[wid][128 + lane*8 + j2] = accV1[j2]*iv1;
  }
  __syncthreads();
  // spatial: 96 points per node
  {
    const float* Rn = R + (size_t)n*9;
    float t0 = tr[n*3], t1 = tr[n*3+1], t2 = tr[n*3+2];
    #pragma unroll
    for (int pp = 0; pp < 2; pp++) {
      int pt = lane + pp*64;
      if (pt < 96) {
        float d0 = sAgg[wid][pt*3+0] - t0;
        float d1 = sAgg[wid][pt*3+1] - t1;
        float d2 = sAgg[wid][pt*3+2] - t2;
        float l0 = Rn[0]*d0 + Rn[3]*d1 + Rn[6]*d2;
        float l1 = Rn[1]*d0 + Rn[4]*d1 + Rn[7]*d2;
        float l2 = Rn[2]*d0 + Rn[5]*d1 + Rn[8]*d2;
        float nr = sqrtf(l0*l0 + l1*l1 + l2*l2);
        float ivn = 1.f / fmaxf(nr, 1e-8f);
        fr[768 + pt*3+0] = __float2bfloat16(l0);
        fr[768 + pt*3+1] = __float2bfloat16(l1);
        fr[768 + pt*3+2] = __float2bfloat16(l2);
        fr[1056 + pt]    = __float2bfloat16(nr);
        fr[1152 + pt*3+0] = __float2bfloat16(l0*ivn);
        fr[1152 + pt*3+1] = __float2bfloat16(l1*ivn);
        fr[1152 + pt*3+2] = __float2bfloat16(l2*ivn);
      }
    }
  }
}

// ---------------- MFMA wo, 2-way K-split: slice0 -> xo (+bo+x), slice1 -> XO2
__global__ __launch_bounds__(256) void wo_mfma(
    const __hip_bfloat16* __restrict__ featB, const __hip_bfloat16* __restrict__ WoT,
    const float* __restrict__ bo, const float* __restrict__ x,
    float* __restrict__ xo, float* __restrict__ XO2)
{
  __shared__ short A_lds[64*104];
  __shared__ short B_lds[128*104];
  const int t = threadIdx.x;
  const int n0 = blockIdx.x * 64;
  const int ysl = blockIdx.y;
  const int kbeg = ysl ? 768 : 0;
  const int kend = ysl ? 1440 : 768;
  const int lane = t & 63, wid = t >> 6;
  const int wm = wid >> 1, wn = wid & 1;
  const int lrow = lane >> 4, lcol = lane & 15;
  f32x4v zero = {0.f, 0.f, 0.f, 0.f};
  f32x4v acc[2][4];
  #pragma unroll
  for (int i = 0; i < 2; i++)
    #pragma unroll
    for (int j = 0; j < 4; j++) acc[i][j] = zero;
  for (int k0 = kbeg; k0 < kend; k0 += 96) {
    __syncthreads();
    {
      int r = t >> 2, kc = (t & 3) * 24;
      int gr = n0 + r; if (gr >= NN) gr = NN-1;
      const uint4* src = (const uint4*)(featB + (size_t)gr*FCOLS + k0 + kc);
      uint4 v0 = src[0], v1 = src[1], v2 = src[2];
      *(uint4*)&A_lds[r*104 + kc +  0] = v0;
      *(uint4*)&A_lds[r*104 + kc +  8] = v1;
      *(uint4*)&A_lds[r*104 + kc + 16] = v2;
    }
    {
      int cI = t >> 1, ko = (t & 1) * 48;
      const uint4* src = (const uint4*)(WoT + (size_t)cI*1440 + k0 + ko);
      #pragma unroll
      for (int j = 0; j < 6; j++)
        *(uint4*)&B_lds[cI*104 + ko + j*8] = src[j];
    }
    __syncthreads();
    #pragma unroll
    for (int ks = 0; ks < 3; ks++) {
      int kb = ks*32 + lrow*8;
      bf16x8v a0 = *(const bf16x8v*)&A_lds[(wm*32 +      lcol)*104 + kb];
      bf16x8v a1 = *(const bf16x8v*)&A_lds[(wm*32 + 16 + lcol)*104 + kb];
      #pragma unroll
      for (int nt = 0; nt < 4; nt++) {
        bf16x8v b = *(const bf16x8v*)&B_lds[(wn*64 + nt*16 + lcol)*104 + kb];
        acc[0][nt] = __builtin_amdgcn_mfma_f32_16x16x32_bf16(a0, b, acc[0][nt], 0, 0, 0);
        acc[1][nt] = __builtin_amdgcn_mfma_f32_16x16x32_bf16(a1, b, acc[1][nt], 0, 0, 0);
      }
    }
  }
  #pragma unroll
  for (int nt = 0; nt < 4; nt++) {
    int col = wn*64 + nt*16 + lcol;
    float bv = bo[col];
    #pragma unroll
    for (int mt = 0; mt < 2; mt++) {
      #pragma unroll
      for (int r = 0; r < 4; r++) {
        int grow = n0 + wm*32 + mt*16 + lrow*4 + r;
        if (grow < NN) {
          if (ysl == 0)
            xo[(size_t)grow*128 + col] = acc[mt][nt][r] + bv + x[(size_t)grow*128 + col];
          else
            XO2[(size_t)grow*128 + col] = acc[mt][nt][r];
        }
      }
    }
  }
}

// ---------------- LN1 -> MLP -> residual -> LN2 (reads xo + XO2 partial)
__global__ __launch_bounds__(256) void lnmlp2(
    const float* __restrict__ xo, const float* __restrict__ XO2,
    const float* __restrict__ g1, const float* __restrict__ b1v,
    const float* __restrict__ w1, const float* __restrict__ bb1,
    const float* __restrict__ w2, const float* __restrict__ bb2,
    const float* __restrict__ w3, const float* __restrict__ bb3,
    const float* __restrict__ g2, const float* __restrict__ b2v,
    float* __restrict__ out)
{
  __shared__ float smem[17344];
  float* hs   = smem;
  float* AT   = smem + 4224;
  float* bA   = smem + 8832;
  float* bB   = smem + 13056;
  float* mu_s = smem + 17280;
  float* rs_s = smem + 17312;

  const int t = threadIdx.x, n0 = blockIdx.x * 32;
  const int tx = t & 31, ty = t >> 5;
  const int c = t & 127, rhalf = t >> 7;
  const int w = t >> 6, lane = t & 63;

  for (int e = t; e < 4096; e += 256) {
    int r = e >> 7, cc = e & 127;
    hs[r*132 + cc] = xo[(size_t)(n0 + r)*128 + cc] + XO2[(size_t)(n0 + r)*128 + cc];
  }
  __syncthreads();
  for (int q = 0; q < 8; q++) {
    int r = w*8 + q;
    float v0 = hs[r*132 + lane], v1 = hs[r*132 + lane + 64];
    float s = v0 + v1, ss = v0*v0 + v1*v1;
    #pragma unroll
    for (int m2 = 32; m2 >= 1; m2 >>= 1) { s += __shfl_xor(s, m2); ss += __shfl_xor(ss, m2); }
    if (lane == 0) { float mu = s*(1.f/128.f); mu_s[r] = mu; rs_s[r] = rsqrtf(ss*(1.f/128.f) - mu*mu + 1e-5f); }
  }
  __syncthreads();
  for (int r = rhalf; r < 32; r += 2)
    hs[r*132 + c] = (hs[r*132 + c] - mu_s[r]) * rs_s[r] * g1[c] + b1v[c];
  __syncthreads();

#define MLP_LAYER(INB, OUTB, WG, BG, DO_RELU, DO_RES)                          \
  {                                                                            \
    for (int e = t; e < 4096; e += 256) {                                      \
      int kk = e >> 5, r = e & 31;                                             \
      AT[kk*36 + r] = INB[r*132 + kk];                                         \
    }                                                                          \
    __syncthreads();                                                           \
    float acc[4][4] = {};                                                      \
    const float4* Wg4 = (const float4*)(WG);                                   \
    for (int kk = 0; kk < 128; kk++) {                                         \
      float4 a4 = *(const float4*)&AT[kk*36 + ty*4];                           \
      float4 b4 = Wg4[kk*32 + tx];                                             \
      float av[4] = {a4.x, a4.y, a4.z, a4.w};                                  \
      float bv[4] = {b4.x, b4.y, b4.z, b4.w};                                  \
      _Pragma("unroll")                                                        \
      for (int i2 = 0; i2 < 4; i2++)                                           \
        _Pragma("unroll")                                                      \
        for (int j2 = 0; j2 < 4; j2++)                                         \
          acc[i2][j2] += av[i2] * bv[j2];                                      \
    }                                                                          \
    _Pragma("unroll")                                                          \
    for (int i2 = 0; i2 < 4; i2++) {                                           \
      int r = ty*4 + i2;                                                       \
      _Pragma("unroll")                                                        \
      for (int j2 = 0; j2 < 4; j2++) {                                         \
        int cc2 = tx*4 + j2;                                                   \
        float v = acc[i2][j2] + BG[cc2];                                       \
        if (DO_RES) v += hs[r*132 + cc2];                                      \
        OUTB[r*132 + cc2] = DO_RELU ? fmaxf(v, 0.f) : v;                       \
      }                                                                        \
    }                                                                          \
    __syncthreads();                                                           \
  }

  MLP_LAYER(hs, bA, w1, bb1, 1, 0)
  MLP_LAYER(bA, bB, w2, bb2, 1, 0)
  MLP_LAYER(bB, bA, w3, bb3, 0, 1)
#undef MLP_LAYER

  for (int q = 0; q < 8; q++) {
    int r = w*8 + q;
    float v0 = bA[r*132 + lane], v1 = bA[r*132 + lane + 64];
    float s = v0 + v1, ss = v0*v0 + v1*v1;
    #pragma unroll
    for (int m2 = 32; m2 >= 1; m2 >>= 1) { s += __shfl_xor(s, m2); ss += __shfl_xor(ss, m2); }
    if (lane == 0) { float mu = s*(1.f/128.f); mu_s[r] = mu; rs_s[r] = rsqrtf(ss*(1.f/128.f) - mu*mu + 1e-5f); }
  }
  __syncthreads();
  for (int r = rhalf; r < 32; r += 2)
    out[(size_t)(n0 + r)*128 + c] = (bA[r*132 + c] - mu_s[r]) * rs_s[r] * g2[c] + b2v[c];
}

__global__ void diag_ws(float* out, float v)
{
  if (blockIdx.x == 0 && threadIdx.x == 0) out[0] = v;
}

// ---------------- host side ----------------
static inline size_t alup(size_t v) { return (v + 255) & ~(size_t)255; }

extern "C" void kernel_launch(void* const* d_in, const int* in_sizes, int n_in,
                              void* d_out, int out_size, void* d_ws, size_t ws_size,
                              hipStream_t stream)
{
  const float* R     = (const float*)d_in[0];
  const float* tr    = (const float*)d_in[1];
  const float* x     = (const float*)d_in[2];
  const float* z     = (const float*)d_in[3];
  const int*   ei    = (const int*)  d_in[4];
  const float* Wq    = (const float*)d_in[5];
  const float* Wk    = (const float*)d_in[6];
  const float* Wv    = (const float*)d_in[7];
  const float* Wpair = (const float*)d_in[8];
  const float* spc   = (const float*)d_in[9];
  const float* Wqp   = (const float*)d_in[10];
  const float* Wkp   = (const float*)d_in[11];
  const float* Wvp   = (const float*)d_in[12];
  const float* Wo    = (const float*)d_in[13];
  const float* bo    = (const float*)d_in[14];
  const float* g1    = (const float*)d_in[15];
  const float* b1v   = (const float*)d_in[16];
  const float* w1    = (const float*)d_in[17];
  const float* bb1   = (const float*)d_in[18];
  const float* w2    = (const float*)d_in[19];
  const float* bb2   = (const float*)d_in[20];
  const float* w3    = (const float*)d_in[21];
  const float* bb3   = (const float*)d_in[22];
  const float* g2    = (const float*)d_in[23];
  const float* b2v   = (const float*)d_in[24];
  float* out = (float*)d_out;
  char* ws = (char*)d_ws;

  // region 0: Pq | Pqp | Pkp (f32, dead after prep_node)
  //   reused as: featB [0, fb) | scratch [fb, fb+max(PL, XO2))  (PL in attn, XO2 after)
  size_t pq_b  = alup((size_t)NN*PQ_COLS*4);
  size_t pqp_b = alup((size_t)NN*PQP_COLS*4);
  size_t pkp_b = alup((size_t)NN*PKP_COLS*4);
  size_t region = pq_b + pqp_b + pkp_b;                         // 76.8 MB
  size_t fb_b = alup((size_t)NN*FCOLS*2);                       // 57.6 MB
  size_t pl_b = alup((size_t)EE*12*4);                          // 15.36 MB
  size_t xo2_b = alup((size_t)NN*128*4);                        // 10.24 MB
  size_t scr = (pl_b > xo2_b) ? pl_b : xo2_b;
  if (fb_b + scr > region) region = fb_b + scr;

  float* Pq  = (float*)ws;
  float* Pqp = (float*)(ws + pq_b);
  float* Pkp = (float*)(ws + pq_b + pqp_b);
  __hip_bfloat16* featB = (__hip_bfloat16*)ws;
  float* PL  = (float*)(ws + fb_b);
  float* XO2 = (float*)(ws + fb_b);

  size_t off = region;
  __hip_bfloat16* QE = (__hip_bfloat16*)(ws + off); off += alup((size_t)NN*QE_COLS*2);
  __hip_bfloat16* VE = (__hip_bfloat16*)(ws + off); off += alup((size_t)NN*VE_COLS*2);
  __hip_bfloat16* KE = (__hip_bfloat16*)(ws + off); off += alup((size_t)NN*KE_COLS*2);
  int* cnt = (int*)(ws + off);       off += alup((size_t)NN*4);
  int* rowptr = (int*)(ws + off);    off += alup((size_t)(NN+1)*4);
  int* cursor = (int*)(ws + off);    off += alup((size_t)NN*4);
  int* eidx = (int*)(ws + off);      off += alup((size_t)EE*4);
  int* dstE = (int*)(ws + off);      off += alup((size_t)EE*4);
  __hip_bfloat16* XB  = (__hip_bfloat16*)(ws + off); off += alup((size_t)NN*128*2);
  __hip_bfloat16* WBt = (__hip_bfloat16*)(ws + off); off += alup((size_t)2016*128*2);
  __hip_bfloat16* WoT = (__hip_bfloat16*)(ws + off); off += alup((size_t)128*1440*2);
  float* xo = out;

  if (ws_size < off) {
    diag_ws<<<1, 64, 0, stream>>>(out, (float)((double)ws_size / (1024.0*1024.0)));
    return;
  }

  hipMemsetAsync(cnt, 0, (size_t)NN*4, stream);

  cvt_x<<<(NN*128/4 + 255)/256, 256, 0, stream>>>(x, XB);
  cvt_w<<<(2016*128 + 128*1440 + 255)/256, 256, 0, stream>>>(Wq, Wk, Wv, Wqp, Wkp, Wvp, Wo, WBt, WoT);
  proj_mfma<<<dim3((NN + 63)/64, 16), 256, 0, stream>>>(XB, WBt, Pq, Pqp, Pkp, KE, VE);
  prep_node<<<NN, 256, 0, stream>>>(Pq, Pqp, Pkp, R, tr, spc, QE, KE, VE);
  pl_kernel<<<(EE + 63)/64, 256, 0, stream>>>(z, Wpair, PL);   // after prep_node (PL aliases Pkp)
  count_edges<<<EE/256, 256, 0, stream>>>(ei, cnt);
  scan_csr<<<1, 1024, 0, stream>>>(cnt, rowptr, cursor);
  fill_csr<<<EE/256, 256, 0, stream>>>(ei, cursor, eidx, dstE);
  attn_wave<<<NN/4, 256, 0, stream>>>(QE, KE, VE, z, PL, rowptr, eidx, dstE, R, tr, featB);
  wo_mfma<<<dim3((NN + 63)/64, 2), 256, 0, stream>>>(featB, WoT, bo, x, xo, XO2);
  lnmlp2<<<NN/32, 256, 0, stream>>>(xo, XO2, g1, b1v, w1, bb1, w2, bb2,
                                    w3, bb3, g2, b2v, out);
}

// Round 13
// 408.982 us; speedup vs baseline: 2.3748x; 1.1075x over previous
//
#include <hip/hip_runtime.h>
#include <hip/hip_bf16.h>
#include <math.h>

#define NN 20000
#define EE 320000
#define PQ_COLS  384
#define PQP_COLS 288
#define PKP_COLS 288
#define QE_COLS  768
#define VE_COLS  672
#define KE_COLS  768
#define FCOLS 1440

typedef __attribute__((ext_vector_type(8))) short bf16x8v;
typedef __attribute__((ext_vector_type(4))) float f32x4v;

__device__ __forceinline__ float b2f(unsigned short u) {
  return __uint_as_float(((unsigned)u) << 16);
}
__device__ __forceinline__ unsigned short f2bu(float f) {
  __hip_bfloat16 h = __float2bfloat16(f);
  return *reinterpret_cast<unsigned short*>(&h);
}

// ---------------- dtype conversion prekernels
__global__ void cvt_x(const float* __restrict__ x, __hip_bfloat16* __restrict__ XB)
{
  int i = (blockIdx.x*256 + threadIdx.x) * 4;
  if (i >= NN*128) return;
  float4 v = *(const float4*)&x[i];
  XB[i+0] = __float2bfloat16(v.x); XB[i+1] = __float2bfloat16(v.y);
  XB[i+2] = __float2bfloat16(v.z); XB[i+3] = __float2bfloat16(v.w);
}

__global__ void cvt_w(const float* __restrict__ Wq, const float* __restrict__ Wk,
                      const float* __restrict__ Wv, const float* __restrict__ Wqp,
                      const float* __restrict__ Wkp, const float* __restrict__ Wvp,
                      const float* __restrict__ Wo,
                      const float* __restrict__ w1, const float* __restrict__ w2,
                      const float* __restrict__ w3,
                      __hip_bfloat16* __restrict__ WBt, __hip_bfloat16* __restrict__ WoT,
                      __hip_bfloat16* __restrict__ W1T, __hip_bfloat16* __restrict__ W2T,
                      __hip_bfloat16* __restrict__ W3T)
{
  int idx = blockIdx.x*256 + threadIdx.x;
  if (idx < 2016*128) {
    int c = idx >> 7, k = idx & 127;
    float v;
    if      (c < 384)  v = Wq [k*384 + c];
    else if (c < 768)  v = Wk [k*384 + (c-384)];
    else if (c < 1152) v = Wv [k*384 + (c-768)];
    else if (c < 1440) v = Wqp[k*288 + (c-1152)];
    else if (c < 1728) v = Wkp[k*288 + (c-1440)];
    else               v = Wvp[k*288 + (c-1728)];
    WBt[idx] = __float2bfloat16(v);
    return;
  }
  int j = idx - 2016*128;
  if (j < 128*1440) {
    int c = j / 1440, k = j - c*1440;
    WoT[j] = __float2bfloat16(Wo[k*128 + c]);
    return;
  }
  int m = j - 128*1440;
  if (m < 3*16384) {
    int layer = m >> 14, cm = m & 16383;
    int c = cm >> 7, k = cm & 127;
    const float* w = (layer == 0) ? w1 : (layer == 1) ? w2 : w3;
    __hip_bfloat16* o = (layer == 0) ? W1T : (layer == 1) ? W2T : W3T;
    o[cm] = __float2bfloat16(w[k*128 + c]);
  }
}

// ---------------- MFMA projection (unchanged)
__global__ __launch_bounds__(256) void proj_mfma(
    const __hip_bfloat16* __restrict__ XB, const __hip_bfloat16* __restrict__ WBt,
    float* __restrict__ Pq, float* __restrict__ Pqp, float* __restrict__ Pkp,
    __hip_bfloat16* __restrict__ KE, __hip_bfloat16* __restrict__ VE)
{
  __shared__ short A_lds[64*136];
  __shared__ short B_lds[128*136];
  const int t = threadIdx.x;
  const int n0 = blockIdx.x * 64;
  const int c0 = blockIdx.y * 128;
  {
    int r = t >> 2, kc = (t & 3) * 32;
    int gr = n0 + r; if (gr >= NN) gr = NN-1;
    const uint4* src = (const uint4*)(XB + (size_t)gr*128 + kc);
    uint4 v0 = src[0], v1 = src[1], v2 = src[2], v3 = src[3];
    *(uint4*)&A_lds[r*136 + kc +  0] = v0;
    *(uint4*)&A_lds[r*136 + kc +  8] = v1;
    *(uint4*)&A_lds[r*136 + kc + 16] = v2;
    *(uint4*)&A_lds[r*136 + kc + 24] = v3;
  }
  {
    int cI = t >> 1, ko = (t & 1) * 64;
    int gc = c0 + cI; if (gc > 2015) gc = 2015;
    const uint4* src = (const uint4*)(WBt + (size_t)gc*128 + ko);
    #pragma unroll
    for (int j = 0; j < 8; j++)
      *(uint4*)&B_lds[cI*136 + ko + j*8] = src[j];
  }
  __syncthreads();
  const int lane = t & 63, wid = t >> 6;
  const int wm = wid >> 1, wn = wid & 1;
  const int lrow = lane >> 4, lcol = lane & 15;
  f32x4v zero = {0.f, 0.f, 0.f, 0.f};
  f32x4v acc[2][4];
  #pragma unroll
  for (int i = 0; i < 2; i++)
    #pragma unroll
    for (int j = 0; j < 4; j++) acc[i][j] = zero;
  #pragma unroll
  for (int ks = 0; ks < 4; ks++) {
    int kb = ks*32 + lrow*8;
    bf16x8v a0 = *(const bf16x8v*)&A_lds[(wm*32 +      lcol)*136 + kb];
    bf16x8v a1 = *(const bf16x8v*)&A_lds[(wm*32 + 16 + lcol)*136 + kb];
    #pragma unroll
    for (int nt = 0; nt < 4; nt++) {
      bf16x8v b = *(const bf16x8v*)&B_lds[(wn*64 + nt*16 + lcol)*136 + kb];
      acc[0][nt] = __builtin_amdgcn_mfma_f32_16x16x32_bf16(a0, b, acc[0][nt], 0, 0, 0);
      acc[1][nt] = __builtin_amdgcn_mfma_f32_16x16x32_bf16(a1, b, acc[1][nt], 0, 0, 0);
    }
  }
  #pragma unroll
  for (int nt = 0; nt < 4; nt++) {
    int colb = c0 + wn*64 + nt*16;
    if (colb >= 2016) continue;
    int col = colb + lcol;
    #pragma unroll
    for (int mt = 0; mt < 2; mt++) {
      #pragma unroll
      for (int r = 0; r < 4; r++) {
        int grow = n0 + wm*32 + mt*16 + lrow*4 + r;
        if (grow >= NN) continue;
        float v = acc[mt][nt][r];
        if      (col < 384)  Pq[(size_t)grow*PQ_COLS + col] = v;
        else if (col < 768)  { int d = col-384; KE[(size_t)grow*KE_COLS + (d>>5)*64 + (d&31)] = __float2bfloat16(v); }
        else if (col < 1152) VE[(size_t)grow*VE_COLS + (col-768)] = __float2bfloat16(v);
        else if (col < 1440) Pqp[(size_t)grow*PQP_COLS + (col-1152)] = v;
        else if (col < 1728) Pkp[(size_t)grow*PKP_COLS + (col-1440)] = v;
        else                 VE[(size_t)grow*VE_COLS + 384 + (col-1728)] = __float2bfloat16(v);
      }
    }
  }
}

// ---------------- fused per-node prep (unchanged)
__global__ __launch_bounds__(256) void prep_node(
    const float* __restrict__ Pq, const float* __restrict__ Pqp, const float* __restrict__ Pkp,
    const float* __restrict__ R, const float* __restrict__ tr, const float* __restrict__ spc,
    __hip_bfloat16* __restrict__ QE, __hip_bfloat16* __restrict__ KE,
    __hip_bfloat16* __restrict__ VE)
{
  __shared__ float qpg[288];
  __shared__ float skk[12], cf[12];
  const int n = blockIdx.x, t = threadIdx.x;
  if (t < 12) { cf[t] = log1pf(expf(spc[t])) * (1.f/12.f); skk[t] = 0.f; }
  __syncthreads();
  const float* Rn = R + (size_t)n*9;
  const float r0=Rn[0],r1=Rn[1],r2=Rn[2],r3=Rn[3],r4=Rn[4],r5=Rn[5],r6=Rn[6],r7=Rn[7],r8=Rn[8];
  const float t0=tr[n*3],t1=tr[n*3+1],t2=tr[n*3+2];
  for (int task = t; task < 288; task += 256) {
    if (task < 96) {
      const float* p = Pqp + (size_t)n*PQP_COLS + task*3;
      float l0=p[0],l1=p[1],l2=p[2];
      qpg[task*3+0] = r0*l0+r1*l1+r2*l2+t0;
      qpg[task*3+1] = r3*l0+r4*l1+r5*l2+t1;
      qpg[task*3+2] = r6*l0+r7*l1+r8*l2+t2;
    } else if (task < 192) {
      int j = task-96, h = j>>3, jj = j&7;
      const float* p = Pkp + (size_t)n*PKP_COLS + h*24 + jj*3;
      float l0=p[0],l1=p[1],l2=p[2];
      __hip_bfloat16 b0=__float2bfloat16(r0*l0+r1*l1+r2*l2+t0);
      __hip_bfloat16 b1=__float2bfloat16(r3*l0+r4*l1+r5*l2+t1);
      __hip_bfloat16 b2=__float2bfloat16(r6*l0+r7*l1+r8*l2+t2);
      __hip_bfloat16* o = KE + (size_t)n*KE_COLS + h*64 + 32 + jj*3;
      o[0]=b0; o[1]=b1; o[2]=b2;
      float f0=__bfloat162float(b0), f1=__bfloat162float(b1), f2=__bfloat162float(b2);
      atomicAdd(&skk[h], f0*f0 + f1*f1 + f2*f2);
    } else {
      __hip_bfloat16* p = VE + (size_t)n*VE_COLS + 384 + (task-192)*3;
      float l0=__bfloat162float(p[0]), l1=__bfloat162float(p[1]), l2=__bfloat162float(p[2]);
      p[0] = __float2bfloat16(r0*l0+r1*l1+r2*l2+t0);
      p[1] = __float2bfloat16(r3*l0+r4*l1+r5*l2+t1);
      p[2] = __float2bfloat16(r6*l0+r7*l1+r8*l2+t2);
    }
  }
  __syncthreads();
  #pragma unroll
  for (int u = 0; u < 3; u++) {
    int s = t + 256*u;
    int h = s >> 6, i = s & 63;
    float val = 0.f;
    if (i < 32)      val = 0.1020620726f * Pq[(size_t)n*PQ_COLS + h*32 + i];
    else if (i < 56) val = 1.15470053838f * cf[h] * qpg[h*24 + (i-32)];
    else if (i == 58 || i == 59) val = 1.0f;
    QE[(size_t)n*QE_COLS + s] = __float2bfloat16(val);
  }
  if (t < 96) {
    int h = t >> 3, i = t & 7;
    float skkp = -0.57735026919f * cf[h] * skk[h];
    __hip_bfloat16 hi = __float2bfloat16(skkp);
    float res = skkp - __bfloat162float(hi);
    __hip_bfloat16 outv;
    if (i == 2)      outv = hi;
    else if (i == 3) outv = __float2bfloat16(res);
    else             outv = __float2bfloat16(0.0f);
    KE[(size_t)n*KE_COLS + h*64 + 56 + i] = outv;
  }
}

// ---------------- pair-logit panel
__global__ __launch_bounds__(256) void pl_kernel(
    const float* __restrict__ z, const float* __restrict__ Wpair, float* __restrict__ PL)
{
  __shared__ float wp[384];
  const int t = threadIdx.x;
  for (int i = t; i < 384; i += 256) wp[i] = Wpair[i] * 0.57735026919f;
  __syncthreads();
  int e0 = blockIdx.x * 64;
  #pragma unroll
  for (int u = 0; u < 3; u++) {
    int idx = t + 256*u;
    int q = idx / 12, h = idx - 12*q;
    int e = e0 + q;
    if (q < 64 && e < EE) {
      const float* zr = z + (size_t)e*32;
      float s = 0.f;
      #pragma unroll
      for (int c = 0; c < 32; c++) s += zr[c] * wp[c*12 + h];
      PL[(size_t)e*12 + h] = s;
    }
  }
}

// ---------------- CSR build
__global__ void count_edges(const int* __restrict__ ei, int* __restrict__ cnt)
{
  int e = blockIdx.x*256 + threadIdx.x;
  if (e < EE) atomicAdd(&cnt[ei[e]], 1);
}

__global__ __launch_bounds__(1024) void scan_csr(const int* __restrict__ cnt,
                                                 int* __restrict__ rowptr,
                                                 int* __restrict__ cursor)
{
  __shared__ int part[1024];
  int t = threadIdx.x;
  int base = t*20;
  int loc[20];
  int s = 0;
  #pragma unroll
  for (int i = 0; i < 20; i++) {
    int idx = base + i;
    int cc = (idx < NN) ? cnt[idx] : 0;
    loc[i] = s; s += cc;
  }
  part[t] = s;
  __syncthreads();
  for (int off = 1; off < 1024; off <<= 1) {
    int v = (t >= off) ? part[t-off] : 0;
    __syncthreads();
    part[t] += v;
    __syncthreads();
  }
  int pre = (t == 0) ? 0 : part[t-1];
  #pragma unroll
  for (int i = 0; i < 20; i++) {
    int idx = base + i;
    if (idx < NN) { rowptr[idx] = pre + loc[i]; cursor[idx] = pre + loc[i]; }
  }
  if (t == 1023) rowptr[NN] = part[1023];
}

__global__ void fill_csr(const int* __restrict__ ei, int* __restrict__ cursor,
                         int* __restrict__ eidx, int* __restrict__ dstE)
{
  int e = blockIdx.x*256 + threadIdx.x;
  if (e >= EE) return;
  int pos = atomicAdd(&cursor[ei[e]], 1);
  eidx[pos] = e;
  dstE[pos] = ei[EE + e];
}

__device__ __forceinline__ float dot8(const float* qr, uint4 v) {
  float s;
  s  = qr[0]*b2f((unsigned short)(v.x & 0xffffu));
  s += qr[1]*b2f((unsigned short)(v.x >> 16));
  s += qr[2]*b2f((unsigned short)(v.y & 0xffffu));
  s += qr[3]*b2f((unsigned short)(v.y >> 16));
  s += qr[4]*b2f((unsigned short)(v.z & 0xffffu));
  s += qr[5]*b2f((unsigned short)(v.z >> 16));
  s += qr[6]*b2f((unsigned short)(v.w & 0xffffu));
  s += qr[7]*b2f((unsigned short)(v.w >> 16));
  return s;
}

// ---------------- wave-per-node fused attention (r11-verbatim, passing version)
__global__ __launch_bounds__(256) void attn_wave(
    const __hip_bfloat16* __restrict__ QE,
    const __hip_bfloat16* __restrict__ KE,
    const __hip_bfloat16* __restrict__ VE,
    const float* __restrict__ z, const float* __restrict__ PL,
    const int* __restrict__ rowptr, const int* __restrict__ eidx,
    const int* __restrict__ dstE,
    const float* __restrict__ R, const float* __restrict__ tr,
    __hip_bfloat16* __restrict__ featB)
{
  __shared__ float sAgg[4][288];
  const int wid = threadIdx.x >> 6, lane = threadIdx.x & 63;
  const int n = blockIdx.x*4 + wid;

  float q0[8], q1[8];
  {
    const uint4* qrow = (const uint4*)(QE + (size_t)n*QE_COLS);
    uint4 Q0 = qrow[lane];
    q0[0]=b2f((unsigned short)(Q0.x&0xffffu)); q0[1]=b2f((unsigned short)(Q0.x>>16));
    q0[2]=b2f((unsigned short)(Q0.y&0xffffu)); q0[3]=b2f((unsigned short)(Q0.y>>16));
    q0[4]=b2f((unsigned short)(Q0.z&0xffffu)); q0[5]=b2f((unsigned short)(Q0.z>>16));
    q0[6]=b2f((unsigned short)(Q0.w&0xffffu)); q0[7]=b2f((unsigned short)(Q0.w>>16));
    if (lane < 32) {
      uint4 Q1 = qrow[64 + lane];
      q1[0]=b2f((unsigned short)(Q1.x&0xffffu)); q1[1]=b2f((unsigned short)(Q1.x>>16));
      q1[2]=b2f((unsigned short)(Q1.y&0xffffu)); q1[3]=b2f((unsigned short)(Q1.y>>16));
      q1[4]=b2f((unsigned short)(Q1.z&0xffffu)); q1[5]=b2f((unsigned short)(Q1.z>>16));
      q1[6]=b2f((unsigned short)(Q1.w&0xffffu)); q1[7]=b2f((unsigned short)(Q1.w>>16));
    } else {
      #pragma unroll
      for (int j = 0; j < 8; j++) q1[j] = 0.f;
    }
  }

  const int myh0 = (lane < 48) ? (lane >> 2) : ((8*lane - 384) / 24);
  const int myh1 = (128 + 8*lane) / 24;

  float mreg = -1e30f, sreg = 0.f;
  float accV0[8] = {}, accV1[8] = {}, accZ[12] = {};

  const int beg = rowptr[n], end = rowptr[n+1];
  for (int c0 = beg; c0 < end; c0 += 64) {
    const int cn = min(64, end - c0);
    int eL = (lane < cn) ? eidx[c0 + lane] : 0;
    int dL = (lane < cn) ? dstE[c0 + lane] : 0;
    for (int j = 0; j < cn; j++) {
      const int e   = __shfl(eL, j);
      const int dst = __shfl(dL, j);
      const uint4* ke = (const uint4*)(KE + (size_t)dst*KE_COLS);
      uint4 K0 = ke[lane];
      uint4 K1 = make_uint4(0,0,0,0);
      if (lane < 32) K1 = ke[64 + lane];
      const uint4* ve = (const uint4*)(VE + (size_t)dst*VE_COLS);
      uint4 V0 = ve[lane];
      uint4 V1 = make_uint4(0,0,0,0);
      if (lane < 20) V1 = ve[64 + lane];
      float zc = (lane < 32) ? z[(size_t)e*32 + lane] : 0.f;
      float pl = (lane < 12) ? PL[(size_t)e*12 + lane] : 0.f;
      float p0 = dot8(q0, K0);
      p0 += __shfl_xor(p0, 1); p0 += __shfl_xor(p0, 2); p0 += __shfl_xor(p0, 4);
      float p1 = dot8(q1, K1);
      p1 += __shfl_xor(p1, 1); p1 += __shfl_xor(p1, 2); p1 += __shfl_xor(p1, 4);
      float pa = __shfl(p0, (lane & 7) * 8);
      float pb = __shfl(p1, (lane & 3) * 8);
      float lg = ((lane < 8) ? pa : pb) + pl;
      float mn = fmaxf(mreg, lg);
      unsigned long long chg = __ballot(mn > mreg) & 0xFFFull;
      float w = expf(lg - mn);
      float r = expf(mreg - mn);
      mreg = mn;
      sreg = sreg * r + w;
      if (chg) {
        float rv0 = __shfl(r, myh0);
        #pragma unroll
        for (int q2 = 0; q2 < 8; q2++) accV0[q2] *= rv0;
        float rv1 = __shfl(r, myh1);
        if (lane < 20) {
          #pragma unroll
          for (int q2 = 0; q2 < 8; q2++) accV1[q2] *= rv1;
        }
        #pragma unroll
        for (int h = 0; h < 12; h++) accZ[h] *= __shfl(r, h);
      }
      float wv0 = __shfl(w, myh0);
      accV0[0] += wv0 * b2f((unsigned short)(V0.x & 0xffffu));
      accV0[1] += wv0 * b2f((unsigned short)(V0.x >> 16));
      accV0[2] += wv0 * b2f((unsigned short)(V0.y & 0xffffu));
      accV0[3] += wv0 * b2f((unsigned short)(V0.y >> 16));
      accV0[4] += wv0 * b2f((unsigned short)(V0.z & 0xffffu));
      accV0[5] += wv0 * b2f((unsigned short)(V0.z >> 16));
      accV0[6] += wv0 * b2f((unsigned short)(V0.w & 0xffffu));
      accV0[7] += wv0 * b2f((unsigned short)(V0.w >> 16));
      float wv1 = __shfl(w, myh1);
      if (lane < 20) {
        accV1[0] += wv1 * b2f((unsigned short)(V1.x & 0xffffu));
        accV1[1] += wv1 * b2f((unsigned short)(V1.x >> 16));
        accV1[2] += wv1 * b2f((unsigned short)(V1.y & 0xffffu));
        accV1[3] += wv1 * b2f((unsigned short)(V1.y >> 16));
        accV1[4] += wv1 * b2f((unsigned short)(V1.z & 0xffffu));
        accV1[5] += wv1 * b2f((unsigned short)(V1.z >> 16));
        accV1[6] += wv1 * b2f((unsigned short)(V1.w & 0xffffu));
        accV1[7] += wv1 * b2f((unsigned short)(V1.w >> 16));
      }
      #pragma unroll
      for (int h = 0; h < 12; h++) accZ[h] += __shfl(w, h) * zc;
    }
  }

  float inv = 0.f;
  if (lane < 12) inv = (sreg > 0.f) ? 1.f/sreg : 0.f;
  __hip_bfloat16* fr = featB + (size_t)n*FCOLS;
  #pragma unroll
  for (int h = 0; h < 12; h++) {
    float iv = __shfl(inv, h);
    if (lane < 32) fr[h*32 + lane] = __float2bfloat16(accZ[h] * iv);
  }
  float iv0 = __shfl(inv, myh0);
  if (lane < 48) {
    uint4 P;
    P.x = (unsigned)f2bu(accV0[0]*iv0) | ((unsigned)f2bu(accV0[1]*iv0) << 16);
    P.y = (unsigned)f2bu(accV0[2]*iv0) | ((unsigned)f2bu(accV0[3]*iv0) << 16);
    P.z = (unsigned)f2bu(accV0[4]*iv0) | ((unsigned)f2bu(accV0[5]*iv0) << 16);
    P.w = (unsigned)f2bu(accV0[6]*iv0) | ((unsigned)f2bu(accV0[7]*iv0) << 16);
    *(uint4*)(fr + 384 + lane*8) = P;
  } else {
    #pragma unroll
    for (int j2 = 0; j2 < 8; j2++) sAgg[wid][(lane-48)*8 + j2] = accV0[j2]*iv0;
  }
  float iv1 = __shfl(inv, myh1);
  if (lane < 20) {
    #pragma unroll
    for (int j2 = 0; j2 < 8; j2++) sAgg[wid][128 + lane*8 + j2] = accV1[j2]*iv1;
  }
  __syncthreads();
  {
    const float* Rn = R + (size_t)n*9;
    float t0 = tr[n*3], t1 = tr[n*3+1], t2 = tr[n*3+2];
    #pragma unroll
    for (int pp = 0; pp < 2; pp++) {
      int pt = lane + pp*64;
      if (pt < 96) {
        float d0 = sAgg[wid][pt*3+0] - t0;
        float d1 = sAgg[wid][pt*3+1] - t1;
        float d2 = sAgg[wid][pt*3+2] - t2;
        float l0 = Rn[0]*d0 + Rn[3]*d1 + Rn[6]*d2;
        float l1 = Rn[1]*d0 + Rn[4]*d1 + Rn[7]*d2;
        float l2 = Rn[2]*d0 + Rn[5]*d1 + Rn[8]*d2;
        float nr = sqrtf(l0*l0 + l1*l1 + l2*l2);
        float ivn = 1.f / fmaxf(nr, 1e-8f);
        fr[768 + pt*3+0] = __float2bfloat16(l0);
        fr[768 + pt*3+1] = __float2bfloat16(l1);
        fr[768 + pt*3+2] = __float2bfloat16(l2);
        fr[1056 + pt]    = __float2bfloat16(nr);
        fr[1152 + pt*3+0] = __float2bfloat16(l0*ivn);
        fr[1152 + pt*3+1] = __float2bfloat16(l1*ivn);
        fr[1152 + pt*3+2] = __float2bfloat16(l2*ivn);
      }
    }
  }
}

// ---------------- fused Wo GEMM + LN1 + MLP(MFMA) + residual + LN2 -> out
// arena hardened: float4-typed (guaranteed 16B alignment)
__global__ __launch_bounds__(256) void wo_mlp(
    const __hip_bfloat16* __restrict__ featB, const __hip_bfloat16* __restrict__ WoT,
    const float* __restrict__ bo, const float* __restrict__ x,
    const __hip_bfloat16* __restrict__ W1T, const float* __restrict__ bb1,
    const __hip_bfloat16* __restrict__ W2T, const float* __restrict__ bb2,
    const __hip_bfloat16* __restrict__ W3T, const float* __restrict__ bb3,
    const float* __restrict__ g1, const float* __restrict__ b1v,
    const float* __restrict__ g2, const float* __restrict__ b2v,
    float* __restrict__ out)
{
  // arena: phase1 A_lds short[64*104]@0 (13312B) | B_lds short[128*104]@13312 (26624B)
  //        phase2 hs float[64*132]@0 (33792B)   | actB short[64*136]@33792 (17408B)
  __shared__ float4 arenaV[3200];   // 51200 bytes, 16B-aligned
  __shared__ float mu_s[64], rs_s[64];
  char* arena  = (char*)arenaV;
  short* A_lds = (short*)arena;
  short* B_lds = (short*)(arena + 13312);
  float* hs    = (float*)arena;
  short* actB  = (short*)(arena + 33792);

  const int t = threadIdx.x;
  const int n0 = blockIdx.x * 64;
  const int lane = t & 63, wid = t >> 6;
  const int wm = wid >> 1, wn = wid & 1;
  const int lrow = lane >> 4, lcol = lane & 15;
  f32x4v zero = {0.f, 0.f, 0.f, 0.f};

  // ---- phase 1: xo = featB @ Wo  (K=1440)
  f32x4v acc[2][4];
  #pragma unroll
  for (int i = 0; i < 2; i++)
    #pragma unroll
    for (int j = 0; j < 4; j++) acc[i][j] = zero;
  for (int k0 = 0; k0 < 1440; k0 += 96) {
    __syncthreads();
    {
      int r = t >> 2, kc = (t & 3) * 24;
      int gr = n0 + r; if (gr >= NN) gr = NN-1;
      const uint4* src = (const uint4*)(featB + (size_t)gr*FCOLS + k0 + kc);
      uint4 v0 = src[0], v1 = src[1], v2 = src[2];
      *(uint4*)&A_lds[r*104 + kc +  0] = v0;
      *(uint4*)&A_lds[r*104 + kc +  8] = v1;
      *(uint4*)&A_lds[r*104 + kc + 16] = v2;
    }
    {
      int cI = t >> 1, ko = (t & 1) * 48;
      const uint4* src = (const uint4*)(WoT + (size_t)cI*1440 + k0 + ko);
      #pragma unroll
      for (int j = 0; j < 6; j++)
        *(uint4*)&B_lds[cI*104 + ko + j*8] = src[j];
    }
    __syncthreads();
    #pragma unroll
    for (int ks = 0; ks < 3; ks++) {
      int kb = ks*32 + lrow*8;
      bf16x8v a0 = *(const bf16x8v*)&A_lds[(wm*32 +      lcol)*104 + kb];
      bf16x8v a1 = *(const bf16x8v*)&A_lds[(wm*32 + 16 + lcol)*104 + kb];
      #pragma unroll
      for (int nt = 0; nt < 4; nt++) {
        bf16x8v b = *(const bf16x8v*)&B_lds[(wn*64 + nt*16 + lcol)*104 + kb];
        acc[0][nt] = __builtin_amdgcn_mfma_f32_16x16x32_bf16(a0, b, acc[0][nt], 0, 0, 0);
        acc[1][nt] = __builtin_amdgcn_mfma_f32_16x16x32_bf16(a1, b, acc[1][nt], 0, 0, 0);
      }
    }
  }
  __syncthreads();   // all MFMA reads done before hs overwrites A/B
  #pragma unroll
  for (int nt = 0; nt < 4; nt++) {
    int col = wn*64 + nt*16 + lcol;
    float bv = bo[col];
    #pragma unroll
    for (int mt = 0; mt < 2; mt++) {
      #pragma unroll
      for (int r = 0; r < 4; r++) {
        int row = wm*32 + mt*16 + lrow*4 + r;
        int gr = n0 + row; if (gr >= NN) gr = NN-1;
        hs[row*132 + col] = acc[mt][nt][r] + bv + x[(size_t)gr*128 + col];
      }
    }
  }
  __syncthreads();
  // LN1
  for (int q = 0; q < 16; q++) {
    int r = wid*16 + q;
    float v0 = hs[r*132 + lane], v1 = hs[r*132 + lane + 64];
    float s = v0 + v1, ss = v0*v0 + v1*v1;
    #pragma unroll
    for (int m2 = 32; m2 >= 1; m2 >>= 1) { s += __shfl_xor(s, m2); ss += __shfl_xor(ss, m2); }
    if (lane == 0) { float mu = s*(1.f/128.f); mu_s[r] = mu; rs_s[r] = rsqrtf(ss*(1.f/128.f) - mu*mu + 1e-5f); }
  }
  __syncthreads();
  for (int e = t; e < 8192; e += 256) {
    int r = e >> 7, c = e & 127;
    float v = (hs[r*132 + c] - mu_s[r]) * rs_s[r] * g1[c] + b1v[c];
    hs[r*132 + c] = v;
    actB[r*136 + c] = (short)f2bu(v);
  }
  __syncthreads();

#define MLP_MFMA_LAYER(WT, BIAS, IS_LAST)                                       \
  {                                                                             \
    f32x4v acc2[2][4];                                                          \
    _Pragma("unroll")                                                           \
    for (int i = 0; i < 2; i++)                                                 \
      _Pragma("unroll")                                                         \
      for (int j = 0; j < 4; j++) acc2[i][j] = zero;                            \
    _Pragma("unroll")                                                           \
    for (int ks = 0; ks < 4; ks++) {                                            \
      int kb = ks*32 + lrow*8;                                                  \
      bf16x8v a0 = *(const bf16x8v*)&actB[(wm*32 +      lcol)*136 + kb];        \
      bf16x8v a1 = *(const bf16x8v*)&actB[(wm*32 + 16 + lcol)*136 + kb];        \
      _Pragma("unroll")                                                         \
      for (int nt = 0; nt < 4; nt++) {                                          \
        int col = wn*64 + nt*16 + lcol;                                         \
        bf16x8v b = *(const bf16x8v*)(WT + (size_t)col*128 + kb);               \
        acc2[0][nt] = __builtin_amdgcn_mfma_f32_16x16x32_bf16(a0, b, acc2[0][nt], 0, 0, 0); \
        acc2[1][nt] = __builtin_amdgcn_mfma_f32_16x16x32_bf16(a1, b, acc2[1][nt], 0, 0, 0); \
      }                                                                         \
    }                                                                           \
    __syncthreads();                                                            \
    _Pragma("unroll")                                                           \
    for (int nt = 0; nt < 4; nt++) {                                            \
      int col = wn*64 + nt*16 + lcol;                                           \
      float bv = BIAS[col];                                                     \
      _Pragma("unroll")                                                         \
      for (int mt = 0; mt < 2; mt++) {                                          \
        _Pragma("unroll")                                                       \
        for (int r = 0; r < 4; r++) {                                           \
          int row = wm*32 + mt*16 + lrow*4 + r;                                 \
          float v = acc2[mt][nt][r] + bv;                                       \
          if (IS_LAST) hs[row*132 + col] += v;                                  \
          else         actB[row*136 + col] = (short)f2bu(fmaxf(v, 0.f));        \
        }                                                                       \
      }                                                                         \
    }                                                                           \
    __syncthreads();                                                            \
  }

  MLP_MFMA_LAYER(W1T, bb1, 0)
  MLP_MFMA_LAYER(W2T, bb2, 0)
  MLP_MFMA_LAYER(W3T, bb3, 1)
#undef MLP_MFMA_LAYER

  // LN2
  for (int q = 0; q < 16; q++) {
    int r = wid*16 + q;
    float v0 = hs[r*132 + lane], v1 = hs[r*132 + lane + 64];
    float s = v0 + v1, ss = v0*v0 + v1*v1;
    #pragma unroll
    for (int m2 = 32; m2 >= 1; m2 >>= 1) { s += __shfl_xor(s, m2); ss += __shfl_xor(ss, m2); }
    if (lane == 0) { float mu = s*(1.f/128.f); mu_s[r] = mu; rs_s[r] = rsqrtf(ss*(1.f/128.f) - mu*mu + 1e-5f); }
  }
  __syncthreads();
  for (int e = t; e < 8192; e += 256) {
    int r = e >> 7, c = e & 127;
    int gr = n0 + r;
    if (gr < NN)
      out[(size_t)gr*128 + c] = (hs[r*132 + c] - mu_s[r]) * rs_s[r] * g2[c] + b2v[c];
  }
}

__global__ void diag_ws(float* out, float v)
{
  if (blockIdx.x == 0 && threadIdx.x == 0) out[0] = v;
}

// ---------------- host side ----------------
static inline size_t alup(size_t v) { return (v + 255) & ~(size_t)255; }

extern "C" void kernel_launch(void* const* d_in, const int* in_sizes, int n_in,
                              void* d_out, int out_size, void* d_ws, size_t ws_size,
                              hipStream_t stream)
{
  const float* R     = (const float*)d_in[0];
  const float* tr    = (const float*)d_in[1];
  const float* x     = (const float*)d_in[2];
  const float* z     = (const float*)d_in[3];
  const int*   ei    = (const int*)  d_in[4];
  const float* Wq    = (const float*)d_in[5];
  const float* Wk    = (const float*)d_in[6];
  const float* Wv    = (const float*)d_in[7];
  const float* Wpair = (const float*)d_in[8];
  const float* spc   = (const float*)d_in[9];
  const float* Wqp   = (const float*)d_in[10];
  const float* Wkp   = (const float*)d_in[11];
  const float* Wvp   = (const float*)d_in[12];
  const float* Wo    = (const float*)d_in[13];
  const float* bo    = (const float*)d_in[14];
  const float* g1    = (const float*)d_in[15];
  const float* b1v   = (const float*)d_in[16];
  const float* w1    = (const float*)d_in[17];
  const float* bb1   = (const float*)d_in[18];
  const float* w2    = (const float*)d_in[19];
  const float* bb2   = (const float*)d_in[20];
  const float* w3    = (const float*)d_in[21];
  const float* bb3   = (const float*)d_in[22];
  const float* g2    = (const float*)d_in[23];
  const float* b2v   = (const float*)d_in[24];
  float* out = (float*)d_out;
  char* ws = (char*)d_ws;

  size_t pq_b  = alup((size_t)NN*PQ_COLS*4);
  size_t pqp_b = alup((size_t)NN*PQP_COLS*4);
  size_t pkp_b = alup((size_t)NN*PKP_COLS*4);
  size_t region = pq_b + pqp_b + pkp_b;
  size_t fb_b = alup((size_t)NN*FCOLS*2);
  size_t pl_b = alup((size_t)EE*12*4);
  if (fb_b + pl_b > region) region = fb_b + pl_b;

  float* Pq  = (float*)ws;
  float* Pqp = (float*)(ws + pq_b);
  float* Pkp = (float*)(ws + pq_b + pqp_b);
  __hip_bfloat16* featB = (__hip_bfloat16*)ws;
  float* PL  = (float*)(ws + fb_b);

  size_t off = region;
  __hip_bfloat16* QE = (__hip_bfloat16*)(ws + off); off += alup((size_t)NN*QE_COLS*2);
  __hip_bfloat16* VE = (__hip_bfloat16*)(ws + off); off += alup((size_t)NN*VE_COLS*2);
  __hip_bfloat16* KE = (__hip_bfloat16*)(ws + off); off += alup((size_t)NN*KE_COLS*2);
  int* cnt = (int*)(ws + off);       off += alup((size_t)NN*4);
  int* rowptr = (int*)(ws + off);    off += alup((size_t)(NN+1)*4);
  int* cursor = (int*)(ws + off);    off += alup((size_t)NN*4);
  int* eidx = (int*)(ws + off);      off += alup((size_t)EE*4);
  int* dstE = (int*)(ws + off);      off += alup((size_t)EE*4);
  __hip_bfloat16* XB  = (__hip_bfloat16*)(ws + off); off += alup((size_t)NN*128*2);
  __hip_bfloat16* WBt = (__hip_bfloat16*)(ws + off); off += alup((size_t)2016*128*2);
  __hip_bfloat16* WoT = (__hip_bfloat16*)(ws + off); off += alup((size_t)128*1440*2);
  __hip_bfloat16* W1T = (__hip_bfloat16*)(ws + off); off += alup((size_t)128*128*2);
  __hip_bfloat16* W2T = (__hip_bfloat16*)(ws + off); off += alup((size_t)128*128*2);
  __hip_bfloat16* W3T = (__hip_bfloat16*)(ws + off); off += alup((size_t)128*128*2);

  if (ws_size < off) {
    diag_ws<<<1, 64, 0, stream>>>(out, (float)((double)ws_size / (1024.0*1024.0)));
    return;
  }

  hipMemsetAsync(cnt, 0, (size_t)NN*4, stream);

  cvt_x<<<(NN*128/4 + 255)/256, 256, 0, stream>>>(x, XB);
  cvt_w<<<(2016*128 + 128*1440 + 3*16384 + 255)/256, 256, 0, stream>>>(
      Wq, Wk, Wv, Wqp, Wkp, Wvp, Wo, w1, w2, w3, WBt, WoT, W1T, W2T, W3T);
  proj_mfma<<<dim3((NN + 63)/64, 16), 256, 0, stream>>>(XB, WBt, Pq, Pqp, Pkp, KE, VE);
  prep_node<<<NN, 256, 0, stream>>>(Pq, Pqp, Pkp, R, tr, spc, QE, KE, VE);
  pl_kernel<<<(EE + 63)/64, 256, 0, stream>>>(z, Wpair, PL);
  count_edges<<<EE/256, 256, 0, stream>>>(ei, cnt);
  scan_csr<<<1, 1024, 0, stream>>>(cnt, rowptr, cursor);
  fill_csr<<<EE/256, 256, 0, stream>>>(ei, cursor, eidx, dstE);
  attn_wave<<<NN/4, 256, 0, stream>>>(QE, KE, VE, z, PL, rowptr, eidx, dstE, R, tr, featB);
  wo_mlp<<<(NN + 63)/64, 256, 0, stream>>>(featB, WoT, bo, x,
                                           W1T, bb1, W2T, bb2, W3T, bb3,
                                           g1, b1v, g2, b2v, out);
}